// Round 7
// baseline (242.541 us; speedup 1.0000x reference)
//
#include <hip/hip_runtime.h>

typedef short short8 __attribute__((ext_vector_type(8)));
typedef unsigned short ushort8v __attribute__((ext_vector_type(8)));
typedef float f32x4 __attribute__((ext_vector_type(4)));

static __device__ __forceinline__ unsigned short f2b(float f) {
    unsigned int u = __builtin_bit_cast(unsigned int, f);
    unsigned int r = (u + 0x7fffu + ((u >> 16) & 1u)) >> 16;
    return (unsigned short)r;
}
static __device__ __forceinline__ unsigned short f2b_trunc(float f) {
    return (unsigned short)(__builtin_bit_cast(unsigned int, f) >> 16);
}
static __device__ __forceinline__ float b2f(unsigned short u) {
    return __builtin_bit_cast(float, (unsigned int)u << 16);
}
static __device__ __forceinline__ float exp2v(float x) {
    float r;
    asm("v_exp_f32 %0, %1" : "=v"(r) : "v"(x));
    return r;
}

__device__ __forceinline__ void gload16(void* lds, const void* g) {
    __builtin_amdgcn_global_load_lds(
        (const __attribute__((address_space(1))) void*)g,
        (__attribute__((address_space(3))) void*)lds, 16, 0, 0);
}

#define L2E 1.4426950408889634f

// ---------------- convert x (f32 -> bf16) ----------------
__global__ __launch_bounds__(256) void cvt_x_kernel(const float* __restrict__ x,
                                                    unsigned short* __restrict__ o, int n4) {
    int i = blockIdx.x * 256 + threadIdx.x;
    float4 f = ((const float4*)x)[i];
    ushort4 u;
    u.x = f2b(f.x); u.y = f2b(f.y); u.z = f2b(f.z); u.w = f2b(f.w);
    ((ushort4*)o)[i] = u;
}

// ---------------- transpose weight W[K][N] f32 -> Wt[N][K] bf16 ----------------
__global__ __launch_bounds__(256) void transpose_w(const float* __restrict__ W,
                                                   unsigned short* __restrict__ Wt,
                                                   int K, int N) {
    __shared__ float t[32][33];
    int kb = blockIdx.y << 5, nb = blockIdx.x << 5;
    int tx = threadIdx.x & 31, ty = threadIdx.x >> 5;  // 32 x 8
#pragma unroll
    for (int i = 0; i < 32; i += 8)
        t[ty + i][tx] = W[(size_t)(kb + ty + i) * N + nb + tx];
    __syncthreads();
#pragma unroll
    for (int i = 0; i < 32; i += 8)
        Wt[(size_t)(nb + ty + i) * K + kb + tx] = f2b(t[tx][ty + i]);
}

// ---------------- aug columns for Q/K (type+mask bias folded into MFMA) ----------------
__global__ __launch_bounds__(256) void aug_qk(const int* __restrict__ types,
                                              const int* __restrict__ nmask,
                                              const float* __restrict__ tt,
                                              unsigned short* __restrict__ Qb,
                                              unsigned short* __restrict__ Kb) {
    int t = blockIdx.x * 256 + threadIdx.x;  // 65536 threads
    int bh = t >> 10, n = t & 1023;
    int b = bh >> 3, h = bh & 7;
    int tj = types[b * 1024 + n];
    int mk = nmask[b * 1024 + n];
    float t00 = tt[h * 4], t01 = tt[h * 4 + 1], t10 = tt[h * 4 + 2], t11 = tt[h * 4 + 3];
    float bA = L2E * (t00 + (t01 - t00) * tj) + (mk ? 0.f : -1e30f);
    float bB = L2E * ((t10 - t00) + (t11 - t01 - t10 + t00) * tj);
    size_t off = ((size_t)bh * 1024 + n) * 128 + 96;
    ushort8v z = {0, 0, 0, 0, 0, 0, 0, 0};
    ushort8v qv = z, kv = z;
    qv[0] = 0x3F80u;
    qv[1] = tj ? 0x3F80u : 0u;
    kv[0] = f2b(bA);
    kv[1] = f2b(bB);
    *(ushort8v*)&Qb[off] = qv;
    *(ushort8v*)&Qb[off + 8] = z;
    *(ushort8v*)&Qb[off + 16] = z;
    *(ushort8v*)&Qb[off + 24] = z;
    *(ushort8v*)&Kb[off] = kv;
    *(ushort8v*)&Kb[off + 8] = z;
    *(ushort8v*)&Kb[off + 16] = z;
    *(ushort8v*)&Kb[off + 24] = z;
}

// ---------------- 128x128 BK=64 2-phase GEMM (unchanged from r6) ----------------
template <int EPI>
__global__ __launch_bounds__(256, 2) void gemm2p(
    const unsigned short* __restrict__ A, const unsigned short* __restrict__ Bt,
    const float* __restrict__ bias, float* __restrict__ outf,
    unsigned short* __restrict__ outb, unsigned short* __restrict__ q_o,
    unsigned short* __restrict__ k_o, unsigned short* __restrict__ v_o,
    int N, int K, int ntn, int NT) {
    __shared__ unsigned short a_lds[2][8192];
    __shared__ unsigned short b_lds[2][8192];
    const int tid = threadIdx.x;
    const int wave = tid >> 6, lane = tid & 63;
    const int lr = lane & 15, lg = lane >> 4;
    const int wm = wave >> 1, wn = wave & 1;
    const int nwg = gridDim.x;
    const int orig = blockIdx.x;
    const int swz = (orig & 7) * (nwg >> 3) + (orig >> 3);
    const int tm = swz / ntn, tn = swz % ntn;

    const unsigned short* srcA[4];
    const unsigned short* srcB[4];
#pragma unroll
    for (int i = 0; i < 4; ++i) {
        int g = i * 256 + tid;
        int row = g >> 3, sl = g & 7;
        int colg = sl ^ (row & 7);
        srcA[i] = A + (size_t)(tm * 128 + row) * K + colg * 8;
        srcB[i] = Bt + (size_t)(tn * 128 + row) * K + colg * 8;
    }
    auto stage = [&](int buf, int k0) {
#pragma unroll
        for (int i = 0; i < 4; ++i) {
            gload16(&a_lds[buf][i * 2048 + wave * 512], srcA[i] + k0);
            gload16(&b_lds[buf][i * 2048 + wave * 512], srcB[i] + k0);
        }
    };

    f32x4 acc[4][4] = {};

    stage(0, 0);
    asm volatile("s_waitcnt vmcnt(0)" ::: "memory");
    __builtin_amdgcn_s_barrier();

    for (int t = 0; t < NT; ++t) {
        const int buf = t & 1;
        if (t + 1 < NT) stage(buf ^ 1, (t + 1) * 64);
#pragma unroll
        for (int ks = 0; ks < 2; ++ks) {
            short8 af[4], bfr[4];
#pragma unroll
            for (int mf = 0; mf < 4; ++mf) {
                int row = wm * 64 + mf * 16 + lr;
                int slot = (ks * 4 + lg) ^ (row & 7);
                af[mf] = *(const short8*)&a_lds[buf][row * 64 + slot * 8];
            }
#pragma unroll
            for (int nf = 0; nf < 4; ++nf) {
                int row = wn * 64 + nf * 16 + lr;
                int slot = (ks * 4 + lg) ^ (row & 7);
                bfr[nf] = *(const short8*)&b_lds[buf][row * 64 + slot * 8];
            }
#pragma unroll
            for (int mf = 0; mf < 4; ++mf)
#pragma unroll
                for (int nf = 0; nf < 4; ++nf)
                    acc[mf][nf] = __builtin_amdgcn_mfma_f32_16x16x32_bf16(af[mf], bfr[nf], acc[mf][nf], 0, 0, 0);
        }
        asm volatile("s_waitcnt vmcnt(0)" ::: "memory");
        __builtin_amdgcn_s_barrier();
    }

#pragma unroll
    for (int mf = 0; mf < 4; ++mf) {
        int grb = tm * 128 + wm * 64 + mf * 16 + lg * 4;
#pragma unroll
        for (int nf = 0; nf < 4; ++nf) {
            int gc = tn * 128 + wn * 64 + nf * 16 + lr;
            float bv = bias[gc];
#pragma unroll
            for (int r = 0; r < 4; ++r) {
                int gr = grb + r;
                float v = acc[mf][nf][r] + bv;
                if constexpr (EPI == 0) {
                    outf[(size_t)gr * N + gc] = v;
                } else if constexpr (EPI == 2) {
                    float gl = 0.5f * v * (1.f + erff(v * 0.70710678f));
                    outb[(size_t)gr * N + gc] = f2b(gl);
                } else {
                    int part = gc / 768;
                    int cc = gc - part * 768;
                    int h = cc / 96, dh = cc - h * 96;
                    int b = gr >> 10, n2 = gr & 1023;
                    size_t bh = (size_t)(b * 8 + h);
                    if (part == 0) q_o[(bh * 1024 + n2) * 128 + dh] = f2b(v * 0.14724445f);
                    else if (part == 1) k_o[(bh * 1024 + n2) * 128 + dh] = f2b(v);
                    else v_o[(bh * 96 + dh) * 1024 + n2] = f2b(v);  // V transposed
                }
            }
        }
    }
}

// ---------------- flash attention (8 waves, dbuf, aug-K, exp2, flat-tile fast path) ----
__global__ __launch_bounds__(512, 4) void attn_kernel(
    const unsigned short* __restrict__ Qb, const unsigned short* __restrict__ Kb,
    const unsigned short* __restrict__ Vt, const float* __restrict__ centers,
    const float* __restrict__ rel_emb, unsigned short* __restrict__ Y) {
    __shared__ unsigned short kv_lds[2 * 14336];  // 56 KB
    __shared__ unsigned short p_lds[8 * 1024];    // 16 KB
    __shared__ float c_lds[1024];
    __shared__ float rel_lds[41];
    __shared__ float cjmm[2][16];  // per-tile cj min/max

    const int tid = threadIdx.x;
    const int wave = tid >> 6, lane = tid & 63;
    const int lr = lane & 15, lg = lane >> 4;
    const int bh = blockIdx.x, qb = blockIdx.y;
    const int b = bh >> 3, h = bh & 7;
    const int q0 = qb * 128 + wave * 16;
    const size_t kvbase = (size_t)bh * 1024 * 128;

    c_lds[tid] = centers[b * 1024 + tid];
    c_lds[tid + 512] = centers[b * 1024 + 512 + tid];
    if (tid < 41) rel_lds[tid] = rel_emb[tid * 8 + h] * L2E;
    __syncthreads();
    if (tid < 16) {
        float mn = c_lds[tid * 64], mx = mn;
        for (int j = 1; j < 64; ++j) {
            float c = c_lds[tid * 64 + j];
            mn = fminf(mn, c);
            mx = fmaxf(mx, c);
        }
        cjmm[0][tid] = mn;
        cjmm[1][tid] = mx;
    }

    const unsigned short* sbase[4];
    int sstep[4];
#pragma unroll
    for (int it = 0; it < 4; ++it) {
        int g = (it < 3) ? it * 512 + tid : 1536 + wave * 64 + lane;
        if (g < 1024) {  // K granule
            int ks = g >> 8, rem = g & 255, pr = rem >> 3, sl = rem & 7;
            int so = sl ^ (pr & 7);
            int r = ((so >> 2) << 5) + pr, oct = so & 3;
            sbase[it] = Kb + kvbase + (size_t)r * 128 + ks * 32 + oct * 8;
            sstep[it] = 64 * 128;
        } else {  // V granule
            int v = g - 1024, pr = v >> 3, sl = v & 7;
            int so = sl ^ (pr & 7);
            sbase[it] = Vt + (size_t)(bh * 96 + (pr < 96 ? pr : 95)) * 1024 + so * 8;
            sstep[it] = 64;
        }
    }
    auto stage = [&](int bufb, int kt) {
        unsigned short* dst = kv_lds + bufb * 14336;
#pragma unroll
        for (int it = 0; it < 3; ++it)
            gload16(dst + it * 4096 + wave * 512, sbase[it] + (size_t)kt * sstep[it]);
        if (tid < 256)
            gload16(dst + 3 * 4096 + wave * 512, sbase[3] + (size_t)kt * sstep[3]);
    };

    short8 qa[4];
#pragma unroll
    for (int ks = 0; ks < 4; ++ks)
        qa[ks] = *(const short8*)&Qb[kvbase + (size_t)(q0 + lr) * 128 + ks * 32 + lg * 8];
    float ci20[4];
#pragma unroll
    for (int r = 0; r < 4; ++r) ci20[r] = centers[b * 1024 + q0 + lg * 4 + r] + 20.f;

    // wave-level ci range (rows q0..q0+15)
    float cimax20 = fmaxf(fmaxf(ci20[0], ci20[1]), fmaxf(ci20[2], ci20[3]));
    float cimin20 = fminf(fminf(ci20[0], ci20[1]), fminf(ci20[2], ci20[3]));
    cimax20 = fmaxf(cimax20, __shfl_xor(cimax20, 16));
    cimax20 = fmaxf(cimax20, __shfl_xor(cimax20, 32));
    cimin20 = fminf(cimin20, __shfl_xor(cimin20, 16));
    cimin20 = fminf(cimin20, __shfl_xor(cimin20, 32));

    short8 vone = {};
    if (lr == 0) {
#pragma unroll
        for (int e = 0; e < 8; ++e) vone[e] = (short)0x3F80;
    }

    float m_r[4] = {-3e30f, -3e30f, -3e30f, -3e30f};
    f32x4 oacc[7] = {};

    stage(0, 0);
    __syncthreads();  // cjmm visible; tile-0 stage drained
    const float rel0 = rel_lds[0], rel40 = rel_lds[40];

    for (int kt = 0; kt < 16; ++kt) {
        const int buf = kt & 1;
        if (kt < 15) {
            stage(buf ^ 1, kt + 1);
            asm volatile("s_waitcnt vmcnt(3)" ::: "memory");
        } else {
            asm volatile("s_waitcnt vmcnt(0)" ::: "memory");
        }
        __builtin_amdgcn_s_barrier();
        const unsigned short* kv = kv_lds + buf * 14336;

        f32x4 s[4] = {};
#pragma unroll
        for (int jf = 0; jf < 4; ++jf) {
            int pr = ((jf & 1) << 4) + lr;
            int slp = (((jf >> 1) << 2) + lg) ^ (lr & 7);
#pragma unroll
            for (int ks = 0; ks < 4; ++ks) {
                short8 kf = *(const short8*)&kv[ks * 2048 + pr * 64 + slp * 8];
                s[jf] = __builtin_amdgcn_mfma_f32_16x16x32_bf16(qa[ks], kf, s[jf], 0, 0, 0);
            }
        }

        // ---- rel bias: flat-tile fast path (generic band check) ----
        {
            float cjmin = cjmm[0][kt], cjmax = cjmm[1][kt];
            if (cimin20 - cjmax >= 40.f) {  // all d >= +20 -> idx 40
#pragma unroll
                for (int jf = 0; jf < 4; ++jf)
#pragma unroll
                    for (int r = 0; r < 4; ++r) s[jf][r] += rel40;
            } else if (cimax20 - cjmin <= 0.f) {  // all d <= -20 -> idx 0
#pragma unroll
                for (int jf = 0; jf < 4; ++jf)
#pragma unroll
                    for (int r = 0; r < 4; ++r) s[jf][r] += rel0;
            } else {
#pragma unroll
                for (int jf = 0; jf < 4; ++jf) {
                    float cj = c_lds[kt * 64 + jf * 16 + lr];
#pragma unroll
                    for (int r = 0; r < 4; ++r) {
                        float idxf = __builtin_amdgcn_fmed3f(ci20[r] - cj, 0.f, 40.f);
                        s[jf][r] += rel_lds[(int)rintf(idxf)];
                    }
                }
            }
        }

        // ---- online softmax: defer-max with cheap trigger ----
#pragma unroll
        for (int r = 0; r < 4; ++r) {
            float mlr = fmaxf(fmaxf(s[0][r], s[1][r]), fmaxf(s[2][r], s[3][r]));
            if (!__all(mlr <= m_r[r] + 8.f)) {
                float mx = mlr;
#pragma unroll
                for (int off = 1; off < 16; off <<= 1) mx = fmaxf(mx, __shfl_xor(mx, off));
                float mn = fmaxf(m_r[r], mx);
                float al = exp2v(m_r[r] - mn);
                m_r[r] = mn;
#pragma unroll
                for (int nf = 0; nf < 7; ++nf) oacc[nf][r] *= al;
            }
#pragma unroll
            for (int jf = 0; jf < 4; ++jf) s[jf][r] = exp2v(s[jf][r] - m_r[r]);
        }

        // ---- P (C/D layout) -> swizzled LDS -> A-fragment ----
#pragma unroll
        for (int jf = 0; jf < 4; ++jf)
#pragma unroll
            for (int r = 0; r < 4; ++r) {
                int row = lg * 4 + r, col = jf * 16 + lr;
                int gp = (col >> 3) ^ (row & 7);
                p_lds[wave * 1024 + row * 64 + gp * 8 + (col & 7)] = f2b_trunc(s[jf][r]);
            }
        asm volatile("s_waitcnt lgkmcnt(0)" ::: "memory");
        short8 pa[2];
#pragma unroll
        for (int js = 0; js < 2; ++js) {
            int slp = ((js << 2) + lg) ^ (lr & 7);
            pa[js] = *(const short8*)&p_lds[wave * 1024 + lr * 64 + slp * 8];
        }

#pragma unroll
        for (int nf = 0; nf < 6; ++nf) {
            int vrow = nf * 16 + lr;
#pragma unroll
            for (int js = 0; js < 2; ++js) {
                int slp = ((js << 2) + lg) ^ (lr & 7);
                short8 vf = *(const short8*)&kv[8192 + vrow * 64 + slp * 8];
                oacc[nf] = __builtin_amdgcn_mfma_f32_16x16x32_bf16(pa[js], vf, oacc[nf], 0, 0, 0);
            }
        }
#pragma unroll
        for (int js = 0; js < 2; ++js)
            oacc[6] = __builtin_amdgcn_mfma_f32_16x16x32_bf16(pa[js], vone, oacc[6], 0, 0, 0);
        __builtin_amdgcn_s_barrier();
    }

#pragma unroll
    for (int r = 0; r < 4; ++r) {
        float l = __shfl(oacc[6][r], lane & 48);
        float inv = (l > 0.f) ? 1.f / l : 0.f;
        int qi = q0 + lg * 4 + r;
#pragma unroll
        for (int nf = 0; nf < 6; ++nf)
            Y[((size_t)b * 1024 + qi) * 768 + h * 96 + nf * 16 + lr] = f2b(oacc[nf][r] * inv);
    }
}

// ---------------- layernorm with residual add (vectorized, 2 rows/block) ----------------
template <bool IN1BF>
__global__ __launch_bounds__(384) void ln_kernel(const void* __restrict__ in1,
                                                 const float* __restrict__ in2,
                                                 const float* __restrict__ g,
                                                 const float* __restrict__ be,
                                                 float* __restrict__ of,
                                                 unsigned short* __restrict__ ob) {
    const int tid = threadIdx.x;
    const int half = tid / 192;       // waves 0-2 -> row0, waves 3-5 -> row1
    const int t = tid - half * 192;   // 0..191
    const int row = blockIdx.x * 2 + half;
    const size_t base = (size_t)row * 768 + t * 4;
    float v[4];
    if (IN1BF) {
        ushort4 a = *(const ushort4*)((const unsigned short*)in1 + base);
        float4 bb = *(const float4*)(in2 + base);
        v[0] = b2f(a.x) + bb.x; v[1] = b2f(a.y) + bb.y;
        v[2] = b2f(a.z) + bb.z; v[3] = b2f(a.w) + bb.w;
    } else {
        float4 a = *(const float4*)((const float*)in1 + base);
        float4 bb = *(const float4*)(in2 + base);
        v[0] = a.x + bb.x; v[1] = a.y + bb.y; v[2] = a.z + bb.z; v[3] = a.w + bb.w;
    }
    float s1 = v[0] + v[1] + v[2] + v[3];
    float s2 = v[0] * v[0] + v[1] * v[1] + v[2] * v[2] + v[3] * v[3];
#pragma unroll
    for (int off = 32; off > 0; off >>= 1) {
        s1 += __shfl_xor(s1, off);
        s2 += __shfl_xor(s2, off);
    }
    __shared__ float red[12];
    const int wv = tid >> 6;  // 0..5
    if ((tid & 63) == 0) { red[wv] = s1; red[6 + wv] = s2; }
    __syncthreads();
    const int w0 = half * 3;
    s1 = red[w0] + red[w0 + 1] + red[w0 + 2];
    s2 = red[6 + w0] + red[6 + w0 + 1] + red[6 + w0 + 2];
    float mu = s1 * (1.f / 768.f);
    float var = s2 * (1.f / 768.f) - mu * mu;
    float inv = rsqrtf(var + 1e-5f);
    float o[4];
#pragma unroll
    for (int i = 0; i < 4; ++i)
        o[i] = (v[i] - mu) * inv * g[t * 4 + i] + be[t * 4 + i];
    if (of) {
        float4 w = {o[0], o[1], o[2], o[3]};
        *(float4*)(of + base) = w;
    }
    if (ob) {
        ushort4 w = {f2b(o[0]), f2b(o[1]), f2b(o[2]), f2b(o[3])};
        *(ushort4*)(ob + base) = w;
    }
}

extern "C" void kernel_launch(void* const* d_in, const int* in_sizes, int n_in,
                              void* d_out, int out_size, void* d_ws, size_t ws_size,
                              hipStream_t stream) {
    const float* x     = (const float*)d_in[0];
    const int*   nmask = (const int*)d_in[1];
    const float* cent  = (const float*)d_in[2];
    const int*   types = (const int*)d_in[3];
    const float* qkv_w = (const float*)d_in[4];
    const float* qkv_b = (const float*)d_in[5];
    const float* out_w = (const float*)d_in[6];
    const float* out_b = (const float*)d_in[7];
    const float* ff1_w = (const float*)d_in[8];
    const float* ff1_b = (const float*)d_in[9];
    const float* ff2_w = (const float*)d_in[10];
    const float* ff2_b = (const float*)d_in[11];
    const float* ln1_g = (const float*)d_in[12];
    const float* ln1_b = (const float*)d_in[13];
    const float* ln2_g = (const float*)d_in[14];
    const float* ln2_b = (const float*)d_in[15];
    const float* rel   = (const float*)d_in[16];
    const float* ttp   = (const float*)d_in[17];

    char* w = (char*)d_ws;
    auto alloc = [&](size_t bytes) {
        char* p = w;
        w += (bytes + 255) & ~(size_t)255;
        return p;
    };
    unsigned short* xb  = (unsigned short*)alloc(8192ull * 768 * 2);   // x bf16; reused as Y
    unsigned short* qwT = (unsigned short*)alloc(2304ull * 768 * 2);
    unsigned short* owT = (unsigned short*)alloc(768ull * 768 * 2);
    unsigned short* f1T = (unsigned short*)alloc(1024ull * 768 * 2);
    unsigned short* f2T = (unsigned short*)alloc(768ull * 1024 * 2);
    unsigned short* Qb  = (unsigned short*)alloc(64ull * 1024 * 128 * 2);
    unsigned short* Kb  = (unsigned short*)alloc(64ull * 1024 * 128 * 2);
    unsigned short* Vt  = (unsigned short*)alloc(64ull * 96 * 1024 * 2);
    float*          ao  = (float*)alloc(8192ull * 768 * 4);
    unsigned short* h1b = (unsigned short*)alloc(8192ull * 768 * 2);
    unsigned short* ffa = Qb;  // alias: Qb dead after attn

    cvt_x_kernel<<<6144, 256, 0, stream>>>(x, xb, 8192 * 768 / 4);
    transpose_w<<<dim3(2304 / 32, 768 / 32), 256, 0, stream>>>(qkv_w, qwT, 768, 2304);
    transpose_w<<<dim3(768 / 32, 768 / 32), 256, 0, stream>>>(out_w, owT, 768, 768);
    transpose_w<<<dim3(1024 / 32, 768 / 32), 256, 0, stream>>>(ff1_w, f1T, 768, 1024);
    transpose_w<<<dim3(768 / 32, 1024 / 32), 256, 0, stream>>>(ff2_w, f2T, 1024, 768);

    // QKV: M=8192 N=2304 K=768 -> 64x18 = 1152 blocks
    gemm2p<3><<<1152, 256, 0, stream>>>(xb, qwT, qkv_b, nullptr, nullptr,
                                        Qb, Kb, Vt, 2304, 768, 18, 12);
    aug_qk<<<256, 256, 0, stream>>>(types, nmask, ttp, Qb, Kb);
    attn_kernel<<<dim3(64, 8), 512, 0, stream>>>(Qb, Kb, Vt, cent, rel, xb);
    // out proj: N=768 K=768 -> 64x6 = 384 blocks
    gemm2p<0><<<384, 256, 0, stream>>>(xb, owT, out_b, ao, nullptr,
                                       nullptr, nullptr, nullptr, 768, 768, 6, 12);
    ln_kernel<false><<<4096, 384, 0, stream>>>(x, ao, ln1_g, ln1_b, nullptr, h1b);
    // ff1+gelu: N=1024 K=768 -> 64x8 = 512 blocks
    gemm2p<2><<<512, 256, 0, stream>>>(h1b, f1T, ff1_b, nullptr, ffa,
                                       nullptr, nullptr, nullptr, 1024, 768, 8, 12);
    // ff2: N=768 K=1024 -> 64x6 = 384 blocks, NT=16
    gemm2p<0><<<384, 256, 0, stream>>>(ffa, f2T, ff2_b, ao, nullptr,
                                       nullptr, nullptr, nullptr, 768, 1024, 6, 16);
    ln_kernel<true><<<4096, 384, 0, stream>>>(h1b, ao, ln2_g, ln2_b, (float*)d_out, nullptr);
}

// Round 8
// 230.884 us; speedup vs baseline: 1.0505x; 1.0505x over previous
//
#include <hip/hip_runtime.h>

typedef short short8 __attribute__((ext_vector_type(8)));
typedef unsigned short ushort8v __attribute__((ext_vector_type(8)));
typedef float f32x4 __attribute__((ext_vector_type(4)));

static __device__ __forceinline__ unsigned short f2b(float f) {
    unsigned int u = __builtin_bit_cast(unsigned int, f);
    unsigned int r = (u + 0x7fffu + ((u >> 16) & 1u)) >> 16;
    return (unsigned short)r;
}
static __device__ __forceinline__ unsigned short f2b_trunc(float f) {
    return (unsigned short)(__builtin_bit_cast(unsigned int, f) >> 16);
}
static __device__ __forceinline__ float b2f(unsigned short u) {
    return __builtin_bit_cast(float, (unsigned int)u << 16);
}
static __device__ __forceinline__ float exp2v(float x) {
    float r;
    asm("v_exp_f32 %0, %1" : "=v"(r) : "v"(x));
    return r;
}

__device__ __forceinline__ void gload16(void* lds, const void* g) {
    __builtin_amdgcn_global_load_lds(
        (const __attribute__((address_space(1))) void*)g,
        (__attribute__((address_space(3))) void*)lds, 16, 0, 0);
}

#define L2E 1.4426950408889634f

// ---------------- convert x (f32 -> bf16) ----------------
__global__ __launch_bounds__(256) void cvt_x_kernel(const float* __restrict__ x,
                                                    unsigned short* __restrict__ o, int n4) {
    int i = blockIdx.x * 256 + threadIdx.x;
    float4 f = ((const float4*)x)[i];
    ushort4 u;
    u.x = f2b(f.x); u.y = f2b(f.y); u.z = f2b(f.z); u.w = f2b(f.w);
    ((ushort4*)o)[i] = u;
}

// ---------------- transpose weight W[K][N] f32 -> Wt[N][K] bf16 ----------------
__global__ __launch_bounds__(256) void transpose_w(const float* __restrict__ W,
                                                   unsigned short* __restrict__ Wt,
                                                   int K, int N) {
    __shared__ float t[32][33];
    int kb = blockIdx.y << 5, nb = blockIdx.x << 5;
    int tx = threadIdx.x & 31, ty = threadIdx.x >> 5;  // 32 x 8
#pragma unroll
    for (int i = 0; i < 32; i += 8)
        t[ty + i][tx] = W[(size_t)(kb + ty + i) * N + nb + tx];
    __syncthreads();
#pragma unroll
    for (int i = 0; i < 32; i += 8)
        Wt[(size_t)(nb + ty + i) * K + kb + tx] = f2b(t[tx][ty + i]);
}

// ---------------- aug columns for Q/K (type+mask bias folded into MFMA) ----------------
__global__ __launch_bounds__(256) void aug_qk(const int* __restrict__ types,
                                              const int* __restrict__ nmask,
                                              const float* __restrict__ tt,
                                              unsigned short* __restrict__ Qb,
                                              unsigned short* __restrict__ Kb) {
    int t = blockIdx.x * 256 + threadIdx.x;  // 65536 threads
    int bh = t >> 10, n = t & 1023;
    int b = bh >> 3, h = bh & 7;
    int tj = types[b * 1024 + n];
    int mk = nmask[b * 1024 + n];
    float t00 = tt[h * 4], t01 = tt[h * 4 + 1], t10 = tt[h * 4 + 2], t11 = tt[h * 4 + 3];
    float bA = L2E * (t00 + (t01 - t00) * tj) + (mk ? 0.f : -1e30f);
    float bB = L2E * ((t10 - t00) + (t11 - t01 - t10 + t00) * tj);
    size_t off = ((size_t)bh * 1024 + n) * 128 + 96;
    ushort8v z = {0, 0, 0, 0, 0, 0, 0, 0};
    ushort8v qv = z, kv = z;
    qv[0] = 0x3F80u;
    qv[1] = tj ? 0x3F80u : 0u;
    kv[0] = f2b(bA);
    kv[1] = f2b(bB);
    *(ushort8v*)&Qb[off] = qv;
    *(ushort8v*)&Qb[off + 8] = z;
    *(ushort8v*)&Qb[off + 16] = z;
    *(ushort8v*)&Qb[off + 24] = z;
    *(ushort8v*)&Kb[off] = kv;
    *(ushort8v*)&Kb[off + 8] = z;
    *(ushort8v*)&Kb[off + 16] = z;
    *(ushort8v*)&Kb[off + 24] = z;
}

// ---------------- 128x128 BK=64 2-phase GEMM: C = A[M][K] * Bt[N][K]^T + bias ----
// EPI: 0 = f32 out, 1 = bf16 out, 2 = gelu->bf16 out, 3 = qkv scatter
template <int EPI>
__global__ __launch_bounds__(256, 2) void gemm2p(
    const unsigned short* __restrict__ A, const unsigned short* __restrict__ Bt,
    const float* __restrict__ bias, float* __restrict__ outf,
    unsigned short* __restrict__ outb, unsigned short* __restrict__ q_o,
    unsigned short* __restrict__ k_o, unsigned short* __restrict__ v_o,
    int N, int K, int ntn, int NT) {
    __shared__ unsigned short a_lds[2][8192];
    __shared__ unsigned short b_lds[2][8192];
    const int tid = threadIdx.x;
    const int wave = tid >> 6, lane = tid & 63;
    const int lr = lane & 15, lg = lane >> 4;
    const int wm = wave >> 1, wn = wave & 1;
    const int nwg = gridDim.x;
    const int orig = blockIdx.x;
    const int swz = (orig & 7) * (nwg >> 3) + (orig >> 3);
    const int tm = swz / ntn, tn = swz % ntn;

    const unsigned short* srcA[4];
    const unsigned short* srcB[4];
#pragma unroll
    for (int i = 0; i < 4; ++i) {
        int g = i * 256 + tid;
        int row = g >> 3, sl = g & 7;
        int colg = sl ^ (row & 7);
        srcA[i] = A + (size_t)(tm * 128 + row) * K + colg * 8;
        srcB[i] = Bt + (size_t)(tn * 128 + row) * K + colg * 8;
    }
    auto stage = [&](int buf, int k0) {
#pragma unroll
        for (int i = 0; i < 4; ++i) {
            gload16(&a_lds[buf][i * 2048 + wave * 512], srcA[i] + k0);
            gload16(&b_lds[buf][i * 2048 + wave * 512], srcB[i] + k0);
        }
    };

    f32x4 acc[4][4] = {};

    stage(0, 0);
    asm volatile("s_waitcnt vmcnt(0)" ::: "memory");
    __builtin_amdgcn_s_barrier();

    for (int t = 0; t < NT; ++t) {
        const int buf = t & 1;
        if (t + 1 < NT) stage(buf ^ 1, (t + 1) * 64);
#pragma unroll
        for (int ks = 0; ks < 2; ++ks) {
            short8 af[4], bfr[4];
#pragma unroll
            for (int mf = 0; mf < 4; ++mf) {
                int row = wm * 64 + mf * 16 + lr;
                int slot = (ks * 4 + lg) ^ (row & 7);
                af[mf] = *(const short8*)&a_lds[buf][row * 64 + slot * 8];
            }
#pragma unroll
            for (int nf = 0; nf < 4; ++nf) {
                int row = wn * 64 + nf * 16 + lr;
                int slot = (ks * 4 + lg) ^ (row & 7);
                bfr[nf] = *(const short8*)&b_lds[buf][row * 64 + slot * 8];
            }
#pragma unroll
            for (int mf = 0; mf < 4; ++mf)
#pragma unroll
                for (int nf = 0; nf < 4; ++nf)
                    acc[mf][nf] = __builtin_amdgcn_mfma_f32_16x16x32_bf16(af[mf], bfr[nf], acc[mf][nf], 0, 0, 0);
        }
        asm volatile("s_waitcnt vmcnt(0)" ::: "memory");
        __builtin_amdgcn_s_barrier();
    }

#pragma unroll
    for (int mf = 0; mf < 4; ++mf) {
        int grb = tm * 128 + wm * 64 + mf * 16 + lg * 4;
#pragma unroll
        for (int nf = 0; nf < 4; ++nf) {
            int gc = tn * 128 + wn * 64 + nf * 16 + lr;
            float bv = bias[gc];
#pragma unroll
            for (int r = 0; r < 4; ++r) {
                int gr = grb + r;
                float v = acc[mf][nf][r] + bv;
                if constexpr (EPI == 0) {
                    outf[(size_t)gr * N + gc] = v;
                } else if constexpr (EPI == 1) {
                    outb[(size_t)gr * N + gc] = f2b(v);
                } else if constexpr (EPI == 2) {
                    float gl = 0.5f * v * (1.f + erff(v * 0.70710678f));
                    outb[(size_t)gr * N + gc] = f2b(gl);
                } else {
                    int part = gc / 768;
                    int cc = gc - part * 768;
                    int h = cc / 96, dh = cc - h * 96;
                    int b = gr >> 10, n2 = gr & 1023;
                    size_t bh = (size_t)(b * 8 + h);
                    if (part == 0) q_o[(bh * 1024 + n2) * 128 + dh] = f2b(v * 0.14724445f);
                    else if (part == 1) k_o[(bh * 1024 + n2) * 128 + dh] = f2b(v);
                    else v_o[(bh * 96 + dh) * 1024 + n2] = f2b(v);  // V transposed
                }
            }
        }
    }
}

// ---------------- flash attention (exact r6 version: 8 waves, dbuf, aug-K, exp2) ----------
__global__ __launch_bounds__(512, 4) void attn_kernel(
    const unsigned short* __restrict__ Qb, const unsigned short* __restrict__ Kb,
    const unsigned short* __restrict__ Vt, const float* __restrict__ centers,
    const float* __restrict__ rel_emb, unsigned short* __restrict__ Y) {
    __shared__ unsigned short kv_lds[2 * 14336];  // 56 KB
    __shared__ unsigned short p_lds[8 * 1024];    // 16 KB
    __shared__ float c_lds[1024];
    __shared__ float rel_lds[41];

    const int tid = threadIdx.x;
    const int wave = tid >> 6, lane = tid & 63;
    const int lr = lane & 15, lg = lane >> 4;
    const int bh = blockIdx.x, qb = blockIdx.y;
    const int b = bh >> 3, h = bh & 7;
    const int q0 = qb * 128 + wave * 16;
    const size_t kvbase = (size_t)bh * 1024 * 128;

    c_lds[tid] = centers[b * 1024 + tid];
    c_lds[tid + 512] = centers[b * 1024 + 512 + tid];
    if (tid < 41) rel_lds[tid] = rel_emb[tid * 8 + h] * L2E;

    const unsigned short* sbase[4];
    int sstep[4];
#pragma unroll
    for (int it = 0; it < 4; ++it) {
        int g = (it < 3) ? it * 512 + tid : 1536 + wave * 64 + lane;
        if (g < 1024) {  // K granule
            int ks = g >> 8, rem = g & 255, pr = rem >> 3, sl = rem & 7;
            int so = sl ^ (pr & 7);
            int r = ((so >> 2) << 5) + pr, oct = so & 3;
            sbase[it] = Kb + kvbase + (size_t)r * 128 + ks * 32 + oct * 8;
            sstep[it] = 64 * 128;
        } else {  // V granule
            int v = g - 1024, pr = v >> 3, sl = v & 7;
            int so = sl ^ (pr & 7);
            sbase[it] = Vt + (size_t)(bh * 96 + (pr < 96 ? pr : 95)) * 1024 + so * 8;
            sstep[it] = 64;
        }
    }
    auto stage = [&](int bufb, int kt) {
        unsigned short* dst = kv_lds + bufb * 14336;
#pragma unroll
        for (int it = 0; it < 3; ++it)
            gload16(dst + it * 4096 + wave * 512, sbase[it] + (size_t)kt * sstep[it]);
        if (tid < 256)
            gload16(dst + 3 * 4096 + wave * 512, sbase[3] + (size_t)kt * sstep[3]);
    };

    short8 qa[4];
#pragma unroll
    for (int ks = 0; ks < 4; ++ks)
        qa[ks] = *(const short8*)&Qb[kvbase + (size_t)(q0 + lr) * 128 + ks * 32 + lg * 8];
    float ci20[4];
#pragma unroll
    for (int r = 0; r < 4; ++r) ci20[r] = centers[b * 1024 + q0 + lg * 4 + r] + 20.f;

    short8 vone = {};
    if (lr == 0) {
#pragma unroll
        for (int e = 0; e < 8; ++e) vone[e] = (short)0x3F80;
    }

    float m_r[4] = {-3e30f, -3e30f, -3e30f, -3e30f};
    f32x4 oacc[7] = {};

    stage(0, 0);
    asm volatile("s_waitcnt lgkmcnt(0)" ::: "memory");

    for (int kt = 0; kt < 16; ++kt) {
        const int buf = kt & 1;
        if (kt < 15) {
            stage(buf ^ 1, kt + 1);
            asm volatile("s_waitcnt vmcnt(3)" ::: "memory");
        } else {
            asm volatile("s_waitcnt vmcnt(0)" ::: "memory");
        }
        __builtin_amdgcn_s_barrier();
        const unsigned short* kv = kv_lds + buf * 14336;

        f32x4 s[4] = {};
#pragma unroll
        for (int jf = 0; jf < 4; ++jf) {
            int pr = ((jf & 1) << 4) + lr;
            int slp = (((jf >> 1) << 2) + lg) ^ (lr & 7);
#pragma unroll
            for (int ks = 0; ks < 4; ++ks) {
                short8 kf = *(const short8*)&kv[ks * 2048 + pr * 64 + slp * 8];
                s[jf] = __builtin_amdgcn_mfma_f32_16x16x32_bf16(qa[ks], kf, s[jf], 0, 0, 0);
            }
        }

#pragma unroll
        for (int jf = 0; jf < 4; ++jf) {
            float cj = c_lds[kt * 64 + jf * 16 + lr];
#pragma unroll
            for (int r = 0; r < 4; ++r) {
                float idxf = __builtin_amdgcn_fmed3f(ci20[r] - cj, 0.f, 40.f);
                s[jf][r] += rel_lds[(int)rintf(idxf)];
            }
        }

#pragma unroll
        for (int r = 0; r < 4; ++r) {
            float mx = fmaxf(fmaxf(s[0][r], s[1][r]), fmaxf(s[2][r], s[3][r]));
#pragma unroll
            for (int off = 1; off < 16; off <<= 1) mx = fmaxf(mx, __shfl_xor(mx, off));
            if (!__all(mx <= m_r[r] + 8.f)) {
                float mn = fmaxf(m_r[r], mx);
                float al = exp2v(m_r[r] - mn);
                m_r[r] = mn;
#pragma unroll
                for (int nf = 0; nf < 7; ++nf) oacc[nf][r] *= al;
            }
#pragma unroll
            for (int jf = 0; jf < 4; ++jf) s[jf][r] = exp2v(s[jf][r] - m_r[r]);
        }

#pragma unroll
        for (int jf = 0; jf < 4; ++jf)
#pragma unroll
            for (int r = 0; r < 4; ++r) {
                int row = lg * 4 + r, col = jf * 16 + lr;
                int gp = (col >> 3) ^ (row & 7);
                p_lds[wave * 1024 + row * 64 + gp * 8 + (col & 7)] = f2b_trunc(s[jf][r]);
            }
        asm volatile("s_waitcnt lgkmcnt(0)" ::: "memory");
        short8 pa[2];
#pragma unroll
        for (int js = 0; js < 2; ++js) {
            int slp = ((js << 2) + lg) ^ (lr & 7);
            pa[js] = *(const short8*)&p_lds[wave * 1024 + lr * 64 + slp * 8];
        }

#pragma unroll
        for (int nf = 0; nf < 6; ++nf) {
            int vrow = nf * 16 + lr;
#pragma unroll
            for (int js = 0; js < 2; ++js) {
                int slp = ((js << 2) + lg) ^ (lr & 7);
                short8 vf = *(const short8*)&kv[8192 + vrow * 64 + slp * 8];
                oacc[nf] = __builtin_amdgcn_mfma_f32_16x16x32_bf16(pa[js], vf, oacc[nf], 0, 0, 0);
            }
        }
#pragma unroll
        for (int js = 0; js < 2; ++js)
            oacc[6] = __builtin_amdgcn_mfma_f32_16x16x32_bf16(pa[js], vone, oacc[6], 0, 0, 0);
        __builtin_amdgcn_s_barrier();
    }

#pragma unroll
    for (int r = 0; r < 4; ++r) {
        float l = __shfl(oacc[6][r], lane & 48);
        float inv = (l > 0.f) ? 1.f / l : 0.f;
        int qi = q0 + lg * 4 + r;
#pragma unroll
        for (int nf = 0; nf < 6; ++nf)
            Y[((size_t)b * 1024 + qi) * 768 + h * 96 + nf * 16 + lr] = f2b(oacc[nf][r] * inv);
    }
}

// ---------------- layernorm with residual add (vectorized, 2 rows/block) ----------------
template <bool IN1BF, bool IN2BF>
__global__ __launch_bounds__(384) void ln_kernel(const void* __restrict__ in1,
                                                 const void* __restrict__ in2,
                                                 const float* __restrict__ g,
                                                 const float* __restrict__ be,
                                                 float* __restrict__ of,
                                                 unsigned short* __restrict__ ob) {
    const int tid = threadIdx.x;
    const int half = tid / 192;       // waves 0-2 -> row0, waves 3-5 -> row1
    const int t = tid - half * 192;   // 0..191
    const int row = blockIdx.x * 2 + half;
    const size_t base = (size_t)row * 768 + t * 4;
    float a[4], bb[4];
    if (IN1BF) {
        ushort4 u = *(const ushort4*)((const unsigned short*)in1 + base);
        a[0] = b2f(u.x); a[1] = b2f(u.y); a[2] = b2f(u.z); a[3] = b2f(u.w);
    } else {
        float4 u = *(const float4*)((const float*)in1 + base);
        a[0] = u.x; a[1] = u.y; a[2] = u.z; a[3] = u.w;
    }
    if (IN2BF) {
        ushort4 u = *(const ushort4*)((const unsigned short*)in2 + base);
        bb[0] = b2f(u.x); bb[1] = b2f(u.y); bb[2] = b2f(u.z); bb[3] = b2f(u.w);
    } else {
        float4 u = *(const float4*)((const float*)in2 + base);
        bb[0] = u.x; bb[1] = u.y; bb[2] = u.z; bb[3] = u.w;
    }
    float v[4];
#pragma unroll
    for (int i = 0; i < 4; ++i) v[i] = a[i] + bb[i];
    float s1 = v[0] + v[1] + v[2] + v[3];
    float s2 = v[0] * v[0] + v[1] * v[1] + v[2] * v[2] + v[3] * v[3];
#pragma unroll
    for (int off = 32; off > 0; off >>= 1) {
        s1 += __shfl_xor(s1, off);
        s2 += __shfl_xor(s2, off);
    }
    __shared__ float red[12];
    const int wv = tid >> 6;  // 0..5
    if ((tid & 63) == 0) { red[wv] = s1; red[6 + wv] = s2; }
    __syncthreads();
    const int w0 = half * 3;
    s1 = red[w0] + red[w0 + 1] + red[w0 + 2];
    s2 = red[6 + w0] + red[6 + w0 + 1] + red[6 + w0 + 2];
    float mu = s1 * (1.f / 768.f);
    float var = s2 * (1.f / 768.f) - mu * mu;
    float inv = rsqrtf(var + 1e-5f);
    float o[4];
#pragma unroll
    for (int i = 0; i < 4; ++i)
        o[i] = (v[i] - mu) * inv * g[t * 4 + i] + be[t * 4 + i];
    if (of) {
        float4 w = {o[0], o[1], o[2], o[3]};
        *(float4*)(of + base) = w;
    }
    if (ob) {
        ushort4 w = {f2b(o[0]), f2b(o[1]), f2b(o[2]), f2b(o[3])};
        *(ushort4*)(ob + base) = w;
    }
}

extern "C" void kernel_launch(void* const* d_in, const int* in_sizes, int n_in,
                              void* d_out, int out_size, void* d_ws, size_t ws_size,
                              hipStream_t stream) {
    const float* x     = (const float*)d_in[0];
    const int*   nmask = (const int*)d_in[1];
    const float* cent  = (const float*)d_in[2];
    const int*   types = (const int*)d_in[3];
    const float* qkv_w = (const float*)d_in[4];
    const float* qkv_b = (const float*)d_in[5];
    const float* out_w = (const float*)d_in[6];
    const float* out_b = (const float*)d_in[7];
    const float* ff1_w = (const float*)d_in[8];
    const float* ff1_b = (const float*)d_in[9];
    const float* ff2_w = (const float*)d_in[10];
    const float* ff2_b = (const float*)d_in[11];
    const float* ln1_g = (const float*)d_in[12];
    const float* ln1_b = (const float*)d_in[13];
    const float* ln2_g = (const float*)d_in[14];
    const float* ln2_b = (const float*)d_in[15];
    const float* rel   = (const float*)d_in[16];
    const float* ttp   = (const float*)d_in[17];

    char* w = (char*)d_ws;
    auto alloc = [&](size_t bytes) {
        char* p = w;
        w += (bytes + 255) & ~(size_t)255;
        return p;
    };
    unsigned short* xb  = (unsigned short*)alloc(8192ull * 768 * 2);   // x bf16; reused as Y
    unsigned short* qwT = (unsigned short*)alloc(2304ull * 768 * 2);
    unsigned short* owT = (unsigned short*)alloc(768ull * 768 * 2);
    unsigned short* f1T = (unsigned short*)alloc(1024ull * 768 * 2);
    unsigned short* f2T = (unsigned short*)alloc(768ull * 1024 * 2);
    unsigned short* Qb  = (unsigned short*)alloc(64ull * 1024 * 128 * 2);
    unsigned short* Kb  = (unsigned short*)alloc(64ull * 1024 * 128 * 2);
    unsigned short* Vt  = (unsigned short*)alloc(64ull * 96 * 1024 * 2);
    unsigned short* aob = (unsigned short*)alloc(8192ull * 768 * 2);  // residual branch (bf16)
    unsigned short* h1b = (unsigned short*)alloc(8192ull * 768 * 2);
    unsigned short* ffa = Qb;  // alias: Qb dead after attn

    cvt_x_kernel<<<6144, 256, 0, stream>>>(x, xb, 8192 * 768 / 4);
    transpose_w<<<dim3(2304 / 32, 768 / 32), 256, 0, stream>>>(qkv_w, qwT, 768, 2304);
    transpose_w<<<dim3(768 / 32, 768 / 32), 256, 0, stream>>>(out_w, owT, 768, 768);
    transpose_w<<<dim3(1024 / 32, 768 / 32), 256, 0, stream>>>(ff1_w, f1T, 768, 1024);
    transpose_w<<<dim3(768 / 32, 1024 / 32), 256, 0, stream>>>(ff2_w, f2T, 1024, 768);

    // QKV: M=8192 N=2304 K=768 -> 64x18 = 1152 blocks
    gemm2p<3><<<1152, 256, 0, stream>>>(xb, qwT, qkv_b, nullptr, nullptr,
                                        Qb, Kb, Vt, 2304, 768, 18, 12);
    aug_qk<<<256, 256, 0, stream>>>(types, nmask, ttp, Qb, Kb);
    attn_kernel<<<dim3(64, 8), 512, 0, stream>>>(Qb, Kb, Vt, cent, rel, xb);
    // out proj: N=768 K=768 -> 384 blocks, bf16 out
    gemm2p<1><<<384, 256, 0, stream>>>(xb, owT, out_b, nullptr, aob,
                                       nullptr, nullptr, nullptr, 768, 768, 6, 12);
    ln_kernel<false, true><<<4096, 384, 0, stream>>>(x, aob, ln1_g, ln1_b, nullptr, h1b);
    // ff1+gelu: N=1024 K=768 -> 512 blocks
    gemm2p<2><<<512, 256, 0, stream>>>(h1b, f1T, ff1_b, nullptr, ffa,
                                       nullptr, nullptr, nullptr, 1024, 768, 8, 12);
    // ff2: N=768 K=1024 -> 384 blocks, NT=16, bf16 out (reuse aob)
    gemm2p<1><<<384, 256, 0, stream>>>(ffa, f2T, ff2_b, nullptr, aob,
                                       nullptr, nullptr, nullptr, 768, 1024, 6, 16);
    ln_kernel<true, true><<<4096, 384, 0, stream>>>(h1b, aob, ln2_g, ln2_b, (float*)d_out, nullptr);
}

// Round 9
// 214.080 us; speedup vs baseline: 1.1329x; 1.0785x over previous
//
#include <hip/hip_runtime.h>

typedef short short8 __attribute__((ext_vector_type(8)));
typedef unsigned short ushort8v __attribute__((ext_vector_type(8)));
typedef float f32x4 __attribute__((ext_vector_type(4)));

static __device__ __forceinline__ unsigned short f2b(float f) {
    unsigned int u = __builtin_bit_cast(unsigned int, f);
    unsigned int r = (u + 0x7fffu + ((u >> 16) & 1u)) >> 16;
    return (unsigned short)r;
}
static __device__ __forceinline__ unsigned short f2b_trunc(float f) {
    return (unsigned short)(__builtin_bit_cast(unsigned int, f) >> 16);
}
static __device__ __forceinline__ float b2f(unsigned short u) {
    return __builtin_bit_cast(float, (unsigned int)u << 16);
}
static __device__ __forceinline__ float exp2v(float x) {
    float r;
    asm("v_exp_f32 %0, %1" : "=v"(r) : "v"(x));
    return r;
}

__device__ __forceinline__ void gload16(void* lds, const void* g) {
    __builtin_amdgcn_global_load_lds(
        (const __attribute__((address_space(1))) void*)g,
        (__attribute__((address_space(3))) void*)lds, 16, 0, 0);
}

#define L2E 1.4426950408889634f

// ---------------- convert x (f32 -> bf16) ----------------
__global__ __launch_bounds__(256) void cvt_x_kernel(const float* __restrict__ x,
                                                    unsigned short* __restrict__ o, int n4) {
    int i = blockIdx.x * 256 + threadIdx.x;
    float4 f = ((const float4*)x)[i];
    ushort4 u;
    u.x = f2b(f.x); u.y = f2b(f.y); u.z = f2b(f.z); u.w = f2b(f.w);
    ((ushort4*)o)[i] = u;
}

// ---------------- transpose weight W[K][N] f32 -> Wt[N][K] bf16 ----------------
__global__ __launch_bounds__(256) void transpose_w(const float* __restrict__ W,
                                                   unsigned short* __restrict__ Wt,
                                                   int K, int N) {
    __shared__ float t[32][33];
    int kb = blockIdx.y << 5, nb = blockIdx.x << 5;
    int tx = threadIdx.x & 31, ty = threadIdx.x >> 5;  // 32 x 8
#pragma unroll
    for (int i = 0; i < 32; i += 8)
        t[ty + i][tx] = W[(size_t)(kb + ty + i) * N + nb + tx];
    __syncthreads();
#pragma unroll
    for (int i = 0; i < 32; i += 8)
        Wt[(size_t)(nb + ty + i) * K + kb + tx] = f2b(t[tx][ty + i]);
}

// ---------------- aug columns for Q/K (type+mask bias folded into MFMA) ----------------
__global__ __launch_bounds__(256) void aug_qk(const int* __restrict__ types,
                                              const int* __restrict__ nmask,
                                              const float* __restrict__ tt,
                                              unsigned short* __restrict__ Qb,
                                              unsigned short* __restrict__ Kb) {
    int t = blockIdx.x * 256 + threadIdx.x;  // 65536 threads
    int bh = t >> 10, n = t & 1023;
    int b = bh >> 3, h = bh & 7;
    int tj = types[b * 1024 + n];
    int mk = nmask[b * 1024 + n];
    float t00 = tt[h * 4], t01 = tt[h * 4 + 1], t10 = tt[h * 4 + 2], t11 = tt[h * 4 + 3];
    float bA = L2E * (t00 + (t01 - t00) * tj) + (mk ? 0.f : -1e30f);
    float bB = L2E * ((t10 - t00) + (t11 - t01 - t10 + t00) * tj);
    size_t off = ((size_t)bh * 1024 + n) * 128 + 96;
    ushort8v z = {0, 0, 0, 0, 0, 0, 0, 0};
    ushort8v qv = z, kv = z;
    qv[0] = 0x3F80u;
    qv[1] = tj ? 0x3F80u : 0u;
    kv[0] = f2b(bA);
    kv[1] = f2b(bB);
    *(ushort8v*)&Qb[off] = qv;
    *(ushort8v*)&Qb[off + 8] = z;
    *(ushort8v*)&Qb[off + 16] = z;
    *(ushort8v*)&Qb[off + 24] = z;
    *(ushort8v*)&Kb[off] = kv;
    *(ushort8v*)&Kb[off + 8] = z;
    *(ushort8v*)&Kb[off + 16] = z;
    *(ushort8v*)&Kb[off + 24] = z;
}

// ---------------- 128x128 BK=64 2-phase GEMM, 8 waves (64x32 per wave) ----------------
// EPI: 0 = f32 out, 1 = bf16 out, 2 = gelu->bf16 out, 3 = qkv scatter
// Double-buffered 64KiB LDS [buf][128 row][8 slot^(row&7)][8 shorts]; stage(t+1) issued
// before compute(t); one vmcnt(0)+barrier per K-step. 512 thr -> 2 blk/CU = 4 waves/SIMD.
template <int EPI>
__global__ __launch_bounds__(512, 4) void gemm2p(
    const unsigned short* __restrict__ A, const unsigned short* __restrict__ Bt,
    const float* __restrict__ bias, float* __restrict__ outf,
    unsigned short* __restrict__ outb, unsigned short* __restrict__ q_o,
    unsigned short* __restrict__ k_o, unsigned short* __restrict__ v_o,
    int N, int K, int ntn, int NT) {
    __shared__ unsigned short a_lds[2][8192];
    __shared__ unsigned short b_lds[2][8192];
    const int tid = threadIdx.x;
    const int wave = tid >> 6, lane = tid & 63;
    const int lr = lane & 15, lg = lane >> 4;
    const int wm = wave >> 2, wn = wave & 3;  // 2 x 4 wave grid: 64-row x 32-col tiles
    const int nwg = gridDim.x;
    const int orig = blockIdx.x;
    const int swz = (orig & 7) * (nwg >> 3) + (orig >> 3);
    const int tm = swz / ntn, tn = swz % ntn;

    // staging: granule g = i*512+tid -> row=g>>3, sl=g&7, src col-granule = sl^(row&7)
    const unsigned short* srcA[2];
    const unsigned short* srcB[2];
#pragma unroll
    for (int i = 0; i < 2; ++i) {
        int g = i * 512 + tid;
        int row = g >> 3, sl = g & 7;
        int colg = sl ^ (row & 7);
        srcA[i] = A + (size_t)(tm * 128 + row) * K + colg * 8;
        srcB[i] = Bt + (size_t)(tn * 128 + row) * K + colg * 8;
    }
    auto stage = [&](int buf, int k0) {
#pragma unroll
        for (int i = 0; i < 2; ++i) {
            gload16(&a_lds[buf][i * 4096 + wave * 512], srcA[i] + k0);
            gload16(&b_lds[buf][i * 4096 + wave * 512], srcB[i] + k0);
        }
    };

    f32x4 acc[4][2] = {};

    stage(0, 0);
    asm volatile("s_waitcnt vmcnt(0)" ::: "memory");
    __builtin_amdgcn_s_barrier();

    for (int t = 0; t < NT; ++t) {
        const int buf = t & 1;
        if (t + 1 < NT) stage(buf ^ 1, (t + 1) * 64);
#pragma unroll
        for (int ks = 0; ks < 2; ++ks) {
            short8 af[4], bfr[2];
#pragma unroll
            for (int mf = 0; mf < 4; ++mf) {
                int row = wm * 64 + mf * 16 + lr;
                int slot = (ks * 4 + lg) ^ (row & 7);
                af[mf] = *(const short8*)&a_lds[buf][row * 64 + slot * 8];
            }
#pragma unroll
            for (int nf = 0; nf < 2; ++nf) {
                int row = wn * 32 + nf * 16 + lr;
                int slot = (ks * 4 + lg) ^ (row & 7);
                bfr[nf] = *(const short8*)&b_lds[buf][row * 64 + slot * 8];
            }
#pragma unroll
            for (int mf = 0; mf < 4; ++mf)
#pragma unroll
                for (int nf = 0; nf < 2; ++nf)
                    acc[mf][nf] = __builtin_amdgcn_mfma_f32_16x16x32_bf16(af[mf], bfr[nf], acc[mf][nf], 0, 0, 0);
        }
        asm volatile("s_waitcnt vmcnt(0)" ::: "memory");
        __builtin_amdgcn_s_barrier();
    }

#pragma unroll
    for (int nf = 0; nf < 2; ++nf) {
        int gc = tn * 128 + wn * 32 + nf * 16 + lr;
        float bv = bias[gc];
        int part = 0, h = 0, dh = 0;
        if constexpr (EPI == 3) {
            part = gc / 768;               // hoisted: once per nf, not per element
            int cc = gc - part * 768;
            h = cc / 96;
            dh = cc - h * 96;
        }
#pragma unroll
        for (int mf = 0; mf < 4; ++mf) {
            int grb = tm * 128 + wm * 64 + mf * 16 + lg * 4;
            if constexpr (EPI == 3) {
                int b = grb >> 10, n2 = grb & 1023;  // 4 rows never cross batch boundary
                size_t bh = (size_t)(b * 8 + h);
                if (part == 2) {
                    ushort4 wv;
                    wv.x = f2b(acc[mf][nf][0] + bv);
                    wv.y = f2b(acc[mf][nf][1] + bv);
                    wv.z = f2b(acc[mf][nf][2] + bv);
                    wv.w = f2b(acc[mf][nf][3] + bv);
                    *(ushort4*)&v_o[(bh * 96 + dh) * 1024 + n2] = wv;  // V transposed, contiguous
                } else {
                    unsigned short* dst = (part == 0) ? q_o : k_o;
                    float sc = (part == 0) ? 0.14724445f : 1.f;
#pragma unroll
                    for (int r = 0; r < 4; ++r)
                        dst[(bh * 1024 + n2 + r) * 128 + dh] = f2b((acc[mf][nf][r] + bv) * sc);
                }
            } else {
#pragma unroll
                for (int r = 0; r < 4; ++r) {
                    int gr = grb + r;
                    float v = acc[mf][nf][r] + bv;
                    if constexpr (EPI == 0) {
                        outf[(size_t)gr * N + gc] = v;
                    } else if constexpr (EPI == 1) {
                        outb[(size_t)gr * N + gc] = f2b(v);
                    } else {
                        float gl = 0.5f * v * (1.f + erff(v * 0.70710678f));
                        outb[(size_t)gr * N + gc] = f2b(gl);
                    }
                }
            }
        }
    }
}

// ---------------- flash attention (exact r6/r8 version: 8 waves, dbuf, aug-K, exp2) -------
__global__ __launch_bounds__(512, 4) void attn_kernel(
    const unsigned short* __restrict__ Qb, const unsigned short* __restrict__ Kb,
    const unsigned short* __restrict__ Vt, const float* __restrict__ centers,
    const float* __restrict__ rel_emb, unsigned short* __restrict__ Y) {
    __shared__ unsigned short kv_lds[2 * 14336];  // 56 KB
    __shared__ unsigned short p_lds[8 * 1024];    // 16 KB
    __shared__ float c_lds[1024];
    __shared__ float rel_lds[41];

    const int tid = threadIdx.x;
    const int wave = tid >> 6, lane = tid & 63;
    const int lr = lane & 15, lg = lane >> 4;
    const int bh = blockIdx.x, qb = blockIdx.y;
    const int b = bh >> 3, h = bh & 7;
    const int q0 = qb * 128 + wave * 16;
    const size_t kvbase = (size_t)bh * 1024 * 128;

    c_lds[tid] = centers[b * 1024 + tid];
    c_lds[tid + 512] = centers[b * 1024 + 512 + tid];
    if (tid < 41) rel_lds[tid] = rel_emb[tid * 8 + h] * L2E;

    const unsigned short* sbase[4];
    int sstep[4];
#pragma unroll
    for (int it = 0; it < 4; ++it) {
        int g = (it < 3) ? it * 512 + tid : 1536 + wave * 64 + lane;
        if (g < 1024) {  // K granule
            int ks = g >> 8, rem = g & 255, pr = rem >> 3, sl = rem & 7;
            int so = sl ^ (pr & 7);
            int r = ((so >> 2) << 5) + pr, oct = so & 3;
            sbase[it] = Kb + kvbase + (size_t)r * 128 + ks * 32 + oct * 8;
            sstep[it] = 64 * 128;
        } else {  // V granule
            int v = g - 1024, pr = v >> 3, sl = v & 7;
            int so = sl ^ (pr & 7);
            sbase[it] = Vt + (size_t)(bh * 96 + (pr < 96 ? pr : 95)) * 1024 + so * 8;
            sstep[it] = 64;
        }
    }
    auto stage = [&](int bufb, int kt) {
        unsigned short* dst = kv_lds + bufb * 14336;
#pragma unroll
        for (int it = 0; it < 3; ++it)
            gload16(dst + it * 4096 + wave * 512, sbase[it] + (size_t)kt * sstep[it]);
        if (tid < 256)
            gload16(dst + 3 * 4096 + wave * 512, sbase[3] + (size_t)kt * sstep[3]);
    };

    short8 qa[4];
#pragma unroll
    for (int ks = 0; ks < 4; ++ks)
        qa[ks] = *(const short8*)&Qb[kvbase + (size_t)(q0 + lr) * 128 + ks * 32 + lg * 8];
    float ci20[4];
#pragma unroll
    for (int r = 0; r < 4; ++r) ci20[r] = centers[b * 1024 + q0 + lg * 4 + r] + 20.f;

    short8 vone = {};
    if (lr == 0) {
#pragma unroll
        for (int e = 0; e < 8; ++e) vone[e] = (short)0x3F80;
    }

    float m_r[4] = {-3e30f, -3e30f, -3e30f, -3e30f};
    f32x4 oacc[7] = {};

    stage(0, 0);
    asm volatile("s_waitcnt lgkmcnt(0)" ::: "memory");

    for (int kt = 0; kt < 16; ++kt) {
        const int buf = kt & 1;
        if (kt < 15) {
            stage(buf ^ 1, kt + 1);
            asm volatile("s_waitcnt vmcnt(3)" ::: "memory");
        } else {
            asm volatile("s_waitcnt vmcnt(0)" ::: "memory");
        }
        __builtin_amdgcn_s_barrier();
        const unsigned short* kv = kv_lds + buf * 14336;

        f32x4 s[4] = {};
#pragma unroll
        for (int jf = 0; jf < 4; ++jf) {
            int pr = ((jf & 1) << 4) + lr;
            int slp = (((jf >> 1) << 2) + lg) ^ (lr & 7);
#pragma unroll
            for (int ks = 0; ks < 4; ++ks) {
                short8 kf = *(const short8*)&kv[ks * 2048 + pr * 64 + slp * 8];
                s[jf] = __builtin_amdgcn_mfma_f32_16x16x32_bf16(qa[ks], kf, s[jf], 0, 0, 0);
            }
        }

#pragma unroll
        for (int jf = 0; jf < 4; ++jf) {
            float cj = c_lds[kt * 64 + jf * 16 + lr];
#pragma unroll
            for (int r = 0; r < 4; ++r) {
                float idxf = __builtin_amdgcn_fmed3f(ci20[r] - cj, 0.f, 40.f);
                s[jf][r] += rel_lds[(int)rintf(idxf)];
            }
        }

#pragma unroll
        for (int r = 0; r < 4; ++r) {
            float mx = fmaxf(fmaxf(s[0][r], s[1][r]), fmaxf(s[2][r], s[3][r]));
#pragma unroll
            for (int off = 1; off < 16; off <<= 1) mx = fmaxf(mx, __shfl_xor(mx, off));
            if (!__all(mx <= m_r[r] + 8.f)) {
                float mn = fmaxf(m_r[r], mx);
                float al = exp2v(m_r[r] - mn);
                m_r[r] = mn;
#pragma unroll
                for (int nf = 0; nf < 7; ++nf) oacc[nf][r] *= al;
            }
#pragma unroll
            for (int jf = 0; jf < 4; ++jf) s[jf][r] = exp2v(s[jf][r] - m_r[r]);
        }

#pragma unroll
        for (int jf = 0; jf < 4; ++jf)
#pragma unroll
            for (int r = 0; r < 4; ++r) {
                int row = lg * 4 + r, col = jf * 16 + lr;
                int gp = (col >> 3) ^ (row & 7);
                p_lds[wave * 1024 + row * 64 + gp * 8 + (col & 7)] = f2b_trunc(s[jf][r]);
            }
        asm volatile("s_waitcnt lgkmcnt(0)" ::: "memory");
        short8 pa[2];
#pragma unroll
        for (int js = 0; js < 2; ++js) {
            int slp = ((js << 2) + lg) ^ (lr & 7);
            pa[js] = *(const short8*)&p_lds[wave * 1024 + lr * 64 + slp * 8];
        }

#pragma unroll
        for (int nf = 0; nf < 6; ++nf) {
            int vrow = nf * 16 + lr;
#pragma unroll
            for (int js = 0; js < 2; ++js) {
                int slp = ((js << 2) + lg) ^ (lr & 7);
                short8 vf = *(const short8*)&kv[8192 + vrow * 64 + slp * 8];
                oacc[nf] = __builtin_amdgcn_mfma_f32_16x16x32_bf16(pa[js], vf, oacc[nf], 0, 0, 0);
            }
        }
#pragma unroll
        for (int js = 0; js < 2; ++js)
            oacc[6] = __builtin_amdgcn_mfma_f32_16x16x32_bf16(pa[js], vone, oacc[6], 0, 0, 0);
        __builtin_amdgcn_s_barrier();
    }

#pragma unroll
    for (int r = 0; r < 4; ++r) {
        float l = __shfl(oacc[6][r], lane & 48);
        float inv = (l > 0.f) ? 1.f / l : 0.f;
        int qi = q0 + lg * 4 + r;
#pragma unroll
        for (int nf = 0; nf < 6; ++nf)
            Y[((size_t)b * 1024 + qi) * 768 + h * 96 + nf * 16 + lr] = f2b(oacc[nf][r] * inv);
    }
}

// ---------------- layernorm with residual add (vectorized, 2 rows/block) ----------------
template <bool IN1BF, bool IN2BF>
__global__ __launch_bounds__(384) void ln_kernel(const void* __restrict__ in1,
                                                 const void* __restrict__ in2,
                                                 const float* __restrict__ g,
                                                 const float* __restrict__ be,
                                                 float* __restrict__ of,
                                                 unsigned short* __restrict__ ob) {
    const int tid = threadIdx.x;
    const int half = tid / 192;       // waves 0-2 -> row0, waves 3-5 -> row1
    const int t = tid - half * 192;   // 0..191
    const int row = blockIdx.x * 2 + half;
    const size_t base = (size_t)row * 768 + t * 4;
    float a[4], bb[4];
    if (IN1BF) {
        ushort4 u = *(const ushort4*)((const unsigned short*)in1 + base);
        a[0] = b2f(u.x); a[1] = b2f(u.y); a[2] = b2f(u.z); a[3] = b2f(u.w);
    } else {
        float4 u = *(const float4*)((const float*)in1 + base);
        a[0] = u.x; a[1] = u.y; a[2] = u.z; a[3] = u.w;
    }
    if (IN2BF) {
        ushort4 u = *(const ushort4*)((const unsigned short*)in2 + base);
        bb[0] = b2f(u.x); bb[1] = b2f(u.y); bb[2] = b2f(u.z); bb[3] = b2f(u.w);
    } else {
        float4 u = *(const float4*)((const float*)in2 + base);
        bb[0] = u.x; bb[1] = u.y; bb[2] = u.z; bb[3] = u.w;
    }
    float v[4];
#pragma unroll
    for (int i = 0; i < 4; ++i) v[i] = a[i] + bb[i];
    float s1 = v[0] + v[1] + v[2] + v[3];
    float s2 = v[0] * v[0] + v[1] * v[1] + v[2] * v[2] + v[3] * v[3];
#pragma unroll
    for (int off = 32; off > 0; off >>= 1) {
        s1 += __shfl_xor(s1, off);
        s2 += __shfl_xor(s2, off);
    }
    __shared__ float red[12];
    const int wv = tid >> 6;  // 0..5
    if ((tid & 63) == 0) { red[wv] = s1; red[6 + wv] = s2; }
    __syncthreads();
    const int w0 = half * 3;
    s1 = red[w0] + red[w0 + 1] + red[w0 + 2];
    s2 = red[6 + w0] + red[6 + w0 + 1] + red[6 + w0 + 2];
    float mu = s1 * (1.f / 768.f);
    float var = s2 * (1.f / 768.f) - mu * mu;
    float inv = rsqrtf(var + 1e-5f);
    float o[4];
#pragma unroll
    for (int i = 0; i < 4; ++i)
        o[i] = (v[i] - mu) * inv * g[t * 4 + i] + be[t * 4 + i];
    if (of) {
        float4 w = {o[0], o[1], o[2], o[3]};
        *(float4*)(of + base) = w;
    }
    if (ob) {
        ushort4 w = {f2b(o[0]), f2b(o[1]), f2b(o[2]), f2b(o[3])};
        *(ushort4*)(ob + base) = w;
    }
}

extern "C" void kernel_launch(void* const* d_in, const int* in_sizes, int n_in,
                              void* d_out, int out_size, void* d_ws, size_t ws_size,
                              hipStream_t stream) {
    const float* x     = (const float*)d_in[0];
    const int*   nmask = (const int*)d_in[1];
    const float* cent  = (const float*)d_in[2];
    const int*   types = (const int*)d_in[3];
    const float* qkv_w = (const float*)d_in[4];
    const float* qkv_b = (const float*)d_in[5];
    const float* out_w = (const float*)d_in[6];
    const float* out_b = (const float*)d_in[7];
    const float* ff1_w = (const float*)d_in[8];
    const float* ff1_b = (const float*)d_in[9];
    const float* ff2_w = (const float*)d_in[10];
    const float* ff2_b = (const float*)d_in[11];
    const float* ln1_g = (const float*)d_in[12];
    const float* ln1_b = (const float*)d_in[13];
    const float* ln2_g = (const float*)d_in[14];
    const float* ln2_b = (const float*)d_in[15];
    const float* rel   = (const float*)d_in[16];
    const float* ttp   = (const float*)d_in[17];

    char* w = (char*)d_ws;
    auto alloc = [&](size_t bytes) {
        char* p = w;
        w += (bytes + 255) & ~(size_t)255;
        return p;
    };
    unsigned short* xb  = (unsigned short*)alloc(8192ull * 768 * 2);   // x bf16; reused as Y
    unsigned short* qwT = (unsigned short*)alloc(2304ull * 768 * 2);
    unsigned short* owT = (unsigned short*)alloc(768ull * 768 * 2);
    unsigned short* f1T = (unsigned short*)alloc(1024ull * 768 * 2);
    unsigned short* f2T = (unsigned short*)alloc(768ull * 1024 * 2);
    unsigned short* Qb  = (unsigned short*)alloc(64ull * 1024 * 128 * 2);
    unsigned short* Kb  = (unsigned short*)alloc(64ull * 1024 * 128 * 2);
    unsigned short* Vt  = (unsigned short*)alloc(64ull * 96 * 1024 * 2);
    unsigned short* aob = (unsigned short*)alloc(8192ull * 768 * 2);  // residual branch (bf16)
    unsigned short* h1b = (unsigned short*)alloc(8192ull * 768 * 2);
    unsigned short* ffa = Qb;  // alias: Qb dead after attn

    cvt_x_kernel<<<6144, 256, 0, stream>>>(x, xb, 8192 * 768 / 4);
    transpose_w<<<dim3(2304 / 32, 768 / 32), 256, 0, stream>>>(qkv_w, qwT, 768, 2304);
    transpose_w<<<dim3(768 / 32, 768 / 32), 256, 0, stream>>>(out_w, owT, 768, 768);
    transpose_w<<<dim3(1024 / 32, 768 / 32), 256, 0, stream>>>(ff1_w, f1T, 768, 1024);
    transpose_w<<<dim3(768 / 32, 1024 / 32), 256, 0, stream>>>(ff2_w, f2T, 1024, 768);

    // QKV: M=8192 N=2304 K=768 -> 64x18 = 1152 blocks
    gemm2p<3><<<1152, 512, 0, stream>>>(xb, qwT, qkv_b, nullptr, nullptr,
                                        Qb, Kb, Vt, 2304, 768, 18, 12);
    aug_qk<<<256, 256, 0, stream>>>(types, nmask, ttp, Qb, Kb);
    attn_kernel<<<dim3(64, 8), 512, 0, stream>>>(Qb, Kb, Vt, cent, rel, xb);
    // out proj: N=768 K=768 -> 384 blocks, bf16 out
    gemm2p<1><<<384, 512, 0, stream>>>(xb, owT, out_b, nullptr, aob,
                                       nullptr, nullptr, nullptr, 768, 768, 6, 12);
    ln_kernel<false, true><<<4096, 384, 0, stream>>>(x, aob, ln1_g, ln1_b, nullptr, h1b);
    // ff1+gelu: N=1024 K=768 -> 512 blocks
    gemm2p<2><<<512, 512, 0, stream>>>(h1b, f1T, ff1_b, nullptr, ffa,
                                       nullptr, nullptr, nullptr, 1024, 768, 8, 12);
    // ff2: N=768 K=1024 -> 384 blocks, NT=16, bf16 out (reuse aob)
    gemm2p<1><<<384, 512, 0, stream>>>(ffa, f2T, ff2_b, nullptr, aob,
                                       nullptr, nullptr, nullptr, 768, 1024, 6, 16);
    ln_kernel<true, true><<<4096, 384, 0, stream>>>(h1b, aob, ln2_g, ln2_b, (float*)d_out, nullptr);
}

// Round 10
// 211.014 us; speedup vs baseline: 1.1494x; 1.0145x over previous
//
#include <hip/hip_runtime.h>

typedef short short8 __attribute__((ext_vector_type(8)));
typedef unsigned short ushort8v __attribute__((ext_vector_type(8)));
typedef float f32x4 __attribute__((ext_vector_type(4)));

static __device__ __forceinline__ unsigned short f2b(float f) {
    unsigned int u = __builtin_bit_cast(unsigned int, f);
    unsigned int r = (u + 0x7fffu + ((u >> 16) & 1u)) >> 16;
    return (unsigned short)r;
}
static __device__ __forceinline__ unsigned short f2b_trunc(float f) {
    return (unsigned short)(__builtin_bit_cast(unsigned int, f) >> 16);
}
static __device__ __forceinline__ float b2f(unsigned short u) {
    return __builtin_bit_cast(float, (unsigned int)u << 16);
}
static __device__ __forceinline__ float exp2v(float x) {
    float r;
    asm("v_exp_f32 %0, %1" : "=v"(r) : "v"(x));
    return r;
}

__device__ __forceinline__ void gload16(void* lds, const void* g) {
    __builtin_amdgcn_global_load_lds(
        (const __attribute__((address_space(1))) void*)g,
        (__attribute__((address_space(3))) void*)lds, 16, 0, 0);
}

#define L2E 1.4426950408889634f

// ---------------- fused prep: cvt x (f32->bf16) + 4 weight transposes ----------------
__global__ __launch_bounds__(256) void prep_kernel(
    const float* __restrict__ x, unsigned short* __restrict__ xb,
    const float* __restrict__ qkv_w, unsigned short* __restrict__ qwT,
    const float* __restrict__ out_w, unsigned short* __restrict__ owT,
    const float* __restrict__ ff1_w, unsigned short* __restrict__ f1T,
    const float* __restrict__ ff2_w, unsigned short* __restrict__ f2T) {
    const int bx = blockIdx.x;
    const int tid = threadIdx.x;
    if (bx < 6144) {  // cvt x: 6144 blocks x 256 thr x float4
        int i = bx * 256 + tid;
        float4 f = ((const float4*)x)[i];
        ushort4 u;
        u.x = f2b(f.x); u.y = f2b(f.y); u.z = f2b(f.z); u.w = f2b(f.w);
        ((ushort4*)xb)[i] = u;
        return;
    }
    __shared__ float t[32][33];
    int rb = bx - 6144;
    const float* W; unsigned short* Wt; int K, N;
    if (rb < 1728)      { W = qkv_w; Wt = qwT; K = 768;  N = 2304; }
    else if (rb < 2304) { rb -= 1728; W = out_w; Wt = owT; K = 768;  N = 768; }
    else if (rb < 3072) { rb -= 2304; W = ff1_w; Wt = f1T; K = 768;  N = 1024; }
    else                { rb -= 3072; W = ff2_w; Wt = f2T; K = 1024; N = 768; }
    const int nbl = N / 32;
    const int nb = (rb % nbl) * 32, kb = (rb / nbl) * 32;
    const int tx = tid & 31, ty = tid >> 5;  // 32 x 8
#pragma unroll
    for (int i = 0; i < 32; i += 8)
        t[ty + i][tx] = W[(size_t)(kb + ty + i) * N + nb + tx];
    __syncthreads();
#pragma unroll
    for (int i = 0; i < 32; i += 8)
        Wt[(size_t)(nb + ty + i) * K + kb + tx] = f2b(t[tx][ty + i]);
}

// ---------------- aug columns for Q/K (type+mask bias folded into MFMA) ----------------
__global__ __launch_bounds__(256) void aug_qk(const int* __restrict__ types,
                                              const int* __restrict__ nmask,
                                              const float* __restrict__ tt,
                                              unsigned short* __restrict__ Qb,
                                              unsigned short* __restrict__ Kb) {
    int t = blockIdx.x * 256 + threadIdx.x;  // 65536 threads
    int bh = t >> 10, n = t & 1023;
    int b = bh >> 3, h = bh & 7;
    int tj = types[b * 1024 + n];
    int mk = nmask[b * 1024 + n];
    float t00 = tt[h * 4], t01 = tt[h * 4 + 1], t10 = tt[h * 4 + 2], t11 = tt[h * 4 + 3];
    float bA = L2E * (t00 + (t01 - t00) * tj) + (mk ? 0.f : -1e30f);
    float bB = L2E * ((t10 - t00) + (t11 - t01 - t10 + t00) * tj);
    size_t off = ((size_t)bh * 1024 + n) * 128 + 96;
    ushort8v z = {0, 0, 0, 0, 0, 0, 0, 0};
    ushort8v qv = z, kv = z;
    qv[0] = 0x3F80u;
    qv[1] = tj ? 0x3F80u : 0u;
    kv[0] = f2b(bA);
    kv[1] = f2b(bB);
    *(ushort8v*)&Qb[off] = qv;
    *(ushort8v*)&Qb[off + 8] = z;
    *(ushort8v*)&Qb[off + 16] = z;
    *(ushort8v*)&Qb[off + 24] = z;
    *(ushort8v*)&Kb[off] = kv;
    *(ushort8v*)&Kb[off + 8] = z;
    *(ushort8v*)&Kb[off + 16] = z;
    *(ushort8v*)&Kb[off + 24] = z;
}

// ---------------- 128x128 BK=64 2-phase GEMM, 8 waves (64x32 per wave) ----------------
template <int EPI>
__global__ __launch_bounds__(512, 4) void gemm2p(
    const unsigned short* __restrict__ A, const unsigned short* __restrict__ Bt,
    const float* __restrict__ bias, float* __restrict__ outf,
    unsigned short* __restrict__ outb, unsigned short* __restrict__ q_o,
    unsigned short* __restrict__ k_o, unsigned short* __restrict__ v_o,
    int N, int K, int ntn, int NT) {
    __shared__ unsigned short a_lds[2][8192];
    __shared__ unsigned short b_lds[2][8192];
    const int tid = threadIdx.x;
    const int wave = tid >> 6, lane = tid & 63;
    const int lr = lane & 15, lg = lane >> 4;
    const int wm = wave >> 2, wn = wave & 3;  // 2 x 4 wave grid: 64-row x 32-col tiles
    const int nwg = gridDim.x;
    const int orig = blockIdx.x;
    const int swz = (orig & 7) * (nwg >> 3) + (orig >> 3);
    const int tm = swz / ntn, tn = swz % ntn;

    const unsigned short* srcA[2];
    const unsigned short* srcB[2];
#pragma unroll
    for (int i = 0; i < 2; ++i) {
        int g = i * 512 + tid;
        int row = g >> 3, sl = g & 7;
        int colg = sl ^ (row & 7);
        srcA[i] = A + (size_t)(tm * 128 + row) * K + colg * 8;
        srcB[i] = Bt + (size_t)(tn * 128 + row) * K + colg * 8;
    }
    auto stage = [&](int buf, int k0) {
#pragma unroll
        for (int i = 0; i < 2; ++i) {
            gload16(&a_lds[buf][i * 4096 + wave * 512], srcA[i] + k0);
            gload16(&b_lds[buf][i * 4096 + wave * 512], srcB[i] + k0);
        }
    };

    f32x4 acc[4][2] = {};

    stage(0, 0);
    asm volatile("s_waitcnt vmcnt(0)" ::: "memory");
    __builtin_amdgcn_s_barrier();

    for (int t = 0; t < NT; ++t) {
        const int buf = t & 1;
        if (t + 1 < NT) stage(buf ^ 1, (t + 1) * 64);
#pragma unroll
        for (int ks = 0; ks < 2; ++ks) {
            short8 af[4], bfr[2];
#pragma unroll
            for (int mf = 0; mf < 4; ++mf) {
                int row = wm * 64 + mf * 16 + lr;
                int slot = (ks * 4 + lg) ^ (row & 7);
                af[mf] = *(const short8*)&a_lds[buf][row * 64 + slot * 8];
            }
#pragma unroll
            for (int nf = 0; nf < 2; ++nf) {
                int row = wn * 32 + nf * 16 + lr;
                int slot = (ks * 4 + lg) ^ (row & 7);
                bfr[nf] = *(const short8*)&b_lds[buf][row * 64 + slot * 8];
            }
#pragma unroll
            for (int mf = 0; mf < 4; ++mf)
#pragma unroll
                for (int nf = 0; nf < 2; ++nf)
                    acc[mf][nf] = __builtin_amdgcn_mfma_f32_16x16x32_bf16(af[mf], bfr[nf], acc[mf][nf], 0, 0, 0);
        }
        asm volatile("s_waitcnt vmcnt(0)" ::: "memory");
        __builtin_amdgcn_s_barrier();
    }

#pragma unroll
    for (int nf = 0; nf < 2; ++nf) {
        int gc = tn * 128 + wn * 32 + nf * 16 + lr;
        float bv = bias[gc];
        int part = 0, h = 0, dh = 0;
        if constexpr (EPI == 3) {
            part = gc / 768;
            int cc = gc - part * 768;
            h = cc / 96;
            dh = cc - h * 96;
        }
#pragma unroll
        for (int mf = 0; mf < 4; ++mf) {
            int grb = tm * 128 + wm * 64 + mf * 16 + lg * 4;
            if constexpr (EPI == 3) {
                int b = grb >> 10, n2 = grb & 1023;
                size_t bh = (size_t)(b * 8 + h);
                if (part == 2) {
                    ushort4 wv;
                    wv.x = f2b(acc[mf][nf][0] + bv);
                    wv.y = f2b(acc[mf][nf][1] + bv);
                    wv.z = f2b(acc[mf][nf][2] + bv);
                    wv.w = f2b(acc[mf][nf][3] + bv);
                    *(ushort4*)&v_o[(bh * 96 + dh) * 1024 + n2] = wv;
                } else {
                    unsigned short* dst = (part == 0) ? q_o : k_o;
                    float sc = (part == 0) ? 0.14724445f : 1.f;
#pragma unroll
                    for (int r = 0; r < 4; ++r)
                        dst[(bh * 1024 + n2 + r) * 128 + dh] = f2b((acc[mf][nf][r] + bv) * sc);
                }
            } else {
#pragma unroll
                for (int r = 0; r < 4; ++r) {
                    int gr = grb + r;
                    float v = acc[mf][nf][r] + bv;
                    if constexpr (EPI == 0) {
                        outf[(size_t)gr * N + gc] = v;
                    } else if constexpr (EPI == 1) {
                        outb[(size_t)gr * N + gc] = f2b(v);
                    } else {
                        float gl = 0.5f * v * (1.f + erff(v * 0.70710678f));
                        outb[(size_t)gr * N + gc] = f2b(gl);
                    }
                }
            }
        }
    }
}

// ---------------- flash attention: 4 waves x 32 q-rows, K/V reads amortized 2x ----------
// Q,K: [64][1024][128] bf16 ; Vt: [64][96][1024] bf16 ; Y: [8][1024][768] bf16
__global__ __launch_bounds__(256, 2) void attn_kernel(
    const unsigned short* __restrict__ Qb, const unsigned short* __restrict__ Kb,
    const unsigned short* __restrict__ Vt, const float* __restrict__ centers,
    const float* __restrict__ rel_emb, unsigned short* __restrict__ Y) {
    __shared__ unsigned short kv_lds[2 * 14336];  // 56 KB
    __shared__ unsigned short p_lds[4 * 2048];    // 16 KB (per-wave 32x64)
    __shared__ float c_lds[1024];
    __shared__ float rel_lds[41];

    const int tid = threadIdx.x;  // 0..255
    const int wave = tid >> 6, lane = tid & 63;
    const int lr = lane & 15, lg = lane >> 4;
    const int bh = blockIdx.x, qb = blockIdx.y;
    const int b = bh >> 3, h = bh & 7;
    const int q0 = qb * 128 + wave * 32;
    const size_t kvbase = (size_t)bh * 1024 * 128;

#pragma unroll
    for (int i = 0; i < 4; ++i)
        c_lds[tid + i * 256] = centers[b * 1024 + tid + i * 256];
    if (tid < 41) rel_lds[tid] = rel_emb[tid * 8 + h] * L2E;

    // per-lane pre-swizzled staging sources: 1792 granules = 7 x 256 threads
    const unsigned short* sbase[7];
    int sstep[7];
#pragma unroll
    for (int it = 0; it < 7; ++it) {
        int g = it * 256 + tid;
        if (g < 1024) {  // K granule: g = ks*256 + pr*8 + sl
            int ks = g >> 8, rem = g & 255, pr = rem >> 3, sl = rem & 7;
            int so = sl ^ (pr & 7);
            int r = ((so >> 2) << 5) + pr, oct = so & 3;
            sbase[it] = Kb + kvbase + (size_t)r * 128 + ks * 32 + oct * 8;
            sstep[it] = 64 * 128;
        } else {  // V granule
            int v = g - 1024, pr = v >> 3, sl = v & 7;
            int so = sl ^ (pr & 7);
            sbase[it] = Vt + (size_t)(bh * 96 + pr) * 1024 + so * 8;
            sstep[it] = 64;
        }
    }
    auto stage = [&](int bufb, int kt) {
        unsigned short* dst = kv_lds + bufb * 14336;
#pragma unroll
        for (int it = 0; it < 7; ++it)
            gload16(dst + it * 2048 + wave * 512, sbase[it] + (size_t)kt * sstep[it]);
    };

    // Q fragments for both 16-row halves + per-row constants
    short8 qa[2][4];
#pragma unroll
    for (int h2 = 0; h2 < 2; ++h2)
#pragma unroll
        for (int ks = 0; ks < 4; ++ks)
            qa[h2][ks] = *(const short8*)&Qb[kvbase + (size_t)(q0 + h2 * 16 + lr) * 128 + ks * 32 + lg * 8];
    float ci20[2][4];
#pragma unroll
    for (int h2 = 0; h2 < 2; ++h2)
#pragma unroll
        for (int r = 0; r < 4; ++r)
            ci20[h2][r] = centers[b * 1024 + q0 + h2 * 16 + lg * 4 + r] + 20.f;

    short8 vone = {};
    if (lr == 0) {
#pragma unroll
        for (int e = 0; e < 8; ++e) vone[e] = (short)0x3F80;
    }

    float m_r[2][4] = {{-3e30f, -3e30f, -3e30f, -3e30f}, {-3e30f, -3e30f, -3e30f, -3e30f}};
    f32x4 oacc[2][7] = {};

    stage(0, 0);
    asm volatile("s_waitcnt lgkmcnt(0)" ::: "memory");  // drain c/rel ds_writes

    for (int kt = 0; kt < 16; ++kt) {
        const int buf = kt & 1;
        if (kt < 15) {
            stage(buf ^ 1, kt + 1);
            asm volatile("s_waitcnt vmcnt(7)" ::: "memory");  // tile kt landed; kt+1 in flight
        } else {
            asm volatile("s_waitcnt vmcnt(0)" ::: "memory");
        }
        __builtin_amdgcn_s_barrier();
        const unsigned short* kv = kv_lds + buf * 14336;

        // ---- QK^T: each kf read feeds both q-halves ----
        f32x4 s[2][4] = {};
#pragma unroll
        for (int jf = 0; jf < 4; ++jf) {
            int pr = ((jf & 1) << 4) + lr;
            int slp = (((jf >> 1) << 2) + lg) ^ (lr & 7);
#pragma unroll
            for (int ks = 0; ks < 4; ++ks) {
                short8 kf = *(const short8*)&kv[ks * 2048 + pr * 64 + slp * 8];
                s[0][jf] = __builtin_amdgcn_mfma_f32_16x16x32_bf16(qa[0][ks], kf, s[0][jf], 0, 0, 0);
                s[1][jf] = __builtin_amdgcn_mfma_f32_16x16x32_bf16(qa[1][ks], kf, s[1][jf], 0, 0, 0);
            }
        }

        // ---- rel bias ----
#pragma unroll
        for (int jf = 0; jf < 4; ++jf) {
            float cj = c_lds[kt * 64 + jf * 16 + lr];
#pragma unroll
            for (int h2 = 0; h2 < 2; ++h2)
#pragma unroll
                for (int r = 0; r < 4; ++r) {
                    float idxf = __builtin_amdgcn_fmed3f(ci20[h2][r] - cj, 0.f, 40.f);
                    s[h2][jf][r] += rel_lds[(int)rintf(idxf)];
                }
        }

        // ---- online softmax (defer-max THR=8), per half ----
#pragma unroll
        for (int h2 = 0; h2 < 2; ++h2)
#pragma unroll
            for (int r = 0; r < 4; ++r) {
                float mx = fmaxf(fmaxf(s[h2][0][r], s[h2][1][r]), fmaxf(s[h2][2][r], s[h2][3][r]));
#pragma unroll
                for (int off = 1; off < 16; off <<= 1) mx = fmaxf(mx, __shfl_xor(mx, off));
                if (!__all(mx <= m_r[h2][r] + 8.f)) {
                    float mn = fmaxf(m_r[h2][r], mx);
                    float al = exp2v(m_r[h2][r] - mn);
                    m_r[h2][r] = mn;
#pragma unroll
                    for (int nf = 0; nf < 7; ++nf) oacc[h2][nf][r] *= al;
                }
#pragma unroll
                for (int jf = 0; jf < 4; ++jf) s[h2][jf][r] = exp2v(s[h2][jf][r] - m_r[h2][r]);
            }

        // ---- P (C/D layout) -> swizzled LDS -> A-fragments, both halves ----
#pragma unroll
        for (int h2 = 0; h2 < 2; ++h2)
#pragma unroll
            for (int jf = 0; jf < 4; ++jf)
#pragma unroll
                for (int r = 0; r < 4; ++r) {
                    int row = lg * 4 + r, col = jf * 16 + lr;
                    int gp = (col >> 3) ^ (row & 7);
                    p_lds[wave * 2048 + h2 * 1024 + row * 64 + gp * 8 + (col & 7)] = f2b_trunc(s[h2][jf][r]);
                }
        asm volatile("s_waitcnt lgkmcnt(0)" ::: "memory");
        short8 pa[2][2];
#pragma unroll
        for (int h2 = 0; h2 < 2; ++h2)
#pragma unroll
            for (int js = 0; js < 2; ++js) {
                int slp = ((js << 2) + lg) ^ (lr & 7);
                pa[h2][js] = *(const short8*)&p_lds[wave * 2048 + h2 * 1024 + lr * 64 + slp * 8];
            }

        // ---- PV: each vf read feeds both halves ----
#pragma unroll
        for (int nf = 0; nf < 6; ++nf) {
            int vrow = nf * 16 + lr;
#pragma unroll
            for (int js = 0; js < 2; ++js) {
                int slp = ((js << 2) + lg) ^ (lr & 7);
                short8 vf = *(const short8*)&kv[8192 + vrow * 64 + slp * 8];
                oacc[0][nf] = __builtin_amdgcn_mfma_f32_16x16x32_bf16(pa[0][js], vf, oacc[0][nf], 0, 0, 0);
                oacc[1][nf] = __builtin_amdgcn_mfma_f32_16x16x32_bf16(pa[1][js], vf, oacc[1][nf], 0, 0, 0);
            }
        }
#pragma unroll
        for (int h2 = 0; h2 < 2; ++h2)
#pragma unroll
            for (int js = 0; js < 2; ++js)
                oacc[h2][6] = __builtin_amdgcn_mfma_f32_16x16x32_bf16(pa[h2][js], vone, oacc[h2][6], 0, 0, 0);
        __builtin_amdgcn_s_barrier();
    }

#pragma unroll
    for (int h2 = 0; h2 < 2; ++h2)
#pragma unroll
        for (int r = 0; r < 4; ++r) {
            float l = __shfl(oacc[h2][6][r], lane & 48);
            float inv = (l > 0.f) ? 1.f / l : 0.f;
            int qi = q0 + h2 * 16 + lg * 4 + r;
#pragma unroll
            for (int nf = 0; nf < 6; ++nf)
                Y[((size_t)b * 1024 + qi) * 768 + h * 96 + nf * 16 + lr] = f2b(oacc[h2][nf][r] * inv);
        }
}

// ---------------- layernorm with residual add (vectorized, 2 rows/block) ----------------
template <bool IN1BF, bool IN2BF>
__global__ __launch_bounds__(384) void ln_kernel(const void* __restrict__ in1,
                                                 const void* __restrict__ in2,
                                                 const float* __restrict__ g,
                                                 const float* __restrict__ be,
                                                 float* __restrict__ of,
                                                 unsigned short* __restrict__ ob) {
    const int tid = threadIdx.x;
    const int half = tid / 192;
    const int t = tid - half * 192;
    const int row = blockIdx.x * 2 + half;
    const size_t base = (size_t)row * 768 + t * 4;
    float a[4], bb[4];
    if (IN1BF) {
        ushort4 u = *(const ushort4*)((const unsigned short*)in1 + base);
        a[0] = b2f(u.x); a[1] = b2f(u.y); a[2] = b2f(u.z); a[3] = b2f(u.w);
    } else {
        float4 u = *(const float4*)((const float*)in1 + base);
        a[0] = u.x; a[1] = u.y; a[2] = u.z; a[3] = u.w;
    }
    if (IN2BF) {
        ushort4 u = *(const ushort4*)((const unsigned short*)in2 + base);
        bb[0] = b2f(u.x); bb[1] = b2f(u.y); bb[2] = b2f(u.z); bb[3] = b2f(u.w);
    } else {
        float4 u = *(const float4*)((const float*)in2 + base);
        bb[0] = u.x; bb[1] = u.y; bb[2] = u.z; bb[3] = u.w;
    }
    float v[4];
#pragma unroll
    for (int i = 0; i < 4; ++i) v[i] = a[i] + bb[i];
    float s1 = v[0] + v[1] + v[2] + v[3];
    float s2 = v[0] * v[0] + v[1] * v[1] + v[2] * v[2] + v[3] * v[3];
#pragma unroll
    for (int off = 32; off > 0; off >>= 1) {
        s1 += __shfl_xor(s1, off);
        s2 += __shfl_xor(s2, off);
    }
    __shared__ float red[12];
    const int wv = tid >> 6;
    if ((tid & 63) == 0) { red[wv] = s1; red[6 + wv] = s2; }
    __syncthreads();
    const int w0 = half * 3;
    s1 = red[w0] + red[w0 + 1] + red[w0 + 2];
    s2 = red[6 + w0] + red[6 + w0 + 1] + red[6 + w0 + 2];
    float mu = s1 * (1.f / 768.f);
    float var = s2 * (1.f / 768.f) - mu * mu;
    float inv = rsqrtf(var + 1e-5f);
    float o[4];
#pragma unroll
    for (int i = 0; i < 4; ++i)
        o[i] = (v[i] - mu) * inv * g[t * 4 + i] + be[t * 4 + i];
    if (of) {
        float4 w = {o[0], o[1], o[2], o[3]};
        *(float4*)(of + base) = w;
    }
    if (ob) {
        ushort4 w = {f2b(o[0]), f2b(o[1]), f2b(o[2]), f2b(o[3])};
        *(ushort4*)(ob + base) = w;
    }
}

extern "C" void kernel_launch(void* const* d_in, const int* in_sizes, int n_in,
                              void* d_out, int out_size, void* d_ws, size_t ws_size,
                              hipStream_t stream) {
    const float* x     = (const float*)d_in[0];
    const int*   nmask = (const int*)d_in[1];
    const float* cent  = (const float*)d_in[2];
    const int*   types = (const int*)d_in[3];
    const float* qkv_w = (const float*)d_in[4];
    const float* qkv_b = (const float*)d_in[5];
    const float* out_w = (const float*)d_in[6];
    const float* out_b = (const float*)d_in[7];
    const float* ff1_w = (const float*)d_in[8];
    const float* ff1_b = (const float*)d_in[9];
    const float* ff2_w = (const float*)d_in[10];
    const float* ff2_b = (const float*)d_in[11];
    const float* ln1_g = (const float*)d_in[12];
    const float* ln1_b = (const float*)d_in[13];
    const float* ln2_g = (const float*)d_in[14];
    const float* ln2_b = (const float*)d_in[15];
    const float* rel   = (const float*)d_in[16];
    const float* ttp   = (const float*)d_in[17];

    char* w = (char*)d_ws;
    auto alloc = [&](size_t bytes) {
        char* p = w;
        w += (bytes + 255) & ~(size_t)255;
        return p;
    };
    unsigned short* xb  = (unsigned short*)alloc(8192ull * 768 * 2);   // x bf16; reused as Y
    unsigned short* qwT = (unsigned short*)alloc(2304ull * 768 * 2);
    unsigned short* owT = (unsigned short*)alloc(768ull * 768 * 2);
    unsigned short* f1T = (unsigned short*)alloc(1024ull * 768 * 2);
    unsigned short* f2T = (unsigned short*)alloc(768ull * 1024 * 2);
    unsigned short* Qb  = (unsigned short*)alloc(64ull * 1024 * 128 * 2);
    unsigned short* Kb  = (unsigned short*)alloc(64ull * 1024 * 128 * 2);
    unsigned short* Vt  = (unsigned short*)alloc(64ull * 96 * 1024 * 2);
    unsigned short* aob = (unsigned short*)alloc(8192ull * 768 * 2);  // residual branch (bf16)
    unsigned short* h1b = (unsigned short*)alloc(8192ull * 768 * 2);
    unsigned short* ffa = Qb;  // alias: Qb dead after attn

    // fused cvt + 4 transposes: 6144 + 3840 = 9984 blocks
    prep_kernel<<<9984, 256, 0, stream>>>(x, xb, qkv_w, qwT, out_w, owT,
                                          ff1_w, f1T, ff2_w, f2T);

    // QKV: M=8192 N=2304 K=768 -> 64x18 = 1152 blocks
    gemm2p<3><<<1152, 512, 0, stream>>>(xb, qwT, qkv_b, nullptr, nullptr,
                                        Qb, Kb, Vt, 2304, 768, 18, 12);
    aug_qk<<<256, 256, 0, stream>>>(types, nmask, ttp, Qb, Kb);
    attn_kernel<<<dim3(64, 8), 256, 0, stream>>>(Qb, Kb, Vt, cent, rel, xb);
    // out proj: N=768 K=768 -> 384 blocks, bf16 out
    gemm2p<1><<<384, 512, 0, stream>>>(xb, owT, out_b, nullptr, aob,
                                       nullptr, nullptr, nullptr, 768, 768, 6, 12);
    ln_kernel<false, true><<<4096, 384, 0, stream>>>(x, aob, ln1_g, ln1_b, nullptr, h1b);
    // ff1+gelu: N=1024 K=768 -> 512 blocks
    gemm2p<2><<<512, 512, 0, stream>>>(h1b, f1T, ff1_b, nullptr, ffa,
                                       nullptr, nullptr, nullptr, 1024, 768, 8, 12);
    // ff2: N=768 K=1024 -> 384 blocks, NT=16, bf16 out (reuse aob)
    gemm2p<1><<<384, 512, 0, stream>>>(ffa, f2T, ff2_b, nullptr, aob,
                                       nullptr, nullptr, nullptr, 768, 1024, 6, 16);
    ln_kernel<true, true><<<4096, 384, 0, stream>>>(h1b, aob, ln2_g, ln2_b, (float*)d_out, nullptr);
}

// Round 11
// 202.794 us; speedup vs baseline: 1.1960x; 1.0405x over previous
//
#include <hip/hip_runtime.h>

typedef short short8 __attribute__((ext_vector_type(8)));
typedef unsigned short ushort8v __attribute__((ext_vector_type(8)));
typedef float f32x4 __attribute__((ext_vector_type(4)));

static __device__ __forceinline__ unsigned short f2b(float f) {
    unsigned int u = __builtin_bit_cast(unsigned int, f);
    unsigned int r = (u + 0x7fffu + ((u >> 16) & 1u)) >> 16;
    return (unsigned short)r;
}
static __device__ __forceinline__ unsigned short f2b_trunc(float f) {
    return (unsigned short)(__builtin_bit_cast(unsigned int, f) >> 16);
}
static __device__ __forceinline__ float b2f(unsigned short u) {
    return __builtin_bit_cast(float, (unsigned int)u << 16);
}
static __device__ __forceinline__ float exp2v(float x) {
    float r;
    asm("v_exp_f32 %0, %1" : "=v"(r) : "v"(x));
    return r;
}

__device__ __forceinline__ void gload16(void* lds, const void* g) {
    __builtin_amdgcn_global_load_lds(
        (const __attribute__((address_space(1))) void*)g,
        (__attribute__((address_space(3))) void*)lds, 16, 0, 0);
}

#define L2E 1.4426950408889634f

// ---------------- fused prep: cvt x (f32->bf16) + 4 weight transposes ----------------
__global__ __launch_bounds__(256) void prep_kernel(
    const float* __restrict__ x, unsigned short* __restrict__ xb,
    const float* __restrict__ qkv_w, unsigned short* __restrict__ qwT,
    const float* __restrict__ out_w, unsigned short* __restrict__ owT,
    const float* __restrict__ ff1_w, unsigned short* __restrict__ f1T,
    const float* __restrict__ ff2_w, unsigned short* __restrict__ f2T) {
    const int bx = blockIdx.x;
    const int tid = threadIdx.x;
    if (bx < 6144) {  // cvt x
        int i = bx * 256 + tid;
        float4 f = ((const float4*)x)[i];
        ushort4 u;
        u.x = f2b(f.x); u.y = f2b(f.y); u.z = f2b(f.z); u.w = f2b(f.w);
        ((ushort4*)xb)[i] = u;
        return;
    }
    __shared__ float t[32][33];
    int rb = bx - 6144;
    const float* W; unsigned short* Wt; int K, N;
    if (rb < 1728)      { W = qkv_w; Wt = qwT; K = 768;  N = 2304; }
    else if (rb < 2304) { rb -= 1728; W = out_w; Wt = owT; K = 768;  N = 768; }
    else if (rb < 3072) { rb -= 2304; W = ff1_w; Wt = f1T; K = 768;  N = 1024; }
    else                { rb -= 3072; W = ff2_w; Wt = f2T; K = 1024; N = 768; }
    const int nbl = N / 32;
    const int nb = (rb % nbl) * 32, kb = (rb / nbl) * 32;
    const int tx = tid & 31, ty = tid >> 5;
#pragma unroll
    for (int i = 0; i < 32; i += 8)
        t[ty + i][tx] = W[(size_t)(kb + ty + i) * N + nb + tx];
    __syncthreads();
#pragma unroll
    for (int i = 0; i < 32; i += 8)
        Wt[(size_t)(nb + ty + i) * K + kb + tx] = f2b(t[tx][ty + i]);
}

// ---------------- 128x128 BK=64 2-phase GEMM, 8 waves (64x32 per wave) ----------------
// EPI: 0 = f32 out, 1 = bf16 out, 2 = gelu->bf16 out, 3 = qkv scatter (width-96 Q/K)
template <int EPI>
__global__ __launch_bounds__(512, 4) void gemm2p(
    const unsigned short* __restrict__ A, const unsigned short* __restrict__ Bt,
    const float* __restrict__ bias, float* __restrict__ outf,
    unsigned short* __restrict__ outb, unsigned short* __restrict__ q_o,
    unsigned short* __restrict__ k_o, unsigned short* __restrict__ v_o,
    int N, int K, int ntn, int NT) {
    __shared__ unsigned short a_lds[2][8192];
    __shared__ unsigned short b_lds[2][8192];
    const int tid = threadIdx.x;
    const int wave = tid >> 6, lane = tid & 63;
    const int lr = lane & 15, lg = lane >> 4;
    const int wm = wave >> 2, wn = wave & 3;
    const int nwg = gridDim.x;
    const int orig = blockIdx.x;
    const int swz = (orig & 7) * (nwg >> 3) + (orig >> 3);
    const int tm = swz / ntn, tn = swz % ntn;

    const unsigned short* srcA[2];
    const unsigned short* srcB[2];
#pragma unroll
    for (int i = 0; i < 2; ++i) {
        int g = i * 512 + tid;
        int row = g >> 3, sl = g & 7;
        int colg = sl ^ (row & 7);
        srcA[i] = A + (size_t)(tm * 128 + row) * K + colg * 8;
        srcB[i] = Bt + (size_t)(tn * 128 + row) * K + colg * 8;
    }
    auto stage = [&](int buf, int k0) {
#pragma unroll
        for (int i = 0; i < 2; ++i) {
            gload16(&a_lds[buf][i * 4096 + wave * 512], srcA[i] + k0);
            gload16(&b_lds[buf][i * 4096 + wave * 512], srcB[i] + k0);
        }
    };

    f32x4 acc[4][2] = {};

    stage(0, 0);
    asm volatile("s_waitcnt vmcnt(0)" ::: "memory");
    __builtin_amdgcn_s_barrier();

    for (int t = 0; t < NT; ++t) {
        const int buf = t & 1;
        if (t + 1 < NT) stage(buf ^ 1, (t + 1) * 64);
#pragma unroll
        for (int ks = 0; ks < 2; ++ks) {
            short8 af[4], bfr[2];
#pragma unroll
            for (int mf = 0; mf < 4; ++mf) {
                int row = wm * 64 + mf * 16 + lr;
                int slot = (ks * 4 + lg) ^ (row & 7);
                af[mf] = *(const short8*)&a_lds[buf][row * 64 + slot * 8];
            }
#pragma unroll
            for (int nf = 0; nf < 2; ++nf) {
                int row = wn * 32 + nf * 16 + lr;
                int slot = (ks * 4 + lg) ^ (row & 7);
                bfr[nf] = *(const short8*)&b_lds[buf][row * 64 + slot * 8];
            }
#pragma unroll
            for (int mf = 0; mf < 4; ++mf)
#pragma unroll
                for (int nf = 0; nf < 2; ++nf)
                    acc[mf][nf] = __builtin_amdgcn_mfma_f32_16x16x32_bf16(af[mf], bfr[nf], acc[mf][nf], 0, 0, 0);
        }
        asm volatile("s_waitcnt vmcnt(0)" ::: "memory");
        __builtin_amdgcn_s_barrier();
    }

#pragma unroll
    for (int nf = 0; nf < 2; ++nf) {
        int gc = tn * 128 + wn * 32 + nf * 16 + lr;
        float bv = bias[gc];
        int part = 0, h = 0, dh = 0;
        if constexpr (EPI == 3) {
            part = gc / 768;
            int cc = gc - part * 768;
            h = cc / 96;
            dh = cc - h * 96;
        }
#pragma unroll
        for (int mf = 0; mf < 4; ++mf) {
            int grb = tm * 128 + wm * 64 + mf * 16 + lg * 4;
            if constexpr (EPI == 3) {
                int b = grb >> 10, n2 = grb & 1023;
                size_t bh = (size_t)(b * 8 + h);
                if (part == 2) {
                    ushort4 wv;
                    wv.x = f2b(acc[mf][nf][0] + bv);
                    wv.y = f2b(acc[mf][nf][1] + bv);
                    wv.z = f2b(acc[mf][nf][2] + bv);
                    wv.w = f2b(acc[mf][nf][3] + bv);
                    *(ushort4*)&v_o[(bh * 96 + dh) * 1024 + n2] = wv;
                } else {
                    unsigned short* dst = (part == 0) ? q_o : k_o;
                    float sc = (part == 0) ? 0.14724445f : 1.f;
#pragma unroll
                    for (int r = 0; r < 4; ++r)
                        dst[(bh * 1024 + n2 + r) * 96 + dh] = f2b((acc[mf][nf][r] + bv) * sc);
                }
            } else {
#pragma unroll
                for (int r = 0; r < 4; ++r) {
                    int gr = grb + r;
                    float v = acc[mf][nf][r] + bv;
                    if constexpr (EPI == 0) {
                        outf[(size_t)gr * N + gc] = v;
                    } else if constexpr (EPI == 1) {
                        outb[(size_t)gr * N + gc] = f2b(v);
                    } else {
                        float gl = 0.5f * v * (1.f + erff(v * 0.70710678f));
                        outb[(size_t)gr * N + gc] = f2b(gl);
                    }
                }
            }
        }
    }
}

// ---------------- flash attention: 8 waves x 16 q-rows, width-96 Q/K, in-reg aug -------
// Q,K: [64][1024][96] bf16 (Q pre-scaled by 1/sqrt(96)*L2E) ; Vt: [64][96][1024] bf16
__global__ __launch_bounds__(512, 4) void attn_kernel(
    const unsigned short* __restrict__ Qb, const unsigned short* __restrict__ Kb,
    const unsigned short* __restrict__ Vt, const float* __restrict__ centers,
    const int* __restrict__ types, const int* __restrict__ nmask,
    const float* __restrict__ tt, const float* __restrict__ rel_emb,
    unsigned short* __restrict__ Y) {
    __shared__ unsigned short kv_lds[2 * 12288];  // 48 KB (K 12KB + V 12KB per buf)
    __shared__ unsigned short p_lds[8 * 1024];    // 16 KB
    __shared__ float c_lds[1024];                 // 4 KB
    __shared__ unsigned int bab_lds[1024];        // 4 KB packed (bA,bB) bf16 pairs
    __shared__ float rel_lds[41];

    const int tid = threadIdx.x;
    const int wave = tid >> 6, lane = tid & 63;
    const int lr = lane & 15, lg = lane >> 4;
    const int bh = blockIdx.x, qb = blockIdx.y;
    const int b = bh >> 3, h = bh & 7;
    const int q0 = qb * 128 + wave * 16;
    const size_t kvbase = (size_t)bh * 1024 * 96;

    // ---- prologue: centers, rel table, packed type/mask bias table ----
    c_lds[tid] = centers[b * 1024 + tid];
    c_lds[tid + 512] = centers[b * 1024 + 512 + tid];
    if (tid < 41) rel_lds[tid] = rel_emb[tid * 8 + h] * L2E;
    {
        const float t00 = tt[h * 4], t01 = tt[h * 4 + 1];
        const float t10 = tt[h * 4 + 2], t11 = tt[h * 4 + 3];
#pragma unroll
        for (int i = 0; i < 2; ++i) {
            int j = tid + i * 512;
            int tj = types[b * 1024 + j];
            int mk = nmask[b * 1024 + j];
            float bA = L2E * (t00 + (t01 - t00) * tj) + (mk ? 0.f : -1e30f);
            float bB = L2E * ((t10 - t00) + (t11 - t01 - t10 + t00) * tj);
            bab_lds[j] = (unsigned)f2b(bA) | ((unsigned)f2b(bB) << 16);
        }
    }

    // ---- per-lane pre-swizzled staging sources: 1536 granules = 3 x 512 ----
    const unsigned short* sbase[3];
    int sstep[3];
#pragma unroll
    for (int it = 0; it < 3; ++it) {
        int g = it * 512 + tid;
        if (g < 768) {  // K granule: g = ks*256 + pr*8 + sl
            int ks = g >> 8, rem = g & 255, pr = rem >> 3, sl = rem & 7;
            int so = sl ^ (pr & 7);
            int r = ((so >> 2) << 5) + pr, oct = so & 3;
            sbase[it] = Kb + kvbase + (size_t)r * 96 + ks * 32 + oct * 8;
            sstep[it] = 64 * 96;
        } else {  // V granule: gv = pr*8 + sl, pr 0..95
            int gv = g - 768, pr = gv >> 3, sl = gv & 7;
            int so = sl ^ (pr & 7);
            sbase[it] = Vt + (size_t)(bh * 96 + pr) * 1024 + so * 8;
            sstep[it] = 64;
        }
    }
    auto stage = [&](int bufb, int kt) {
        unsigned short* dst = kv_lds + bufb * 12288;
#pragma unroll
        for (int it = 0; it < 3; ++it)
            gload16(dst + it * 4096 + wave * 512, sbase[it] + (size_t)kt * sstep[it]);
    };

    // ---- Q fragments (3 ks) + in-register aug A-fragment ----
    short8 qa[3];
#pragma unroll
    for (int ks = 0; ks < 3; ++ks)
        qa[ks] = *(const short8*)&Qb[kvbase + (size_t)(q0 + lr) * 96 + ks * 32 + lg * 8];
    short8 qa3 = {};
    {
        int ti0 = types[b * 1024 + q0 + lr];
        if (lg == 0) {
            qa3[0] = (short)0x3F80;
            qa3[1] = ti0 ? (short)0x3F80 : (short)0;
        }
    }
    float ci20[4];
#pragma unroll
    for (int r = 0; r < 4; ++r) ci20[r] = centers[b * 1024 + q0 + lg * 4 + r] + 20.f;

    short8 vone = {};
    if (lr == 0) {
#pragma unroll
        for (int e = 0; e < 8; ++e) vone[e] = (short)0x3F80;
    }

    float m_r[4] = {-3e30f, -3e30f, -3e30f, -3e30f};
    f32x4 oacc[7] = {};

    stage(0, 0);
    asm volatile("s_waitcnt lgkmcnt(0)" ::: "memory");  // drain c/bab/rel ds_writes

    for (int kt = 0; kt < 16; ++kt) {
        const int buf = kt & 1;
        if (kt < 15) {
            stage(buf ^ 1, kt + 1);
            asm volatile("s_waitcnt vmcnt(3)" ::: "memory");  // tile kt landed; kt+1 in flight
        } else {
            asm volatile("s_waitcnt vmcnt(0)" ::: "memory");
        }
        __builtin_amdgcn_s_barrier();
        const unsigned short* kv = kv_lds + buf * 12288;

        // ---- QK^T: 3 ks from LDS + aug from registers ----
        f32x4 s[4] = {};
#pragma unroll
        for (int jf = 0; jf < 4; ++jf) {
            int pr = ((jf & 1) << 4) + lr;
            int slp = (((jf >> 1) << 2) + lg) ^ (lr & 7);
#pragma unroll
            for (int ks = 0; ks < 3; ++ks) {
                short8 kf = *(const short8*)&kv[ks * 2048 + pr * 64 + slp * 8];
                s[jf] = __builtin_amdgcn_mfma_f32_16x16x32_bf16(qa[ks], kf, s[jf], 0, 0, 0);
            }
            unsigned vb = bab_lds[kt * 64 + jf * 16 + lr];
            short8 kf3 = {};
            if (lg == 0) {
                kf3[0] = (short)(vb & 0xffffu);
                kf3[1] = (short)(vb >> 16);
            }
            s[jf] = __builtin_amdgcn_mfma_f32_16x16x32_bf16(qa3, kf3, s[jf], 0, 0, 0);
        }

        // ---- rel bias ----
#pragma unroll
        for (int jf = 0; jf < 4; ++jf) {
            float cj = c_lds[kt * 64 + jf * 16 + lr];
#pragma unroll
            for (int r = 0; r < 4; ++r) {
                float idxf = __builtin_amdgcn_fmed3f(ci20[r] - cj, 0.f, 40.f);
                s[jf][r] += rel_lds[(int)rintf(idxf)];
            }
        }

        // ---- online softmax (exp2 domain, defer-max THR=8) ----
#pragma unroll
        for (int r = 0; r < 4; ++r) {
            float mx = fmaxf(fmaxf(s[0][r], s[1][r]), fmaxf(s[2][r], s[3][r]));
#pragma unroll
            for (int off = 1; off < 16; off <<= 1) mx = fmaxf(mx, __shfl_xor(mx, off));
            if (!__all(mx <= m_r[r] + 8.f)) {
                float mn = fmaxf(m_r[r], mx);
                float al = exp2v(m_r[r] - mn);
                m_r[r] = mn;
#pragma unroll
                for (int nf = 0; nf < 7; ++nf) oacc[nf][r] *= al;
            }
#pragma unroll
            for (int jf = 0; jf < 4; ++jf) s[jf][r] = exp2v(s[jf][r] - m_r[r]);
        }

        // ---- P (C/D layout) -> swizzled LDS -> A-fragment ----
#pragma unroll
        for (int jf = 0; jf < 4; ++jf)
#pragma unroll
            for (int r = 0; r < 4; ++r) {
                int row = lg * 4 + r, col = jf * 16 + lr;
                int gp = (col >> 3) ^ (row & 7);
                p_lds[wave * 1024 + row * 64 + gp * 8 + (col & 7)] = f2b_trunc(s[jf][r]);
            }
        asm volatile("s_waitcnt lgkmcnt(0)" ::: "memory");
        short8 pa[2];
#pragma unroll
        for (int js = 0; js < 2; ++js) {
            int slp = ((js << 2) + lg) ^ (lr & 7);
            pa[js] = *(const short8*)&p_lds[wave * 1024 + lr * 64 + slp * 8];
        }

        // ---- PV (+ l via ones-fragment) ----
#pragma unroll
        for (int nf = 0; nf < 6; ++nf) {
            int vrow = nf * 16 + lr;
#pragma unroll
            for (int js = 0; js < 2; ++js) {
                int slp = ((js << 2) + lg) ^ (lr & 7);
                short8 vf = *(const short8*)&kv[6144 + vrow * 64 + slp * 8];
                oacc[nf] = __builtin_amdgcn_mfma_f32_16x16x32_bf16(pa[js], vf, oacc[nf], 0, 0, 0);
            }
        }
#pragma unroll
        for (int js = 0; js < 2; ++js)
            oacc[6] = __builtin_amdgcn_mfma_f32_16x16x32_bf16(pa[js], vone, oacc[6], 0, 0, 0);
        __builtin_amdgcn_s_barrier();
    }

#pragma unroll
    for (int r = 0; r < 4; ++r) {
        float l = __shfl(oacc[6][r], lane & 48);
        float inv = (l > 0.f) ? 1.f / l : 0.f;
        int qi = q0 + lg * 4 + r;
#pragma unroll
        for (int nf = 0; nf < 6; ++nf)
            Y[((size_t)b * 1024 + qi) * 768 + h * 96 + nf * 16 + lr] = f2b(oacc[nf][r] * inv);
    }
}

// ---------------- layernorm with residual add (vectorized, 2 rows/block) ----------------
template <bool IN1BF, bool IN2BF>
__global__ __launch_bounds__(384) void ln_kernel(const void* __restrict__ in1,
                                                 const void* __restrict__ in2,
                                                 const float* __restrict__ g,
                                                 const float* __restrict__ be,
                                                 float* __restrict__ of,
                                                 unsigned short* __restrict__ ob) {
    const int tid = threadIdx.x;
    const int half = tid / 192;
    const int t = tid - half * 192;
    const int row = blockIdx.x * 2 + half;
    const size_t base = (size_t)row * 768 + t * 4;
    float a[4], bb[4];
    if (IN1BF) {
        ushort4 u = *(const ushort4*)((const unsigned short*)in1 + base);
        a[0] = b2f(u.x); a[1] = b2f(u.y); a[2] = b2f(u.z); a[3] = b2f(u.w);
    } else {
        float4 u = *(const float4*)((const float*)in1 + base);
        a[0] = u.x; a[1] = u.y; a[2] = u.z; a[3] = u.w;
    }
    if (IN2BF) {
        ushort4 u = *(const ushort4*)((const unsigned short*)in2 + base);
        bb[0] = b2f(u.x); bb[1] = b2f(u.y); bb[2] = b2f(u.z); bb[3] = b2f(u.w);
    } else {
        float4 u = *(const float4*)((const float*)in2 + base);
        bb[0] = u.x; bb[1] = u.y; bb[2] = u.z; bb[3] = u.w;
    }
    float v[4];
#pragma unroll
    for (int i = 0; i < 4; ++i) v[i] = a[i] + bb[i];
    float s1 = v[0] + v[1] + v[2] + v[3];
    float s2 = v[0] * v[0] + v[1] * v[1] + v[2] * v[2] + v[3] * v[3];
#pragma unroll
    for (int off = 32; off > 0; off >>= 1) {
        s1 += __shfl_xor(s1, off);
        s2 += __shfl_xor(s2, off);
    }
    __shared__ float red[12];
    const int wv = tid >> 6;
    if ((tid & 63) == 0) { red[wv] = s1; red[6 + wv] = s2; }
    __syncthreads();
    const int w0 = half * 3;
    s1 = red[w0] + red[w0 + 1] + red[w0 + 2];
    s2 = red[6 + w0] + red[6 + w0 + 1] + red[6 + w0 + 2];
    float mu = s1 * (1.f / 768.f);
    float var = s2 * (1.f / 768.f) - mu * mu;
    float inv = rsqrtf(var + 1e-5f);
    float o[4];
#pragma unroll
    for (int i = 0; i < 4; ++i)
        o[i] = (v[i] - mu) * inv * g[t * 4 + i] + be[t * 4 + i];
    if (of) {
        float4 w = {o[0], o[1], o[2], o[3]};
        *(float4*)(of + base) = w;
    }
    if (ob) {
        ushort4 w = {f2b(o[0]), f2b(o[1]), f2b(o[2]), f2b(o[3])};
        *(ushort4*)(ob + base) = w;
    }
}

extern "C" void kernel_launch(void* const* d_in, const int* in_sizes, int n_in,
                              void* d_out, int out_size, void* d_ws, size_t ws_size,
                              hipStream_t stream) {
    const float* x     = (const float*)d_in[0];
    const int*   nmask = (const int*)d_in[1];
    const float* cent  = (const float*)d_in[2];
    const int*   types = (const int*)d_in[3];
    const float* qkv_w = (const float*)d_in[4];
    const float* qkv_b = (const float*)d_in[5];
    const float* out_w = (const float*)d_in[6];
    const float* out_b = (const float*)d_in[7];
    const float* ff1_w = (const float*)d_in[8];
    const float* ff1_b = (const float*)d_in[9];
    const float* ff2_w = (const float*)d_in[10];
    const float* ff2_b = (const float*)d_in[11];
    const float* ln1_g = (const float*)d_in[12];
    const float* ln1_b = (const float*)d_in[13];
    const float* ln2_g = (const float*)d_in[14];
    const float* ln2_b = (const float*)d_in[15];
    const float* rel   = (const float*)d_in[16];
    const float* ttp   = (const float*)d_in[17];

    char* w = (char*)d_ws;
    auto alloc = [&](size_t bytes) {
        char* p = w;
        w += (bytes + 255) & ~(size_t)255;
        return p;
    };
    unsigned short* xb  = (unsigned short*)alloc(8192ull * 768 * 2);   // x bf16; reused as Y
    unsigned short* qwT = (unsigned short*)alloc(2304ull * 768 * 2);
    unsigned short* owT = (unsigned short*)alloc(768ull * 768 * 2);
    unsigned short* f1T = (unsigned short*)alloc(1024ull * 768 * 2);
    unsigned short* f2T = (unsigned short*)alloc(768ull * 1024 * 2);
    unsigned short* Qb  = (unsigned short*)alloc(64ull * 1024 * 96 * 2);
    unsigned short* Kb  = (unsigned short*)alloc(64ull * 1024 * 96 * 2);
    unsigned short* Vt  = (unsigned short*)alloc(64ull * 96 * 1024 * 2);
    unsigned short* aob = (unsigned short*)alloc(8192ull * 768 * 2);  // residual branch (bf16)
    unsigned short* h1b = (unsigned short*)alloc(8192ull * 768 * 2);
    unsigned short* ffa = Qb;  // alias: ff1 act (16.8MB) spans Qb+Kb (25.2MB), both dead after attn

    // fused cvt + 4 transposes: 6144 + 3840 = 9984 blocks
    prep_kernel<<<9984, 256, 0, stream>>>(x, xb, qkv_w, qwT, out_w, owT,
                                          ff1_w, f1T, ff2_w, f2T);

    // QKV: M=8192 N=2304 K=768 -> 64x18 = 1152 blocks
    gemm2p<3><<<1152, 512, 0, stream>>>(xb, qwT, qkv_b, nullptr, nullptr,
                                        Qb, Kb, Vt, 2304, 768, 18, 12);
    attn_kernel<<<dim3(64, 8), 512, 0, stream>>>(Qb, Kb, Vt, cent, types, nmask, ttp, rel, xb);
    // out proj: N=768 K=768 -> 384 blocks, bf16 out
    gemm2p<1><<<384, 512, 0, stream>>>(xb, owT, out_b, nullptr, aob,
                                       nullptr, nullptr, nullptr, 768, 768, 6, 12);
    ln_kernel<false, true><<<4096, 384, 0, stream>>>(x, aob, ln1_g, ln1_b, nullptr, h1b);
    // ff1+gelu: N=1024 K=768 -> 512 blocks
    gemm2p<2><<<512, 512, 0, stream>>>(h1b, f1T, ff1_b, nullptr, ffa,
                                       nullptr, nullptr, nullptr, 1024, 768, 8, 12);
    // ff2: N=768 K=1024 -> 384 blocks, NT=16, bf16 out (reuse aob)
    gemm2p<1><<<384, 512, 0, stream>>>(ffa, f2T, ff2_b, nullptr, aob,
                                       nullptr, nullptr, nullptr, 768, 1024, 6, 16);
    ln_kernel<true, true><<<4096, 384, 0, stream>>>(h1b, aob, ln2_g, ln2_b, (float*)d_out, nullptr);
}

// Round 12
// 197.051 us; speedup vs baseline: 1.2308x; 1.0291x over previous
//
#include <hip/hip_runtime.h>

typedef short short8 __attribute__((ext_vector_type(8)));
typedef unsigned short ushort8v __attribute__((ext_vector_type(8)));
typedef float f32x4 __attribute__((ext_vector_type(4)));

static __device__ __forceinline__ unsigned short f2b(float f) {
    unsigned int u = __builtin_bit_cast(unsigned int, f);
    unsigned int r = (u + 0x7fffu + ((u >> 16) & 1u)) >> 16;
    return (unsigned short)r;
}
static __device__ __forceinline__ unsigned short f2b_trunc(float f) {
    return (unsigned short)(__builtin_bit_cast(unsigned int, f) >> 16);
}
static __device__ __forceinline__ float b2f(unsigned short u) {
    return __builtin_bit_cast(float, (unsigned int)u << 16);
}
static __device__ __forceinline__ float exp2v(float x) {
    float r;
    asm("v_exp_f32 %0, %1" : "=v"(r) : "v"(x));
    return r;
}

__device__ __forceinline__ void gload16(void* lds, const void* g) {
    __builtin_amdgcn_global_load_lds(
        (const __attribute__((address_space(1))) void*)g,
        (__attribute__((address_space(3))) void*)lds, 16, 0, 0);
}

#define L2E 1.4426950408889634f

// ---------------- fused prep: cvt x (f32->bf16) + 4 weight transposes ----------------
__global__ __launch_bounds__(256) void prep_kernel(
    const float* __restrict__ x, unsigned short* __restrict__ xb,
    const float* __restrict__ qkv_w, unsigned short* __restrict__ qwT,
    const float* __restrict__ out_w, unsigned short* __restrict__ owT,
    const float* __restrict__ ff1_w, unsigned short* __restrict__ f1T,
    const float* __restrict__ ff2_w, unsigned short* __restrict__ f2T) {
    const int bx = blockIdx.x;
    const int tid = threadIdx.x;
    if (bx < 6144) {  // cvt x
        int i = bx * 256 + tid;
        float4 f = ((const float4*)x)[i];
        ushort4 u;
        u.x = f2b(f.x); u.y = f2b(f.y); u.z = f2b(f.z); u.w = f2b(f.w);
        ((ushort4*)xb)[i] = u;
        return;
    }
    __shared__ float t[32][33];
    int rb = bx - 6144;
    const float* W; unsigned short* Wt; int K, N;
    if (rb < 1728)      { W = qkv_w; Wt = qwT; K = 768;  N = 2304; }
    else if (rb < 2304) { rb -= 1728; W = out_w; Wt = owT; K = 768;  N = 768; }
    else if (rb < 3072) { rb -= 2304; W = ff1_w; Wt = f1T; K = 768;  N = 1024; }
    else                { rb -= 3072; W = ff2_w; Wt = f2T; K = 1024; N = 768; }
    const int nbl = N / 32;
    const int nb = (rb % nbl) * 32, kb = (rb / nbl) * 32;
    const int tx = tid & 31, ty = tid >> 5;
#pragma unroll
    for (int i = 0; i < 32; i += 8)
        t[ty + i][tx] = W[(size_t)(kb + ty + i) * N + nb + tx];
    __syncthreads();
#pragma unroll
    for (int i = 0; i < 32; i += 8)
        Wt[(size_t)(nb + ty + i) * K + kb + tx] = f2b(t[tx][ty + i]);
}

// ---------------- 128x128 BK=64 2-phase GEMM, 8 waves (64x32 per wave) ----------------
// EPI: 0 = f32 out, 1 = bf16 out, 2 = gelu->bf16 out, 3 = qkv scatter (width-96 Q/K)
template <int EPI>
__global__ __launch_bounds__(512, 4) void gemm2p(
    const unsigned short* __restrict__ A, const unsigned short* __restrict__ Bt,
    const float* __restrict__ bias, float* __restrict__ outf,
    unsigned short* __restrict__ outb, unsigned short* __restrict__ q_o,
    unsigned short* __restrict__ k_o, unsigned short* __restrict__ v_o,
    int N, int K, int ntn, int NT) {
    __shared__ unsigned short a_lds[2][8192];
    __shared__ unsigned short b_lds[2][8192];
    const int tid = threadIdx.x;
    const int wave = tid >> 6, lane = tid & 63;
    const int lr = lane & 15, lg = lane >> 4;
    const int wm = wave >> 2, wn = wave & 3;
    const int nwg = gridDim.x;
    const int orig = blockIdx.x;
    const int swz = (orig & 7) * (nwg >> 3) + (orig >> 3);
    const int tm = swz / ntn, tn = swz % ntn;

    const unsigned short* srcA[2];
    const unsigned short* srcB[2];
#pragma unroll
    for (int i = 0; i < 2; ++i) {
        int g = i * 512 + tid;
        int row = g >> 3, sl = g & 7;
        int colg = sl ^ (row & 7);
        srcA[i] = A + (size_t)(tm * 128 + row) * K + colg * 8;
        srcB[i] = Bt + (size_t)(tn * 128 + row) * K + colg * 8;
    }
    auto stage = [&](int buf, int k0) {
#pragma unroll
        for (int i = 0; i < 2; ++i) {
            gload16(&a_lds[buf][i * 4096 + wave * 512], srcA[i] + k0);
            gload16(&b_lds[buf][i * 4096 + wave * 512], srcB[i] + k0);
        }
    };

    f32x4 acc[4][2] = {};

    stage(0, 0);
    asm volatile("s_waitcnt vmcnt(0)" ::: "memory");
    __builtin_amdgcn_s_barrier();

    for (int t = 0; t < NT; ++t) {
        const int buf = t & 1;
        if (t + 1 < NT) stage(buf ^ 1, (t + 1) * 64);
#pragma unroll
        for (int ks = 0; ks < 2; ++ks) {
            short8 af[4], bfr[2];
#pragma unroll
            for (int mf = 0; mf < 4; ++mf) {
                int row = wm * 64 + mf * 16 + lr;
                int slot = (ks * 4 + lg) ^ (row & 7);
                af[mf] = *(const short8*)&a_lds[buf][row * 64 + slot * 8];
            }
#pragma unroll
            for (int nf = 0; nf < 2; ++nf) {
                int row = wn * 32 + nf * 16 + lr;
                int slot = (ks * 4 + lg) ^ (row & 7);
                bfr[nf] = *(const short8*)&b_lds[buf][row * 64 + slot * 8];
            }
#pragma unroll
            for (int mf = 0; mf < 4; ++mf)
#pragma unroll
                for (int nf = 0; nf < 2; ++nf)
                    acc[mf][nf] = __builtin_amdgcn_mfma_f32_16x16x32_bf16(af[mf], bfr[nf], acc[mf][nf], 0, 0, 0);
        }
        asm volatile("s_waitcnt vmcnt(0)" ::: "memory");
        __builtin_amdgcn_s_barrier();
    }

#pragma unroll
    for (int nf = 0; nf < 2; ++nf) {
        int gc = tn * 128 + wn * 32 + nf * 16 + lr;
        float bv = bias[gc];
        int part = 0, h = 0, dh = 0;
        if constexpr (EPI == 3) {
            part = gc / 768;
            int cc = gc - part * 768;
            h = cc / 96;
            dh = cc - h * 96;
        }
#pragma unroll
        for (int mf = 0; mf < 4; ++mf) {
            int grb = tm * 128 + wm * 64 + mf * 16 + lg * 4;
            if constexpr (EPI == 3) {
                int b = grb >> 10, n2 = grb & 1023;
                size_t bh = (size_t)(b * 8 + h);
                if (part == 2) {
                    ushort4 wv;
                    wv.x = f2b(acc[mf][nf][0] + bv);
                    wv.y = f2b(acc[mf][nf][1] + bv);
                    wv.z = f2b(acc[mf][nf][2] + bv);
                    wv.w = f2b(acc[mf][nf][3] + bv);
                    *(ushort4*)&v_o[(bh * 96 + dh) * 1024 + n2] = wv;
                } else {
                    unsigned short* dst = (part == 0) ? q_o : k_o;
                    float sc = (part == 0) ? 0.14724445f : 1.f;
#pragma unroll
                    for (int r = 0; r < 4; ++r)
                        dst[(bh * 1024 + n2 + r) * 96 + dh] = f2b((acc[mf][nf][r] + bv) * sc);
                }
            } else {
#pragma unroll
                for (int r = 0; r < 4; ++r) {
                    int gr = grb + r;
                    float v = acc[mf][nf][r] + bv;
                    if constexpr (EPI == 0) {
                        outf[(size_t)gr * N + gc] = v;
                    } else if constexpr (EPI == 1) {
                        outb[(size_t)gr * N + gc] = f2b(v);
                    } else {
                        float gl = 0.5f * v * (1.f + erff(v * 0.70710678f));
                        outb[(size_t)gr * N + gc] = f2b(gl);
                    }
                }
            }
        }
    }
}

// ---------------- flash attention: 8 waves x 16 q-rows, width-96 Q/K, in-reg aug -------
// Q,K: [64][1024][96] bf16 (Q pre-scaled by 1/sqrt(96)*L2E) ; Vt: [64][96][1024] bf16
__global__ __launch_bounds__(512, 4) void attn_kernel(
    const unsigned short* __restrict__ Qb, const unsigned short* __restrict__ Kb,
    const unsigned short* __restrict__ Vt, const float* __restrict__ centers,
    const int* __restrict__ types, const int* __restrict__ nmask,
    const float* __restrict__ tt, const float* __restrict__ rel_emb,
    unsigned short* __restrict__ Y) {
    __shared__ unsigned short kv_lds[2 * 12288];  // 48 KB
    __shared__ unsigned short p_lds[8 * 1024];    // 16 KB
    __shared__ float c_lds[1024];                 // 4 KB
    __shared__ unsigned int bab_lds[1024];        // 4 KB packed (bA,bB) bf16 pairs
    __shared__ float rel_lds[41];

    const int tid = threadIdx.x;
    const int wave = tid >> 6, lane = tid & 63;
    const int lr = lane & 15, lg = lane >> 4;
    const int bh = blockIdx.x, qb = blockIdx.y;
    const int b = bh >> 3, h = bh & 7;
    const int q0 = qb * 128 + wave * 16;
    const size_t kvbase = (size_t)bh * 1024 * 96;

    // ---- prologue: centers, rel table, packed type/mask bias table ----
    c_lds[tid] = centers[b * 1024 + tid];
    c_lds[tid + 512] = centers[b * 1024 + 512 + tid];
    if (tid < 41) rel_lds[tid] = rel_emb[tid * 8 + h] * L2E;
    {
        const float t00 = tt[h * 4], t01 = tt[h * 4 + 1];
        const float t10 = tt[h * 4 + 2], t11 = tt[h * 4 + 3];
#pragma unroll
        for (int i = 0; i < 2; ++i) {
            int j = tid + i * 512;
            int tj = types[b * 1024 + j];
            int mk = nmask[b * 1024 + j];
            float bA = L2E * (t00 + (t01 - t00) * tj) + (mk ? 0.f : -1e30f);
            float bB = L2E * ((t10 - t00) + (t11 - t01 - t10 + t00) * tj);
            bab_lds[j] = (unsigned)f2b(bA) | ((unsigned)f2b(bB) << 16);
        }
    }

    // ---- per-lane pre-swizzled staging sources: 1536 granules = 3 x 512 ----
    const unsigned short* sbase[3];
    int sstep[3];
#pragma unroll
    for (int it = 0; it < 3; ++it) {
        int g = it * 512 + tid;
        if (g < 768) {  // K granule
            int ks = g >> 8, rem = g & 255, pr = rem >> 3, sl = rem & 7;
            int so = sl ^ (pr & 7);
            int r = ((so >> 2) << 5) + pr, oct = so & 3;
            sbase[it] = Kb + kvbase + (size_t)r * 96 + ks * 32 + oct * 8;
            sstep[it] = 64 * 96;
        } else {  // V granule
            int gv = g - 768, pr = gv >> 3, sl = gv & 7;
            int so = sl ^ (pr & 7);
            sbase[it] = Vt + (size_t)(bh * 96 + pr) * 1024 + so * 8;
            sstep[it] = 64;
        }
    }
    auto stage = [&](int bufb, int kt) {
        unsigned short* dst = kv_lds + bufb * 12288;
#pragma unroll
        for (int it = 0; it < 3; ++it)
            gload16(dst + it * 4096 + wave * 512, sbase[it] + (size_t)kt * sstep[it]);
    };

    // ---- Q fragments (3 ks) + in-register aug A-fragment ----
    short8 qa[3];
#pragma unroll
    for (int ks = 0; ks < 3; ++ks)
        qa[ks] = *(const short8*)&Qb[kvbase + (size_t)(q0 + lr) * 96 + ks * 32 + lg * 8];
    short8 qa3 = {};
    {
        int ti0 = types[b * 1024 + q0 + lr];
        if (lg == 0) {
            qa3[0] = (short)0x3F80;
            qa3[1] = ti0 ? (short)0x3F80 : (short)0;
        }
    }
    float ci20[4];
#pragma unroll
    for (int r = 0; r < 4; ++r) ci20[r] = centers[b * 1024 + q0 + lg * 4 + r] + 20.f;

    // wave-level ci range (loop-invariant; ci20 varies only with lg -> butterfly bits 4,5)
    float cimax20 = fmaxf(fmaxf(ci20[0], ci20[1]), fmaxf(ci20[2], ci20[3]));
    float cimin20 = fminf(fminf(ci20[0], ci20[1]), fminf(ci20[2], ci20[3]));
    cimax20 = fmaxf(cimax20, __shfl_xor(cimax20, 16));
    cimax20 = fmaxf(cimax20, __shfl_xor(cimax20, 32));
    cimin20 = fminf(cimin20, __shfl_xor(cimin20, 16));
    cimin20 = fminf(cimin20, __shfl_xor(cimin20, 32));

    short8 vone = {};
    if (lr == 0) {
#pragma unroll
        for (int e = 0; e < 8; ++e) vone[e] = (short)0x3F80;
    }

    float m_r[4] = {-3e30f, -3e30f, -3e30f, -3e30f};
    f32x4 oacc[7] = {};

    stage(0, 0);
    asm volatile("s_waitcnt lgkmcnt(0)" ::: "memory");  // drain c/bab/rel ds_writes
    const float rel0v = rel_lds[0], rel40v = rel_lds[40];

    for (int kt = 0; kt < 16; ++kt) {
        const int buf = kt & 1;
        if (kt < 15) {
            stage(buf ^ 1, kt + 1);
            asm volatile("s_waitcnt vmcnt(3)" ::: "memory");
        } else {
            asm volatile("s_waitcnt vmcnt(0)" ::: "memory");
        }
        __builtin_amdgcn_s_barrier();
        const unsigned short* kv = kv_lds + buf * 12288;

        // ---- QK^T: 3 ks from LDS + aug from registers ----
        f32x4 s[4] = {};
#pragma unroll
        for (int jf = 0; jf < 4; ++jf) {
            int pr = ((jf & 1) << 4) + lr;
            int slp = (((jf >> 1) << 2) + lg) ^ (lr & 7);
#pragma unroll
            for (int ks = 0; ks < 3; ++ks) {
                short8 kf = *(const short8*)&kv[ks * 2048 + pr * 64 + slp * 8];
                s[jf] = __builtin_amdgcn_mfma_f32_16x16x32_bf16(qa[ks], kf, s[jf], 0, 0, 0);
            }
            unsigned vb = bab_lds[kt * 64 + jf * 16 + lr];
            short8 kf3 = {};
            if (lg == 0) {
                kf3[0] = (short)(vb & 0xffffu);
                kf3[1] = (short)(vb >> 16);
            }
            s[jf] = __builtin_amdgcn_mfma_f32_16x16x32_bf16(qa3, kf3, s[jf], 0, 0, 0);
        }

        // ---- rel bias: wave-level flat-tile band check (data-adaptive, wave-uniform) ----
        {
            float cj[4];
#pragma unroll
            for (int jf = 0; jf < 4; ++jf) cj[jf] = c_lds[kt * 64 + jf * 16 + lr];
            float cjmx = fmaxf(fmaxf(cj[0], cj[1]), fmaxf(cj[2], cj[3]));
            float cjmn = fminf(fminf(cj[0], cj[1]), fminf(cj[2], cj[3]));
#pragma unroll
            for (int off = 1; off < 16; off <<= 1) {
                cjmx = fmaxf(cjmx, __shfl_xor(cjmx, off));
                cjmn = fminf(cjmn, __shfl_xor(cjmn, off));
            }
            bool flatHi = (cimin20 - cjmx >= 40.f);  // all d >= +20 -> idx 40
            bool flatLo = (cimax20 - cjmn <= 0.f);   // all d <= -20 -> idx 0
            if (flatHi || flatLo) {
                float re = flatHi ? rel40v : rel0v;
#pragma unroll
                for (int jf = 0; jf < 4; ++jf)
#pragma unroll
                    for (int r = 0; r < 4; ++r) s[jf][r] += re;
            } else {
#pragma unroll
                for (int jf = 0; jf < 4; ++jf)
#pragma unroll
                    for (int r = 0; r < 4; ++r) {
                        float idxf = __builtin_amdgcn_fmed3f(ci20[r] - cj[jf], 0.f, 40.f);
                        s[jf][r] += rel_lds[(int)rintf(idxf)];
                    }
            }
        }

        // ---- online softmax (exp2, defer-max THR=8, cheap lane-local trigger) ----
#pragma unroll
        for (int r = 0; r < 4; ++r) {
            float mlr = fmaxf(fmaxf(s[0][r], s[1][r]), fmaxf(s[2][r], s[3][r]));
            if (!__all(mlr <= m_r[r] + 8.f)) {
                float mx = mlr;
#pragma unroll
                for (int off = 1; off < 16; off <<= 1) mx = fmaxf(mx, __shfl_xor(mx, off));
                float mn = fmaxf(m_r[r], mx);
                float al = exp2v(m_r[r] - mn);
                m_r[r] = mn;
#pragma unroll
                for (int nf = 0; nf < 7; ++nf) oacc[nf][r] *= al;
            }
#pragma unroll
            for (int jf = 0; jf < 4; ++jf) s[jf][r] = exp2v(s[jf][r] - m_r[r]);
        }

        // ---- P (C/D layout) -> swizzled LDS -> A-fragment ----
#pragma unroll
        for (int jf = 0; jf < 4; ++jf)
#pragma unroll
            for (int r = 0; r < 4; ++r) {
                int row = lg * 4 + r, col = jf * 16 + lr;
                int gp = (col >> 3) ^ (row & 7);
                p_lds[wave * 1024 + row * 64 + gp * 8 + (col & 7)] = f2b_trunc(s[jf][r]);
            }
        asm volatile("s_waitcnt lgkmcnt(0)" ::: "memory");
        short8 pa[2];
#pragma unroll
        for (int js = 0; js < 2; ++js) {
            int slp = ((js << 2) + lg) ^ (lr & 7);
            pa[js] = *(const short8*)&p_lds[wave * 1024 + lr * 64 + slp * 8];
        }

        // ---- PV (+ l via ones-fragment) ----
#pragma unroll
        for (int nf = 0; nf < 6; ++nf) {
            int vrow = nf * 16 + lr;
#pragma unroll
            for (int js = 0; js < 2; ++js) {
                int slp = ((js << 2) + lg) ^ (lr & 7);
                short8 vf = *(const short8*)&kv[6144 + vrow * 64 + slp * 8];
                oacc[nf] = __builtin_amdgcn_mfma_f32_16x16x32_bf16(pa[js], vf, oacc[nf], 0, 0, 0);
            }
        }
#pragma unroll
        for (int js = 0; js < 2; ++js)
            oacc[6] = __builtin_amdgcn_mfma_f32_16x16x32_bf16(pa[js], vone, oacc[6], 0, 0, 0);
        __builtin_amdgcn_s_barrier();
    }

#pragma unroll
    for (int r = 0; r < 4; ++r) {
        float l = __shfl(oacc[6][r], lane & 48);
        float inv = (l > 0.f) ? 1.f / l : 0.f;
        int qi = q0 + lg * 4 + r;
#pragma unroll
        for (int nf = 0; nf < 6; ++nf)
            Y[((size_t)b * 1024 + qi) * 768 + h * 96 + nf * 16 + lr] = f2b(oacc[nf][r] * inv);
    }
}

// ---------------- layernorm with residual add (vectorized, 2 rows/block) ----------------
template <bool IN1BF, bool IN2BF>
__global__ __launch_bounds__(384) void ln_kernel(const void* __restrict__ in1,
                                                 const void* __restrict__ in2,
                                                 const float* __restrict__ g,
                                                 const float* __restrict__ be,
                                                 float* __restrict__ of,
                                                 unsigned short* __restrict__ ob) {
    const int tid = threadIdx.x;
    const int half = tid / 192;
    const int t = tid - half * 192;
    const int row = blockIdx.x * 2 + half;
    const size_t base = (size_t)row * 768 + t * 4;
    float a[4], bb[4];
    if (IN1BF) {
        ushort4 u = *(const ushort4*)((const unsigned short*)in1 + base);
        a[0] = b2f(u.x); a[1] = b2f(u.y); a[2] = b2f(u.z); a[3] = b2f(u.w);
    } else {
        float4 u = *(const float4*)((const float*)in1 + base);
        a[0] = u.x; a[1] = u.y; a[2] = u.z; a[3] = u.w;
    }
    if (IN2BF) {
        ushort4 u = *(const ushort4*)((const unsigned short*)in2 + base);
        bb[0] = b2f(u.x); bb[1] = b2f(u.y); bb[2] = b2f(u.z); bb[3] = b2f(u.w);
    } else {
        float4 u = *(const float4*)((const float*)in2 + base);
        bb[0] = u.x; bb[1] = u.y; bb[2] = u.z; bb[3] = u.w;
    }
    float v[4];
#pragma unroll
    for (int i = 0; i < 4; ++i) v[i] = a[i] + bb[i];
    float s1 = v[0] + v[1] + v[2] + v[3];
    float s2 = v[0] * v[0] + v[1] * v[1] + v[2] * v[2] + v[3] * v[3];
#pragma unroll
    for (int off = 32; off > 0; off >>= 1) {
        s1 += __shfl_xor(s1, off);
        s2 += __shfl_xor(s2, off);
    }
    __shared__ float red[12];
    const int wv = tid >> 6;
    if ((tid & 63) == 0) { red[wv] = s1; red[6 + wv] = s2; }
    __syncthreads();
    const int w0 = half * 3;
    s1 = red[w0] + red[w0 + 1] + red[w0 + 2];
    s2 = red[6 + w0] + red[6 + w0 + 1] + red[6 + w0 + 2];
    float mu = s1 * (1.f / 768.f);
    float var = s2 * (1.f / 768.f) - mu * mu;
    float inv = rsqrtf(var + 1e-5f);
    float o[4];
#pragma unroll
    for (int i = 0; i < 4; ++i)
        o[i] = (v[i] - mu) * inv * g[t * 4 + i] + be[t * 4 + i];
    if (of) {
        float4 w = {o[0], o[1], o[2], o[3]};
        *(float4*)(of + base) = w;
    }
    if (ob) {
        ushort4 w = {f2b(o[0]), f2b(o[1]), f2b(o[2]), f2b(o[3])};
        *(ushort4*)(ob + base) = w;
    }
}

extern "C" void kernel_launch(void* const* d_in, const int* in_sizes, int n_in,
                              void* d_out, int out_size, void* d_ws, size_t ws_size,
                              hipStream_t stream) {
    const float* x     = (const float*)d_in[0];
    const int*   nmask = (const int*)d_in[1];
    const float* cent  = (const float*)d_in[2];
    const int*   types = (const int*)d_in[3];
    const float* qkv_w = (const float*)d_in[4];
    const float* qkv_b = (const float*)d_in[5];
    const float* out_w = (const float*)d_in[6];
    const float* out_b = (const float*)d_in[7];
    const float* ff1_w = (const float*)d_in[8];
    const float* ff1_b = (const float*)d_in[9];
    const float* ff2_w = (const float*)d_in[10];
    const float* ff2_b = (const float*)d_in[11];
    const float* ln1_g = (const float*)d_in[12];
    const float* ln1_b = (const float*)d_in[13];
    const float* ln2_g = (const float*)d_in[14];
    const float* ln2_b = (const float*)d_in[15];
    const float* rel   = (const float*)d_in[16];
    const float* ttp   = (const float*)d_in[17];

    char* w = (char*)d_ws;
    auto alloc = [&](size_t bytes) {
        char* p = w;
        w += (bytes + 255) & ~(size_t)255;
        return p;
    };
    unsigned short* xb  = (unsigned short*)alloc(8192ull * 768 * 2);   // x bf16; reused as Y
    unsigned short* qwT = (unsigned short*)alloc(2304ull * 768 * 2);
    unsigned short* owT = (unsigned short*)alloc(768ull * 768 * 2);
    unsigned short* f1T = (unsigned short*)alloc(1024ull * 768 * 2);
    unsigned short* f2T = (unsigned short*)alloc(768ull * 1024 * 2);
    unsigned short* Qb  = (unsigned short*)alloc(64ull * 1024 * 96 * 2);
    unsigned short* Kb  = (unsigned short*)alloc(64ull * 1024 * 96 * 2);
    unsigned short* Vt  = (unsigned short*)alloc(64ull * 96 * 1024 * 2);
    unsigned short* aob = (unsigned short*)alloc(8192ull * 768 * 2);  // residual branch (bf16)
    unsigned short* h1b = (unsigned short*)alloc(8192ull * 768 * 2);
    unsigned short* ffa = Qb;  // alias: ff1 act (16.8MB) spans Qb+Kb (25.2MB), both dead after attn

    // fused cvt + 4 transposes: 6144 + 3840 = 9984 blocks
    prep_kernel<<<9984, 256, 0, stream>>>(x, xb, qkv_w, qwT, out_w, owT,
                                          ff1_w, f1T, ff2_w, f2T);

    // QKV: M=8192 N=2304 K=768 -> 64x18 = 1152 blocks
    gemm2p<3><<<1152, 512, 0, stream>>>(xb, qwT, qkv_b, nullptr, nullptr,
                                        Qb, Kb, Vt, 2304, 768, 18, 12);
    attn_kernel<<<dim3(64, 8), 512, 0, stream>>>(Qb, Kb, Vt, cent, types, nmask, ttp, rel, xb);
    // out proj: N=768 K=768 -> 384 blocks, bf16 out
    gemm2p<1><<<384, 512, 0, stream>>>(xb, owT, out_b, nullptr, aob,
                                       nullptr, nullptr, nullptr, 768, 768, 6, 12);
    ln_kernel<false, true><<<4096, 384, 0, stream>>>(x, aob, ln1_g, ln1_b, nullptr, h1b);
    // ff1+gelu: N=1024 K=768 -> 512 blocks
    gemm2p<2><<<512, 512, 0, stream>>>(h1b, f1T, ff1_b, nullptr, ffa,
                                       nullptr, nullptr, nullptr, 1024, 768, 8, 12);
    // ff2: N=768 K=1024 -> 384 blocks, NT=16, bf16 out (reuse aob)
    gemm2p<1><<<384, 512, 0, stream>>>(ffa, f2T, ff2_b, nullptr, aob,
                                       nullptr, nullptr, nullptr, 768, 1024, 6, 16);
    ln_kernel<true, true><<<4096, 384, 0, stream>>>(h1b, aob, ln2_g, ln2_b, (float*)d_out, nullptr);
}

// Round 13
// 186.521 us; speedup vs baseline: 1.3003x; 1.0565x over previous
//
#include <hip/hip_runtime.h>

typedef short short8 __attribute__((ext_vector_type(8)));
typedef unsigned short ushort8v __attribute__((ext_vector_type(8)));
typedef float f32x4 __attribute__((ext_vector_type(4)));

static __device__ __forceinline__ unsigned short f2b(float f) {
    unsigned int u = __builtin_bit_cast(unsigned int, f);
    unsigned int r = (u + 0x7fffu + ((u >> 16) & 1u)) >> 16;
    return (unsigned short)r;
}
static __device__ __forceinline__ float b2f(unsigned short u) {
    return __builtin_bit_cast(float, (unsigned int)u << 16);
}
static __device__ __forceinline__ float exp2v(float x) {
    float r;
    asm("v_exp_f32 %0, %1" : "=v"(r) : "v"(x));
    return r;
}
static __device__ __forceinline__ unsigned cvt_pk_bf16(float lo, float hi) {
    unsigned r;
    asm("v_cvt_pk_bf16_f32 %0, %1, %2" : "=v"(r) : "v"(lo), "v"(hi));
    return r;
}

__device__ __forceinline__ void gload16(void* lds, const void* g) {
    __builtin_amdgcn_global_load_lds(
        (const __attribute__((address_space(1))) void*)g,
        (__attribute__((address_space(3))) void*)lds, 16, 0, 0);
}

#define L2E 1.4426950408889634f

// ---------------- fused prep: cvt x (f32->bf16) + 4 weight transposes ----------------
__global__ __launch_bounds__(256) void prep_kernel(
    const float* __restrict__ x, unsigned short* __restrict__ xb,
    const float* __restrict__ qkv_w, unsigned short* __restrict__ qwT,
    const float* __restrict__ out_w, unsigned short* __restrict__ owT,
    const float* __restrict__ ff1_w, unsigned short* __restrict__ f1T,
    const float* __restrict__ ff2_w, unsigned short* __restrict__ f2T) {
    const int bx = blockIdx.x;
    const int tid = threadIdx.x;
    if (bx < 6144) {  // cvt x
        int i = bx * 256 + tid;
        float4 f = ((const float4*)x)[i];
        ushort4 u;
        u.x = f2b(f.x); u.y = f2b(f.y); u.z = f2b(f.z); u.w = f2b(f.w);
        ((ushort4*)xb)[i] = u;
        return;
    }
    __shared__ float t[32][33];
    int rb = bx - 6144;
    const float* W; unsigned short* Wt; int K, N;
    if (rb < 1728)      { W = qkv_w; Wt = qwT; K = 768;  N = 2304; }
    else if (rb < 2304) { rb -= 1728; W = out_w; Wt = owT; K = 768;  N = 768; }
    else if (rb < 3072) { rb -= 2304; W = ff1_w; Wt = f1T; K = 768;  N = 1024; }
    else                { rb -= 3072; W = ff2_w; Wt = f2T; K = 1024; N = 768; }
    const int nbl = N / 32;
    const int nb = (rb % nbl) * 32, kb = (rb / nbl) * 32;
    const int tx = tid & 31, ty = tid >> 5;
#pragma unroll
    for (int i = 0; i < 32; i += 8)
        t[ty + i][tx] = W[(size_t)(kb + ty + i) * N + nb + tx];
    __syncthreads();
#pragma unroll
    for (int i = 0; i < 32; i += 8)
        Wt[(size_t)(nb + ty + i) * K + kb + tx] = f2b(t[tx][ty + i]);
}

// ---------------- 128x128 BK=64 2-phase GEMM, 8 waves (64x32 per wave) ----------------
// EPI: 0 = f32 out, 1 = bf16 out, 2 = gelu->bf16 out, 3 = qkv scatter (width-96 Q/K)
template <int EPI>
__global__ __launch_bounds__(512, 4) void gemm2p(
    const unsigned short* __restrict__ A, const unsigned short* __restrict__ Bt,
    const float* __restrict__ bias, float* __restrict__ outf,
    unsigned short* __restrict__ outb, unsigned short* __restrict__ q_o,
    unsigned short* __restrict__ k_o, unsigned short* __restrict__ v_o,
    int N, int K, int ntn, int NT) {
    __shared__ unsigned short a_lds[2][8192];
    __shared__ unsigned short b_lds[2][8192];
    const int tid = threadIdx.x;
    const int wave = tid >> 6, lane = tid & 63;
    const int lr = lane & 15, lg = lane >> 4;
    const int wm = wave >> 2, wn = wave & 3;
    const int nwg = gridDim.x;
    const int orig = blockIdx.x;
    const int swz = (orig & 7) * (nwg >> 3) + (orig >> 3);
    const int tm = swz / ntn, tn = swz % ntn;

    const unsigned short* srcA[2];
    const unsigned short* srcB[2];
#pragma unroll
    for (int i = 0; i < 2; ++i) {
        int g = i * 512 + tid;
        int row = g >> 3, sl = g & 7;
        int colg = sl ^ (row & 7);
        srcA[i] = A + (size_t)(tm * 128 + row) * K + colg * 8;
        srcB[i] = Bt + (size_t)(tn * 128 + row) * K + colg * 8;
    }
    auto stage = [&](int buf, int k0) {
#pragma unroll
        for (int i = 0; i < 2; ++i) {
            gload16(&a_lds[buf][i * 4096 + wave * 512], srcA[i] + k0);
            gload16(&b_lds[buf][i * 4096 + wave * 512], srcB[i] + k0);
        }
    };

    f32x4 acc[4][2] = {};

    stage(0, 0);
    asm volatile("s_waitcnt vmcnt(0)" ::: "memory");
    __builtin_amdgcn_s_barrier();

    for (int t = 0; t < NT; ++t) {
        const int buf = t & 1;
        if (t + 1 < NT) stage(buf ^ 1, (t + 1) * 64);
#pragma unroll
        for (int ks = 0; ks < 2; ++ks) {
            short8 af[4], bfr[2];
#pragma unroll
            for (int mf = 0; mf < 4; ++mf) {
                int row = wm * 64 + mf * 16 + lr;
                int slot = (ks * 4 + lg) ^ (row & 7);
                af[mf] = *(const short8*)&a_lds[buf][row * 64 + slot * 8];
            }
#pragma unroll
            for (int nf = 0; nf < 2; ++nf) {
                int row = wn * 32 + nf * 16 + lr;
                int slot = (ks * 4 + lg) ^ (row & 7);
                bfr[nf] = *(const short8*)&b_lds[buf][row * 64 + slot * 8];
            }
#pragma unroll
            for (int mf = 0; mf < 4; ++mf)
#pragma unroll
                for (int nf = 0; nf < 2; ++nf)
                    acc[mf][nf] = __builtin_amdgcn_mfma_f32_16x16x32_bf16(af[mf], bfr[nf], acc[mf][nf], 0, 0, 0);
        }
        asm volatile("s_waitcnt vmcnt(0)" ::: "memory");
        __builtin_amdgcn_s_barrier();
    }

#pragma unroll
    for (int nf = 0; nf < 2; ++nf) {
        int gc = tn * 128 + wn * 32 + nf * 16 + lr;
        float bv = bias[gc];
        int part = 0, h = 0, dh = 0;
        if constexpr (EPI == 3) {
            part = gc / 768;
            int cc = gc - part * 768;
            h = cc / 96;
            dh = cc - h * 96;
        }
#pragma unroll
        for (int mf = 0; mf < 4; ++mf) {
            int grb = tm * 128 + wm * 64 + mf * 16 + lg * 4;
            if constexpr (EPI == 3) {
                int b = grb >> 10, n2 = grb & 1023;
                size_t bh = (size_t)(b * 8 + h);
                if (part == 2) {
                    ushort4 wv;
                    wv.x = f2b(acc[mf][nf][0] + bv);
                    wv.y = f2b(acc[mf][nf][1] + bv);
                    wv.z = f2b(acc[mf][nf][2] + bv);
                    wv.w = f2b(acc[mf][nf][3] + bv);
                    *(ushort4*)&v_o[(bh * 96 + dh) * 1024 + n2] = wv;
                } else {
                    unsigned short* dst = (part == 0) ? q_o : k_o;
                    float sc = (part == 0) ? 0.14724445f : 1.f;
#pragma unroll
                    for (int r = 0; r < 4; ++r)
                        dst[(bh * 1024 + n2 + r) * 96 + dh] = f2b((acc[mf][nf][r] + bv) * sc);
                }
            } else {
#pragma unroll
                for (int r = 0; r < 4; ++r) {
                    int gr = grb + r;
                    float v = acc[mf][nf][r] + bv;
                    if constexpr (EPI == 0) {
                        outf[(size_t)gr * N + gc] = v;
                    } else if constexpr (EPI == 1) {
                        outb[(size_t)gr * N + gc] = f2b(v);
                    } else {
                        float gl = 0.5f * v * (1.f + erff(v * 0.70710678f));
                        outb[(size_t)gr * N + gc] = f2b(gl);
                    }
                }
            }
        }
    }
}

// ---------------- flash attention: swapped QK^T (q lane-local), in-reg P pack ----------
// Q,K: [64][1024][96] bf16 (Q pre-scaled by 1/sqrt(96)*L2E) ; Vt: [64][96][1024] bf16
// Per tile, lane holds S[q=q0+lr][k=jf*16+lg*4+r]. P packed via v_cvt_pk_bf16_f32,
// stored as 4 ds_write_b64 into word layout [q][k/2] (granule ^ (lr&14) swizzle),
// read back as 2 ds_read_b128 A-fragments. l-sum in-lane (+2 shfl), no ones-MFMA.
__global__ __launch_bounds__(512, 4) void attn_kernel(
    const unsigned short* __restrict__ Qb, const unsigned short* __restrict__ Kb,
    const unsigned short* __restrict__ Vt, const float* __restrict__ centers,
    const int* __restrict__ types, const int* __restrict__ nmask,
    const float* __restrict__ tt, const float* __restrict__ rel_emb,
    unsigned short* __restrict__ Y) {
    __shared__ unsigned short kv_lds[2 * 12288];  // 48 KB
    __shared__ unsigned short p_lds[8 * 1024];    // 16 KB (per-wave 16q x 64k bf16)
    __shared__ float c_lds[1024];                 // 4 KB
    __shared__ unsigned int bab_lds[1024];        // 4 KB packed (bA,bB) bf16 pairs
    __shared__ float rel_lds[41];

    const int tid = threadIdx.x;
    const int wave = tid >> 6, lane = tid & 63;
    const int lr = lane & 15, lg = lane >> 4;
    const int bh = blockIdx.x, qb = blockIdx.y;
    const int b = bh >> 3, h = bh & 7;
    const int q0 = qb * 128 + wave * 16;
    const size_t kvbase = (size_t)bh * 1024 * 96;

    // ---- prologue: centers, rel table, packed type/mask bias table ----
    c_lds[tid] = centers[b * 1024 + tid];
    c_lds[tid + 512] = centers[b * 1024 + 512 + tid];
    if (tid < 41) rel_lds[tid] = rel_emb[tid * 8 + h] * L2E;
    {
        const float t00 = tt[h * 4], t01 = tt[h * 4 + 1];
        const float t10 = tt[h * 4 + 2], t11 = tt[h * 4 + 3];
#pragma unroll
        for (int i = 0; i < 2; ++i) {
            int j = tid + i * 512;
            int tj = types[b * 1024 + j];
            int mk = nmask[b * 1024 + j];
            float bA = L2E * (t00 + (t01 - t00) * tj) + (mk ? 0.f : -1e30f);
            float bB = L2E * ((t10 - t00) + (t11 - t01 - t10 + t00) * tj);
            bab_lds[j] = (unsigned)f2b(bA) | ((unsigned)f2b(bB) << 16);
        }
    }

    // ---- per-lane pre-swizzled staging sources: 1536 granules = 3 x 512 ----
    const unsigned short* sbase[3];
    int sstep[3];
#pragma unroll
    for (int it = 0; it < 3; ++it) {
        int g = it * 512 + tid;
        if (g < 768) {  // K granule
            int ks = g >> 8, rem = g & 255, pr = rem >> 3, sl = rem & 7;
            int so = sl ^ (pr & 7);
            int r = ((so >> 2) << 5) + pr, oct = so & 3;
            sbase[it] = Kb + kvbase + (size_t)r * 96 + ks * 32 + oct * 8;
            sstep[it] = 64 * 96;
        } else {  // V granule
            int gv = g - 768, pr = gv >> 3, sl = gv & 7;
            int so = sl ^ (pr & 7);
            sbase[it] = Vt + (size_t)(bh * 96 + pr) * 1024 + so * 8;
            sstep[it] = 64;
        }
    }
    auto stage = [&](int bufb, int kt) {
        unsigned short* dst = kv_lds + bufb * 12288;
#pragma unroll
        for (int it = 0; it < 3; ++it)
            gload16(dst + it * 4096 + wave * 512, sbase[it] + (size_t)kt * sstep[it]);
    };

    // ---- Q fragments (3 ks) + in-register aug B-fragment ----
    short8 qa[3];
#pragma unroll
    for (int ks = 0; ks < 3; ++ks)
        qa[ks] = *(const short8*)&Qb[kvbase + (size_t)(q0 + lr) * 96 + ks * 32 + lg * 8];
    short8 qa3 = {};
    {
        int ti0 = types[b * 1024 + q0 + lr];
        if (lg == 0) {
            qa3[0] = (short)0x3F80;
            qa3[1] = ti0 ? (short)0x3F80 : (short)0;
        }
    }
    // per-lane q center (q = q0 + lr)
    const float ci20 = centers[b * 1024 + q0 + lr] + 20.f;
    // wave-level ci range (loop-invariant; varies with lr -> butterfly bits 0..3)
    float cimax20 = ci20, cimin20 = ci20;
#pragma unroll
    for (int off = 1; off < 16; off <<= 1) {
        cimax20 = fmaxf(cimax20, __shfl_xor(cimax20, off));
        cimin20 = fminf(cimin20, __shfl_xor(cimin20, off));
    }

    float m_s = -3e30f, l_s = 0.f;
    f32x4 oacc[6] = {};
    unsigned* p32 = (unsigned*)&p_lds[wave * 1024];

    stage(0, 0);
    asm volatile("s_waitcnt lgkmcnt(0)" ::: "memory");  // drain c/bab/rel ds_writes
    const float rel0v = rel_lds[0], rel40v = rel_lds[40];

    for (int kt = 0; kt < 16; ++kt) {
        const int buf = kt & 1;
        if (kt < 15) {
            stage(buf ^ 1, kt + 1);
            asm volatile("s_waitcnt vmcnt(3)" ::: "memory");
        } else {
            asm volatile("s_waitcnt vmcnt(0)" ::: "memory");
        }
        __builtin_amdgcn_s_barrier();
        const unsigned short* kv = kv_lds + buf * 12288;

        // ---- swapped QK^T: s[jf][r] = S[q=q0+lr][k = jf*16 + lg*4 + r] ----
        f32x4 s[4] = {};
#pragma unroll
        for (int jf = 0; jf < 4; ++jf) {
            int pr = ((jf & 1) << 4) + lr;
            int slp = (((jf >> 1) << 2) + lg) ^ (lr & 7);
#pragma unroll
            for (int ks = 0; ks < 3; ++ks) {
                short8 kf = *(const short8*)&kv[ks * 2048 + pr * 64 + slp * 8];
                s[jf] = __builtin_amdgcn_mfma_f32_16x16x32_bf16(kf, qa[ks], s[jf], 0, 0, 0);
            }
            unsigned vb = bab_lds[kt * 64 + jf * 16 + lr];
            short8 kf3 = {};
            if (lg == 0) {
                kf3[0] = (short)(vb & 0xffffu);
                kf3[1] = (short)(vb >> 16);
            }
            s[jf] = __builtin_amdgcn_mfma_f32_16x16x32_bf16(kf3, qa3, s[jf], 0, 0, 0);
        }

        // ---- rel bias: flat-tile band check; cj = c_lds[k] broadcast float4 per jf ----
        {
            float4 cj4[4];
#pragma unroll
            for (int jf = 0; jf < 4; ++jf)
                cj4[jf] = *(const float4*)&c_lds[kt * 64 + jf * 16 + lg * 4];
            float cjmx = cj4[0].x, cjmn = cj4[0].x;
#pragma unroll
            for (int jf = 0; jf < 4; ++jf) {
                cjmx = fmaxf(cjmx, fmaxf(fmaxf(cj4[jf].x, cj4[jf].y), fmaxf(cj4[jf].z, cj4[jf].w)));
                cjmn = fminf(cjmn, fminf(fminf(cj4[jf].x, cj4[jf].y), fminf(cj4[jf].z, cj4[jf].w)));
            }
            cjmx = fmaxf(cjmx, __shfl_xor(cjmx, 16));
            cjmx = fmaxf(cjmx, __shfl_xor(cjmx, 32));
            cjmn = fminf(cjmn, __shfl_xor(cjmn, 16));
            cjmn = fminf(cjmn, __shfl_xor(cjmn, 32));
            bool flatHi = (cimin20 - cjmx >= 40.f);
            bool flatLo = (cimax20 - cjmn <= 0.f);
            if (flatHi || flatLo) {
                float re = flatHi ? rel40v : rel0v;
#pragma unroll
                for (int jf = 0; jf < 4; ++jf)
#pragma unroll
                    for (int r = 0; r < 4; ++r) s[jf][r] += re;
            } else {
                float cjl[4][4] = {{cj4[0].x, cj4[0].y, cj4[0].z, cj4[0].w},
                                   {cj4[1].x, cj4[1].y, cj4[1].z, cj4[1].w},
                                   {cj4[2].x, cj4[2].y, cj4[2].z, cj4[2].w},
                                   {cj4[3].x, cj4[3].y, cj4[3].z, cj4[3].w}};
#pragma unroll
                for (int jf = 0; jf < 4; ++jf)
#pragma unroll
                    for (int r = 0; r < 4; ++r) {
                        float idxf = __builtin_amdgcn_fmed3f(ci20 - cjl[jf][r], 0.f, 40.f);
                        s[jf][r] += rel_lds[(int)rintf(idxf)];
                    }
            }
        }

        // ---- online softmax, q lane-local (defer-max THR=8) ----
        {
            float mlr = s[0][0];
#pragma unroll
            for (int jf = 0; jf < 4; ++jf)
#pragma unroll
                for (int r = 0; r < 4; ++r) mlr = fmaxf(mlr, s[jf][r]);
            if (!__all(mlr <= m_s + 8.f)) {
                float mx = fmaxf(mlr, __shfl_xor(mlr, 16));
                mx = fmaxf(mx, __shfl_xor(mx, 32));
                float mn = fmaxf(m_s, mx);
                float al = exp2v(m_s - mn);
                m_s = mn;
                l_s *= al;
#pragma unroll
                for (int r = 0; r < 4; ++r) {
                    float alr = __shfl(al, lg * 4 + r);  // al for oacc row q-sub lg*4+r
#pragma unroll
                    for (int nf = 0; nf < 6; ++nf) oacc[nf][r] *= alr;
                }
            }
            float ls = 0.f;
#pragma unroll
            for (int jf = 0; jf < 4; ++jf)
#pragma unroll
                for (int r = 0; r < 4; ++r) {
                    s[jf][r] = exp2v(s[jf][r] - m_s);
                    ls += s[jf][r];
                }
            ls += __shfl_xor(ls, 16);
            ls += __shfl_xor(ls, 32);
            l_s += ls;
        }

        // ---- P pack (cvt_pk) -> 4 x ds_write_b64 -> 2 x ds_read_b128 A-frags ----
#pragma unroll
        for (int jf = 0; jf < 4; ++jf) {
            uint2 w2;
            w2.x = cvt_pk_bf16(s[jf][0], s[jf][1]);
            w2.y = cvt_pk_bf16(s[jf][2], s[jf][3]);
            int gsw = ((jf * 4 + lg) ^ (lr & 14)) * 2;  // word offset in row
            *(uint2*)&p32[lr * 32 + gsw] = w2;
        }
        asm volatile("s_waitcnt lgkmcnt(0)" ::: "memory");
        short8 pa[2];
#pragma unroll
        for (int js = 0; js < 2; ++js) {
            int gsw = (((js * 8 + lg * 2) ^ (lr & 14))) * 2;
            pa[js] = *(const short8*)&p32[lr * 32 + gsw];
        }

        // ---- PV ----
#pragma unroll
        for (int nf = 0; nf < 6; ++nf) {
            int vrow = nf * 16 + lr;
#pragma unroll
            for (int js = 0; js < 2; ++js) {
                int slp = ((js << 2) + lg) ^ (lr & 7);
                short8 vf = *(const short8*)&kv[6144 + vrow * 64 + slp * 8];
                oacc[nf] = __builtin_amdgcn_mfma_f32_16x16x32_bf16(pa[js], vf, oacc[nf], 0, 0, 0);
            }
        }
        __builtin_amdgcn_s_barrier();
    }

#pragma unroll
    for (int r = 0; r < 4; ++r) {
        float lrow = __shfl(l_s, lg * 4 + r);
        float inv = (lrow > 0.f) ? 1.f / lrow : 0.f;
        int qi = q0 + lg * 4 + r;
#pragma unroll
        for (int nf = 0; nf < 6; ++nf)
            Y[((size_t)b * 1024 + qi) * 768 + h * 96 + nf * 16 + lr] = f2b(oacc[nf][r] * inv);
    }
}

// ---------------- layernorm with residual add (vectorized, 2 rows/block) ----------------
template <bool IN1BF, bool IN2BF>
__global__ __launch_bounds__(384) void ln_kernel(const void* __restrict__ in1,
                                                 const void* __restrict__ in2,
                                                 const float* __restrict__ g,
                                                 const float* __restrict__ be,
                                                 float* __restrict__ of,
                                                 unsigned short* __restrict__ ob) {
    const int tid = threadIdx.x;
    const int half = tid / 192;
    const int t = tid - half * 192;
    const int row = blockIdx.x * 2 + half;
    const size_t base = (size_t)row * 768 + t * 4;
    float a[4], bb[4];
    if (IN1BF) {
        ushort4 u = *(const ushort4*)((const unsigned short*)in1 + base);
        a[0] = b2f(u.x); a[1] = b2f(u.y); a[2] = b2f(u.z); a[3] = b2f(u.w);
    } else {
        float4 u = *(const float4*)((const float*)in1 + base);
        a[0] = u.x; a[1] = u.y; a[2] = u.z; a[3] = u.w;
    }
    if (IN2BF) {
        ushort4 u = *(const ushort4*)((const unsigned short*)in2 + base);
        bb[0] = b2f(u.x); bb[1] = b2f(u.y); bb[2] = b2f(u.z); bb[3] = b2f(u.w);
    } else {
        float4 u = *(const float4*)((const float*)in2 + base);
        bb[0] = u.x; bb[1] = u.y; bb[2] = u.z; bb[3] = u.w;
    }
    float v[4];
#pragma unroll
    for (int i = 0; i < 4; ++i) v[i] = a[i] + bb[i];
    float s1 = v[0] + v[1] + v[2] + v[3];
    float s2 = v[0] * v[0] + v[1] * v[1] + v[2] * v[2] + v[3] * v[3];
#pragma unroll
    for (int off = 32; off > 0; off >>= 1) {
        s1 += __shfl_xor(s1, off);
        s2 += __shfl_xor(s2, off);
    }
    __shared__ float red[12];
    const int wv = tid >> 6;
    if ((tid & 63) == 0) { red[wv] = s1; red[6 + wv] = s2; }
    __syncthreads();
    const int w0 = half * 3;
    s1 = red[w0] + red[w0 + 1] + red[w0 + 2];
    s2 = red[6 + w0] + red[6 + w0 + 1] + red[6 + w0 + 2];
    float mu = s1 * (1.f / 768.f);
    float var = s2 * (1.f / 768.f) - mu * mu;
    float inv = rsqrtf(var + 1e-5f);
    float o[4];
#pragma unroll
    for (int i = 0; i < 4; ++i)
        o[i] = (v[i] - mu) * inv * g[t * 4 + i] + be[t * 4 + i];
    if (of) {
        float4 w = {o[0], o[1], o[2], o[3]};
        *(float4*)(of + base) = w;
    }
    if (ob) {
        ushort4 w = {f2b(o[0]), f2b(o[1]), f2b(o[2]), f2b(o[3])};
        *(ushort4*)(ob + base) = w;
    }
}

extern "C" void kernel_launch(void* const* d_in, const int* in_sizes, int n_in,
                              void* d_out, int out_size, void* d_ws, size_t ws_size,
                              hipStream_t stream) {
    const float* x     = (const float*)d_in[0];
    const int*   nmask = (const int*)d_in[1];
    const float* cent  = (const float*)d_in[2];
    const int*   types = (const int*)d_in[3];
    const float* qkv_w = (const float*)d_in[4];
    const float* qkv_b = (const float*)d_in[5];
    const float* out_w = (const float*)d_in[6];
    const float* out_b = (const float*)d_in[7];
    const float* ff1_w = (const float*)d_in[8];
    const float* ff1_b = (const float*)d_in[9];
    const float* ff2_w = (const float*)d_in[10];
    const float* ff2_b = (const float*)d_in[11];
    const float* ln1_g = (const float*)d_in[12];
    const float* ln1_b = (const float*)d_in[13];
    const float* ln2_g = (const float*)d_in[14];
    const float* ln2_b = (const float*)d_in[15];
    const float* rel   = (const float*)d_in[16];
    const float* ttp   = (const float*)d_in[17];

    char* w = (char*)d_ws;
    auto alloc = [&](size_t bytes) {
        char* p = w;
        w += (bytes + 255) & ~(size_t)255;
        return p;
    };
    unsigned short* xb  = (unsigned short*)alloc(8192ull * 768 * 2);   // x bf16; reused as Y
    unsigned short* qwT = (unsigned short*)alloc(2304ull * 768 * 2);
    unsigned short* owT = (unsigned short*)alloc(768ull * 768 * 2);
    unsigned short* f1T = (unsigned short*)alloc(1024ull * 768 * 2);
    unsigned short* f2T = (unsigned short*)alloc(768ull * 1024 * 2);
    unsigned short* Qb  = (unsigned short*)alloc(64ull * 1024 * 96 * 2);
    unsigned short* Kb  = (unsigned short*)alloc(64ull * 1024 * 96 * 2);
    unsigned short* Vt  = (unsigned short*)alloc(64ull * 96 * 1024 * 2);
    unsigned short* aob = (unsigned short*)alloc(8192ull * 768 * 2);  // residual branch (bf16)
    unsigned short* h1b = (unsigned short*)alloc(8192ull * 768 * 2);
    unsigned short* ffa = Qb;  // alias: ff1 act (16.8MB) spans Qb+Kb (25.2MB), both dead after attn

    // fused cvt + 4 transposes: 6144 + 3840 = 9984 blocks
    prep_kernel<<<9984, 256, 0, stream>>>(x, xb, qkv_w, qwT, out_w, owT,
                                          ff1_w, f1T, ff2_w, f2T);

    // QKV: M=8192 N=2304 K=768 -> 64x18 = 1152 blocks
    gemm2p<3><<<1152, 512, 0, stream>>>(xb, qwT, qkv_b, nullptr, nullptr,
                                        Qb, Kb, Vt, 2304, 768, 18, 12);
    attn_kernel<<<dim3(64, 8), 512, 0, stream>>>(Qb, Kb, Vt, cent, types, nmask, ttp, rel, xb);
    // out proj: N=768 K=768 -> 384 blocks, bf16 out
    gemm2p<1><<<384, 512, 0, stream>>>(xb, owT, out_b, nullptr, aob,
                                       nullptr, nullptr, nullptr, 768, 768, 6, 12);
    ln_kernel<false, true><<<4096, 384, 0, stream>>>(x, aob, ln1_g, ln1_b, nullptr, h1b);
    // ff1+gelu: N=1024 K=768 -> 512 blocks
    gemm2p<2><<<512, 512, 0, stream>>>(h1b, f1T, ff1_b, nullptr, ffa,
                                       nullptr, nullptr, nullptr, 1024, 768, 8, 12);
    // ff2: N=768 K=1024 -> 384 blocks, NT=16, bf16 out (reuse aob)
    gemm2p<1><<<384, 512, 0, stream>>>(ffa, f2T, ff2_b, nullptr, aob,
                                       nullptr, nullptr, nullptr, 768, 1024, 6, 16);
    ln_kernel<true, true><<<4096, 384, 0, stream>>>(h1b, aob, ln2_g, ln2_b, (float*)d_out, nullptr);
}

// Round 15
// 180.471 us; speedup vs baseline: 1.3439x; 1.0335x over previous
//
#include <hip/hip_runtime.h>

typedef short short8 __attribute__((ext_vector_type(8)));
typedef unsigned short ushort8v __attribute__((ext_vector_type(8)));
typedef float f32x4 __attribute__((ext_vector_type(4)));

static __device__ __forceinline__ unsigned short f2b(float f) {
    unsigned int u = __builtin_bit_cast(unsigned int, f);
    unsigned int r = (u + 0x7fffu + ((u >> 16) & 1u)) >> 16;
    return (unsigned short)r;
}
static __device__ __forceinline__ float b2f(unsigned short u) {
    return __builtin_bit_cast(float, (unsigned int)u << 16);
}
static __device__ __forceinline__ float exp2v(float x) {
    float r;
    asm("v_exp_f32 %0, %1" : "=v"(r) : "v"(x));
    return r;
}
static __device__ __forceinline__ unsigned cvt_pk_bf16(float lo, float hi) {
    unsigned r;
    asm("v_cvt_pk_bf16_f32 %0, %1, %2" : "=v"(r) : "v"(lo), "v"(hi));
    return r;
}

__device__ __forceinline__ void gload16(void* lds, const void* g) {
    __builtin_amdgcn_global_load_lds(
        (const __attribute__((address_space(1))) void*)g,
        (__attribute__((address_space(3))) void*)lds, 16, 0, 0);
}

#define L2E 1.4426950408889634f

// ---------------- fused prep: cvt x (f32->bf16) + 4 weight transposes ----------------
__global__ __launch_bounds__(256) void prep_kernel(
    const float* __restrict__ x, unsigned short* __restrict__ xb,
    const float* __restrict__ qkv_w, unsigned short* __restrict__ qwT,
    const float* __restrict__ out_w, unsigned short* __restrict__ owT,
    const float* __restrict__ ff1_w, unsigned short* __restrict__ f1T,
    const float* __restrict__ ff2_w, unsigned short* __restrict__ f2T) {
    const int bx = blockIdx.x;
    const int tid = threadIdx.x;
    if (bx < 6144) {  // cvt x
        int i = bx * 256 + tid;
        float4 f = ((const float4*)x)[i];
        ushort4 u;
        u.x = f2b(f.x); u.y = f2b(f.y); u.z = f2b(f.z); u.w = f2b(f.w);
        ((ushort4*)xb)[i] = u;
        return;
    }
    __shared__ float t[32][33];
    int rb = bx - 6144;
    const float* W; unsigned short* Wt; int K, N;
    if (rb < 1728)      { W = qkv_w; Wt = qwT; K = 768;  N = 2304; }
    else if (rb < 2304) { rb -= 1728; W = out_w; Wt = owT; K = 768;  N = 768; }
    else if (rb < 3072) { rb -= 2304; W = ff1_w; Wt = f1T; K = 768;  N = 1024; }
    else                { rb -= 3072; W = ff2_w; Wt = f2T; K = 1024; N = 768; }
    const int nbl = N / 32;
    const int nb = (rb % nbl) * 32, kb = (rb / nbl) * 32;
    const int tx = tid & 31, ty = tid >> 5;
#pragma unroll
    for (int i = 0; i < 32; i += 8)
        t[ty + i][tx] = W[(size_t)(kb + ty + i) * N + nb + tx];
    __syncthreads();
#pragma unroll
    for (int i = 0; i < 32; i += 8)
        Wt[(size_t)(nb + ty + i) * K + kb + tx] = f2b(t[tx][ty + i]);
}

// ---------------- 128x128 BK=64 2-phase GEMM, 8 waves (64x32 per wave) ----------------
// EPI: 0 = f32 out, 1 = bf16 out, 2 = gelu->bf16 out, 3 = qkv scatter (width-96 Q/K)
template <int EPI>
__global__ __launch_bounds__(512, 4) void gemm2p(
    const unsigned short* __restrict__ A, const unsigned short* __restrict__ Bt,
    const float* __restrict__ bias, float* __restrict__ outf,
    unsigned short* __restrict__ outb, unsigned short* __restrict__ q_o,
    unsigned short* __restrict__ k_o, unsigned short* __restrict__ v_o,
    int N, int K, int ntn, int NT) {
    __shared__ unsigned short a_lds[2][8192];
    __shared__ unsigned short b_lds[2][8192];
    const int tid = threadIdx.x;
    const int wave = tid >> 6, lane = tid & 63;
    const int lr = lane & 15, lg = lane >> 4;
    const int wm = wave >> 2, wn = wave & 3;
    const int nwg = gridDim.x;
    const int orig = blockIdx.x;
    const int swz = (orig & 7) * (nwg >> 3) + (orig >> 3);
    const int tm = swz / ntn, tn = swz % ntn;

    const unsigned short* srcA[2];
    const unsigned short* srcB[2];
#pragma unroll
    for (int i = 0; i < 2; ++i) {
        int g = i * 512 + tid;
        int row = g >> 3, sl = g & 7;
        int colg = sl ^ (row & 7);
        srcA[i] = A + (size_t)(tm * 128 + row) * K + colg * 8;
        srcB[i] = Bt + (size_t)(tn * 128 + row) * K + colg * 8;
    }
    auto stage = [&](int buf, int k0) {
#pragma unroll
        for (int i = 0; i < 2; ++i) {
            gload16(&a_lds[buf][i * 4096 + wave * 512], srcA[i] + k0);
            gload16(&b_lds[buf][i * 4096 + wave * 512], srcB[i] + k0);
        }
    };

    f32x4 acc[4][2] = {};

    stage(0, 0);
    asm volatile("s_waitcnt vmcnt(0)" ::: "memory");
    __builtin_amdgcn_s_barrier();

    for (int t = 0; t < NT; ++t) {
        const int buf = t & 1;
        if (t + 1 < NT) stage(buf ^ 1, (t + 1) * 64);
#pragma unroll
        for (int ks = 0; ks < 2; ++ks) {
            short8 af[4], bfr[2];
#pragma unroll
            for (int mf = 0; mf < 4; ++mf) {
                int row = wm * 64 + mf * 16 + lr;
                int slot = (ks * 4 + lg) ^ (row & 7);
                af[mf] = *(const short8*)&a_lds[buf][row * 64 + slot * 8];
            }
#pragma unroll
            for (int nf = 0; nf < 2; ++nf) {
                int row = wn * 32 + nf * 16 + lr;
                int slot = (ks * 4 + lg) ^ (row & 7);
                bfr[nf] = *(const short8*)&b_lds[buf][row * 64 + slot * 8];
            }
#pragma unroll
            for (int mf = 0; mf < 4; ++mf)
#pragma unroll
                for (int nf = 0; nf < 2; ++nf)
                    acc[mf][nf] = __builtin_amdgcn_mfma_f32_16x16x32_bf16(af[mf], bfr[nf], acc[mf][nf], 0, 0, 0);
        }
        asm volatile("s_waitcnt vmcnt(0)" ::: "memory");
        __builtin_amdgcn_s_barrier();
    }

#pragma unroll
    for (int nf = 0; nf < 2; ++nf) {
        int gc = tn * 128 + wn * 32 + nf * 16 + lr;
        float bv = bias[gc];
        int part = 0, h = 0, dh = 0;
        if constexpr (EPI == 3) {
            part = gc / 768;
            int cc = gc - part * 768;
            h = cc / 96;
            dh = cc - h * 96;
        }
#pragma unroll
        for (int mf = 0; mf < 4; ++mf) {
            int grb = tm * 128 + wm * 64 + mf * 16 + lg * 4;
            if constexpr (EPI == 3) {
                int b = grb >> 10, n2 = grb & 1023;
                size_t bh = (size_t)(b * 8 + h);
                if (part == 2) {
                    ushort4 wv;
                    wv.x = f2b(acc[mf][nf][0] + bv);
                    wv.y = f2b(acc[mf][nf][1] + bv);
                    wv.z = f2b(acc[mf][nf][2] + bv);
                    wv.w = f2b(acc[mf][nf][3] + bv);
                    *(ushort4*)&v_o[(bh * 96 + dh) * 1024 + n2] = wv;
                } else {
                    unsigned short* dst = (part == 0) ? q_o : k_o;
                    float sc = (part == 0) ? 0.14724445f : 1.f;
#pragma unroll
                    for (int r = 0; r < 4; ++r)
                        dst[(bh * 1024 + n2 + r) * 96 + dh] = f2b((acc[mf][nf][r] + bv) * sc);
                }
            } else {
#pragma unroll
                for (int r = 0; r < 4; ++r) {
                    int gr = grb + r;
                    float v = acc[mf][nf][r] + bv;
                    if constexpr (EPI == 0) {
                        outf[(size_t)gr * N + gc] = v;
                    } else if constexpr (EPI == 1) {
                        outb[(size_t)gr * N + gc] = f2b(v);
                    } else {
                        float gl = 0.5f * v * (1.f + erff(v * 0.70710678f));
                        outb[(size_t)gr * N + gc] = f2b(gl);
                    }
                }
            }
        }
    }
}

// ---------------- flash attention: swapped QK^T, hoisted cjmm, folded flat-re ----------
// Q,K: [64][1024][96] bf16 (Q pre-scaled by 1/sqrt(96)*L2E) ; Vt: [64][96][1024] bf16
__global__ __launch_bounds__(512, 4) void attn_kernel(
    const unsigned short* __restrict__ Qb, const unsigned short* __restrict__ Kb,
    const unsigned short* __restrict__ Vt, const float* __restrict__ centers,
    const int* __restrict__ types, const int* __restrict__ nmask,
    const float* __restrict__ tt, const float* __restrict__ rel_emb,
    unsigned short* __restrict__ Y) {
    __shared__ unsigned short kv_lds[2 * 12288];  // 48 KB
    __shared__ unsigned short p_lds[8 * 1024];    // 16 KB (per-wave 16q x 64k bf16)
    __shared__ float c_lds[1024];                 // 4 KB
    __shared__ unsigned int bab_lds[1024];        // 4 KB packed (bA,bB) bf16 pairs
    __shared__ float rel_lds[41];
    __shared__ float cjmm_lds[32];                // [0..15]=min, [16..31]=max per tile

    const int tid = threadIdx.x;
    const int wave = tid >> 6, lane = tid & 63;
    const int lr = lane & 15, lg = lane >> 4;
    const int bh = blockIdx.x, qb = blockIdx.y;
    const int b = bh >> 3, h = bh & 7;
    const int q0 = qb * 128 + wave * 16;
    const size_t kvbase = (size_t)bh * 1024 * 96;

    // ---- prologue: centers, rel table, packed type/mask bias table ----
    c_lds[tid] = centers[b * 1024 + tid];
    c_lds[tid + 512] = centers[b * 1024 + 512 + tid];
    if (tid < 41) rel_lds[tid] = rel_emb[tid * 8 + h] * L2E;
    {
        const float t00 = tt[h * 4], t01 = tt[h * 4 + 1];
        const float t10 = tt[h * 4 + 2], t11 = tt[h * 4 + 3];
#pragma unroll
        for (int i = 0; i < 2; ++i) {
            int j = tid + i * 512;
            int tj = types[b * 1024 + j];
            int mk = nmask[b * 1024 + j];
            float bA = L2E * (t00 + (t01 - t00) * tj) + (mk ? 0.f : -1e30f);
            float bB = L2E * ((t10 - t00) + (t11 - t01 - t10 + t00) * tj);
            bab_lds[j] = (unsigned)f2b(bA) | ((unsigned)f2b(bB) << 16);
        }
    }

    // ---- per-lane pre-swizzled staging sources: 1536 granules = 3 x 512 ----
    const unsigned short* sbase[3];
    int sstep[3];
#pragma unroll
    for (int it = 0; it < 3; ++it) {
        int g = it * 512 + tid;
        if (g < 768) {  // K granule
            int ks = g >> 8, rem = g & 255, pr = rem >> 3, sl = rem & 7;
            int so = sl ^ (pr & 7);
            int r = ((so >> 2) << 5) + pr, oct = so & 3;
            sbase[it] = Kb + kvbase + (size_t)r * 96 + ks * 32 + oct * 8;
            sstep[it] = 64 * 96;
        } else {  // V granule
            int gv = g - 768, pr = gv >> 3, sl = gv & 7;
            int so = sl ^ (pr & 7);
            sbase[it] = Vt + (size_t)(bh * 96 + pr) * 1024 + so * 8;
            sstep[it] = 64;
        }
    }
    auto stage = [&](int bufb, int kt) {
        unsigned short* dst = kv_lds + bufb * 12288;
#pragma unroll
        for (int it = 0; it < 3; ++it)
            gload16(dst + it * 4096 + wave * 512, sbase[it] + (size_t)kt * sstep[it]);
    };

    // ---- Q fragments (3 ks) + in-register aug B-fragment ----
    short8 qa[3];
#pragma unroll
    for (int ks = 0; ks < 3; ++ks)
        qa[ks] = *(const short8*)&Qb[kvbase + (size_t)(q0 + lr) * 96 + ks * 32 + lg * 8];
    short8 qa3 = {};
    {
        int ti0 = types[b * 1024 + q0 + lr];
        if (lg == 0) {
            qa3[0] = (short)0x3F80;
            qa3[1] = ti0 ? (short)0x3F80 : (short)0;
        }
    }
    const float ci20 = centers[b * 1024 + q0 + lr] + 20.f;
    float cimax20 = ci20, cimin20 = ci20;
#pragma unroll
    for (int off = 1; off < 16; off <<= 1) {
        cimax20 = fmaxf(cimax20, __shfl_xor(cimax20, off));
        cimin20 = fminf(cimin20, __shfl_xor(cimin20, off));
    }

    float m_s = -3e30f, l_s = 0.f;
    f32x4 oacc[6] = {};
    unsigned* p32 = (unsigned*)&p_lds[wave * 1024];

    stage(0, 0);  // overlap HBM latency with the cjmm scan below
    asm volatile("s_waitcnt lgkmcnt(0)" ::: "memory");  // own ds_writes drained
    __builtin_amdgcn_s_barrier();                        // c_lds visible block-wide

    // ---- hoisted per-tile cj min/max scan (parallel: 16 tiles x 16 threads) ----
    if (tid < 256) {
        int ktt = tid >> 4;
        float4 cv = *(const float4*)&c_lds[ktt * 64 + (tid & 15) * 4];
        float mn = fminf(fminf(cv.x, cv.y), fminf(cv.z, cv.w));
        float mx = fmaxf(fmaxf(cv.x, cv.y), fmaxf(cv.z, cv.w));
#pragma unroll
        for (int off = 1; off < 16; off <<= 1) {
            mn = fminf(mn, __shfl_xor(mn, off));
            mx = fmaxf(mx, __shfl_xor(mx, off));
        }
        if ((tid & 15) == 0) { cjmm_lds[ktt] = mn; cjmm_lds[16 + ktt] = mx; }
    }
    asm volatile("s_waitcnt lgkmcnt(0)" ::: "memory");  // cjmm writes drained
    const float rel0v = rel_lds[0], rel40v = rel_lds[40];

    for (int kt = 0; kt < 16; ++kt) {
        const int buf = kt & 1;
        if (kt < 15) {
            stage(buf ^ 1, kt + 1);
            asm volatile("s_waitcnt vmcnt(3)" ::: "memory");
        } else {
            asm volatile("s_waitcnt vmcnt(0)" ::: "memory");
        }
        __builtin_amdgcn_s_barrier();  // also publishes cjmm on kt==0
        const unsigned short* kv = kv_lds + buf * 12288;

        // ---- swapped QK^T: s[jf][r] = S[q=q0+lr][k = jf*16 + lg*4 + r] ----
        f32x4 s[4] = {};
#pragma unroll
        for (int jf = 0; jf < 4; ++jf) {
            int pr = ((jf & 1) << 4) + lr;
            int slp = (((jf >> 1) << 2) + lg) ^ (lr & 7);
#pragma unroll
            for (int ks = 0; ks < 3; ++ks) {
                short8 kf = *(const short8*)&kv[ks * 2048 + pr * 64 + slp * 8];
                s[jf] = __builtin_amdgcn_mfma_f32_16x16x32_bf16(kf, qa[ks], s[jf], 0, 0, 0);
            }
            unsigned vb = bab_lds[kt * 64 + jf * 16 + lr];
            short8 kf3 = {};
            if (lg == 0) {
                kf3[0] = (short)(vb & 0xffffu);
                kf3[1] = (short)(vb >> 16);
            }
            s[jf] = __builtin_amdgcn_mfma_f32_16x16x32_bf16(kf3, qa3, s[jf], 0, 0, 0);
        }

        // ---- rel bias: 2-read band check; flat bias folded into exp argument ----
        float re_eff;
        {
            float cjmn = cjmm_lds[kt], cjmx = cjmm_lds[16 + kt];
            bool flatHi = (cimin20 - cjmx >= 40.f);
            bool flatLo = (cimax20 - cjmn <= 0.f);
            if (flatHi || flatLo) {
                re_eff = flatHi ? rel40v : rel0v;  // uniform; folded into mb below
            } else {
                re_eff = 0.f;
#pragma unroll
                for (int jf = 0; jf < 4; ++jf) {
                    float4 cj4 = *(const float4*)&c_lds[kt * 64 + jf * 16 + lg * 4];
                    float cjl[4] = {cj4.x, cj4.y, cj4.z, cj4.w};
#pragma unroll
                    for (int r = 0; r < 4; ++r) {
                        float idxf = __builtin_amdgcn_fmed3f(ci20 - cjl[r], 0.f, 40.f);
                        s[jf][r] += rel_lds[(int)rintf(idxf)];
                    }
                }
            }
        }

        // ---- online softmax, q lane-local (defer-max THR=8, re_eff-folded) ----
        {
            float mlr = s[0][0];
#pragma unroll
            for (int jf = 0; jf < 4; ++jf)
#pragma unroll
                for (int r = 0; r < 4; ++r) mlr = fmaxf(mlr, s[jf][r]);
            float mb = m_s - re_eff;
            if (!__all(mlr <= mb + 8.f)) {
                float mx = fmaxf(mlr, __shfl_xor(mlr, 16));
                mx = fmaxf(mx, __shfl_xor(mx, 32));
                mx += re_eff;
                float mn = fmaxf(m_s, mx);
                float al = exp2v(m_s - mn);
                m_s = mn;
                l_s *= al;
#pragma unroll
                for (int r = 0; r < 4; ++r) {
                    float alr = __shfl(al, lg * 4 + r);
#pragma unroll
                    for (int nf = 0; nf < 6; ++nf) oacc[nf][r] *= alr;
                }
                mb = m_s - re_eff;
            }
            float ls = 0.f;
#pragma unroll
            for (int jf = 0; jf < 4; ++jf)
#pragma unroll
                for (int r = 0; r < 4; ++r) {
                    s[jf][r] = exp2v(s[jf][r] - mb);
                    ls += s[jf][r];
                }
            ls += __shfl_xor(ls, 16);
            ls += __shfl_xor(ls, 32);
            l_s += ls;
        }

        // ---- P pack (cvt_pk) -> 4 x ds_write_b64 -> 2 x ds_read_b128 A-frags ----
#pragma unroll
        for (int jf = 0; jf < 4; ++jf) {
            uint2 w2;
            w2.x = cvt_pk_bf16(s[jf][0], s[jf][1]);
            w2.y = cvt_pk_bf16(s[jf][2], s[jf][3]);
            int gsw = ((jf * 4 + lg) ^ (lr & 14)) * 2;
            *(uint2*)&p32[lr * 32 + gsw] = w2;
        }
        asm volatile("s_waitcnt lgkmcnt(0)" ::: "memory");
        short8 pa[2];
#pragma unroll
        for (int js = 0; js < 2; ++js) {
            int gsw = (((js * 8 + lg * 2) ^ (lr & 14))) * 2;
            pa[js] = *(const short8*)&p32[lr * 32 + gsw];
        }

        // ---- PV ----
#pragma unroll
        for (int nf = 0; nf < 6; ++nf) {
            int vrow = nf * 16 + lr;
#pragma unroll
            for (int js = 0; js < 2; ++js) {
                int slp = ((js << 2) + lg) ^ (lr & 7);
                short8 vf = *(const short8*)&kv[6144 + vrow * 64 + slp * 8];
                oacc[nf] = __builtin_amdgcn_mfma_f32_16x16x32_bf16(pa[js], vf, oacc[nf], 0, 0, 0);
            }
        }
        __builtin_amdgcn_s_barrier();
    }

#pragma unroll
    for (int r = 0; r < 4; ++r) {
        float lrow = __shfl(l_s, lg * 4 + r);
        float inv = (lrow > 0.f) ? 1.f / lrow : 0.f;
        int qi = q0 + lg * 4 + r;
#pragma unroll
        for (int nf = 0; nf < 6; ++nf)
            Y[((size_t)b * 1024 + qi) * 768 + h * 96 + nf * 16 + lr] = f2b(oacc[nf][r] * inv);
    }
}

// ---------------- layernorm with residual add (vectorized, 2 rows/block) ----------------
template <bool IN1BF, bool IN2BF>
__global__ __launch_bounds__(384) void ln_kernel(const void* __restrict__ in1,
                                                 const void* __restrict__ in2,
                                                 const float* __restrict__ g,
                                                 const float* __restrict__ be,
                                                 float* __restrict__ of,
                                                 unsigned short* __restrict__ ob) {
    const int tid = threadIdx.x;
    const int half = tid / 192;
    const int t = tid - half * 192;
    const int row = blockIdx.x * 2 + half;
    const size_t base = (size_t)row * 768 + t * 4;
    float a[4], bb[4];
    if (IN1BF) {
        ushort4 u = *(const ushort4*)((const unsigned short*)in1 + base);
        a[0] = b2f(u.x); a[1] = b2f(u.y); a[2] = b2f(u.z); a[3] = b2f(u.w);
    } else {
        float4 u = *(const float4*)((const float*)in1 + base);
        a[0] = u.x; a[1] = u.y; a[2] = u.z; a[3] = u.w;
    }
    if (IN2BF) {
        ushort4 u = *(const ushort4*)((const unsigned short*)in2 + base);
        bb[0] = b2f(u.x); bb[1] = b2f(u.y); bb[2] = b2f(u.z); bb[3] = b2f(u.w);
    } else {
        float4 u = *(const float4*)((const float*)in2 + base);
        bb[0] = u.x; bb[1] = u.y; bb[2] = u.z; bb[3] = u.w;
    }
    float v[4];
#pragma unroll
    for (int i = 0; i < 4; ++i) v[i] = a[i] + bb[i];
    float s1 = v[0] + v[1] + v[2] + v[3];
    float s2 = v[0] * v[0] + v[1] * v[1] + v[2] * v[2] + v[3] * v[3];
#pragma unroll
    for (int off = 32; off > 0; off >>= 1) {
        s1 += __shfl_xor(s1, off);
        s2 += __shfl_xor(s2, off);
    }
    __shared__ float red[12];
    const int wv = tid >> 6;
    if ((tid & 63) == 0) { red[wv] = s1; red[6 + wv] = s2; }
    __syncthreads();
    const int w0 = half * 3;
    s1 = red[w0] + red[w0 + 1] + red[w0 + 2];
    s2 = red[6 + w0] + red[6 + w0 + 1] + red[6 + w0 + 2];
    float mu = s1 * (1.f / 768.f);
    float var = s2 * (1.f / 768.f) - mu * mu;
    float inv = rsqrtf(var + 1e-5f);
    float o[4];
#pragma unroll
    for (int i = 0; i < 4; ++i)
        o[i] = (v[i] - mu) * inv * g[t * 4 + i] + be[t * 4 + i];
    if (of) {
        float4 w = {o[0], o[1], o[2], o[3]};
        *(float4*)(of + base) = w;
    }
    if (ob) {
        ushort4 w = {f2b(o[0]), f2b(o[1]), f2b(o[2]), f2b(o[3])};
        *(ushort4*)(ob + base) = w;
    }
}

extern "C" void kernel_launch(void* const* d_in, const int* in_sizes, int n_in,
                              void* d_out, int out_size, void* d_ws, size_t ws_size,
                              hipStream_t stream) {
    const float* x     = (const float*)d_in[0];
    const int*   nmask = (const int*)d_in[1];
    const float* cent  = (const float*)d_in[2];
    const int*   types = (const int*)d_in[3];
    const float* qkv_w = (const float*)d_in[4];
    const float* qkv_b = (const float*)d_in[5];
    const float* out_w = (const float*)d_in[6];
    const float* out_b = (const float*)d_in[7];
    const float* ff1_w = (const float*)d_in[8];
    const float* ff1_b = (const float*)d_in[9];
    const float* ff2_w = (const float*)d_in[10];
    const float* ff2_b = (const float*)d_in[11];
    const float* ln1_g = (const float*)d_in[12];
    const float* ln1_b = (const float*)d_in[13];
    const float* ln2_g = (const float*)d_in[14];
    const float* ln2_b = (const float*)d_in[15];
    const float* rel   = (const float*)d_in[16];
    const float* ttp   = (const float*)d_in[17];

    char* w = (char*)d_ws;
    auto alloc = [&](size_t bytes) {
        char* p = w;
        w += (bytes + 255) & ~(size_t)255;
        return p;
    };
    unsigned short* xb  = (unsigned short*)alloc(8192ull * 768 * 2);   // x bf16 (NOT clobbered)
    unsigned short* yb  = (unsigned short*)alloc(8192ull * 768 * 2);   // attn output Y
    unsigned short* qwT = (unsigned short*)alloc(2304ull * 768 * 2);
    unsigned short* owT = (unsigned short*)alloc(768ull * 768 * 2);
    unsigned short* f1T = (unsigned short*)alloc(1024ull * 768 * 2);
    unsigned short* f2T = (unsigned short*)alloc(768ull * 1024 * 2);
    unsigned short* Qb  = (unsigned short*)alloc(64ull * 1024 * 96 * 2);
    unsigned short* Kb  = (unsigned short*)alloc(64ull * 1024 * 96 * 2);
    unsigned short* Vt  = (unsigned short*)alloc(64ull * 96 * 1024 * 2);
    unsigned short* aob = (unsigned short*)alloc(8192ull * 768 * 2);  // residual branch (bf16)
    unsigned short* h1b = (unsigned short*)alloc(8192ull * 768 * 2);
    unsigned short* ffa = Qb;  // alias: ff1 act (16.8MB) spans Qb+Kb (25.2MB), both dead after attn

    // fused cvt + 4 transposes: 6144 + 3840 = 9984 blocks
    prep_kernel<<<9984, 256, 0, stream>>>(x, xb, qkv_w, qwT, out_w, owT,
                                          ff1_w, f1T, ff2_w, f2T);

    // QKV: M=8192 N=2304 K=768 -> 64x18 = 1152 blocks
    gemm2p<3><<<1152, 512, 0, stream>>>(xb, qwT, qkv_b, nullptr, nullptr,
                                        Qb, Kb, Vt, 2304, 768, 18, 12);
    attn_kernel<<<dim3(64, 8), 512, 0, stream>>>(Qb, Kb, Vt, cent, types, nmask, ttp, rel, yb);
    // out proj: N=768 K=768 -> 384 blocks, bf16 out
    gemm2p<1><<<384, 512, 0, stream>>>(yb, owT, out_b, nullptr, aob,
                                       nullptr, nullptr, nullptr, 768, 768, 6, 12);
    // LN1 reads xb (bf16, intact) instead of x (f32): -12.6 MB HBM
    ln_kernel<true, true><<<4096, 384, 0, stream>>>(xb, aob, ln1_g, ln1_b, nullptr, h1b);
    // ff1+gelu: N=1024 K=768 -> 512 blocks
    gemm2p<2><<<512, 512, 0, stream>>>(h1b, f1T, ff1_b, nullptr, ffa,
                                       nullptr, nullptr, nullptr, 1024, 768, 8, 12);
    // ff2: N=768 K=1024 -> 384 blocks, NT=16, bf16 out (reuse aob)
    gemm2p<1><<<384, 512, 0, stream>>>(ffa, f2T, ff2_b, nullptr, aob,
                                       nullptr, nullptr, nullptr, 768, 1024, 6, 16);
    ln_kernel<true, true><<<4096, 384, 0, stream>>>(h1b, aob, ln2_g, ln2_b, (float*)d_out, nullptr);
}